// Round 4
// baseline (621.018 us; speedup 1.0000x reference)
//
#include <hip/hip_runtime.h>
#include <stdint.h>

#define LSEQ 384
#define LL   147456   // 384*384
#define NODE 256
#define NH   8
#define HD   32
#define PDIM 128
#define D1   1280
#define D2   512

typedef __attribute__((ext_vector_type(8))) short s16x8;
typedef __attribute__((ext_vector_type(8))) __bf16 bf16x8;
typedef __attribute__((ext_vector_type(4))) float f32x4;

__device__ __forceinline__ float bf2f(uint16_t u) {
    union { uint32_t i; float f; } x; x.i = ((uint32_t)u) << 16; return x.f;
}
__device__ __forceinline__ uint16_t f2bf(float f) {
    uint32_t b = __float_as_uint(f);
    return (uint16_t)((b + 0x7FFFu + ((b >> 16) & 1u)) >> 16);
}
// dtype-adaptive input load: element index i, bf=1 -> bf16, bf=0 -> f32
__device__ __forceinline__ float ld(const void* p, size_t i, int bf) {
    return bf ? bf2f(((const uint16_t*)p)[i]) : ((const float*)p)[i];
}
// dtype-adaptive output store
__device__ __forceinline__ void stout(void* p, size_t i, float v, int bf) {
    if (bf) ((uint16_t*)p)[i] = f2bf(v);
    else    ((float*)p)[i] = v;
}

__device__ __forceinline__ bf16x8 bf16x8_zero() {
    union { s16x8 s; bf16x8 b; } u; u.s = (s16x8)0; return u.b;
}

__device__ __forceinline__ void block_reduce2_256(float* s1, float* s2, int t) {
    __syncthreads();
    for (int o = 128; o > 0; o >>= 1) {
        if (t < o) { s1[t] += s1[t + o]; s2[t] += s2[t + o]; }
        __syncthreads();
    }
}

// accumulate 8 bf16 packed in a uint4 into sum / sumsq
__device__ __forceinline__ void acc8(uint4 u, float& s, float& ss) {
    uint32_t w[4] = { u.x, u.y, u.z, u.w };
    #pragma unroll
    for (int i = 0; i < 4; ++i) {
        float a = bf2f((uint16_t)(w[i] & 0xFFFFu));
        float b = bf2f((uint16_t)(w[i] >> 16));
        s += a + b;
        ss = fmaf(a, a, ss);
        ss = fmaf(b, b, ss);
    }
}

// ---------------- dtype detection: sample low u16 halves of z ----------------
__global__ void k_detect(const uint32_t* __restrict__ zz, int* __restrict__ flag) {
    if (threadIdx.x == 0 && blockIdx.x == 0) {
        int cnt = 0;
        for (int i = 0; i < 256; ++i) {
            uint32_t lo = zz[i] & 0xFFFFu;
            uint32_t e = (lo >> 7) & 0xFFu;
            if (lo == 0u || (e >= 96u && e <= 142u)) ++cnt;
        }
        flag[0] = (cnt >= 192) ? 1 : 0;   // 1 = inputs are bf16, 0 = f32
    }
}

// ---------------- convert to canon bf16 (identity roundtrip in bf16 mode) ----------------
__global__ __launch_bounds__(256) void k_cvt(
    const void* __restrict__ src, uint16_t* __restrict__ dst, const int* __restrict__ dt)
{
    int bf = dt[0];
    int i = blockIdx.x * 256 + threadIdx.x;
    dst[i] = f2bf(ld(src, i, bf));
}

// ---------------- weight transpose K-major -> N-major bf16 via 32x32 LDS tiles ----------
// dst[n][k] = src[k][n]; grid (K/32, N/32)
__global__ __launch_bounds__(256) void k_wnk(
    const void* __restrict__ src, uint16_t* __restrict__ dst, int K, int N,
    const int* __restrict__ dt)
{
    __shared__ float tile[32][33];
    int bf = dt[0];
    int k0 = blockIdx.x * 32, n0 = blockIdx.y * 32;
    int tr = threadIdx.x >> 5, tc = threadIdx.x & 31;
    #pragma unroll
    for (int i = 0; i < 4; ++i)
        tile[tr + i * 8][tc] = ld(src, (size_t)(k0 + tr + i * 8) * N + n0 + tc, bf);
    __syncthreads();
    #pragma unroll
    for (int i = 0; i < 4; ++i)
        dst[(size_t)(n0 + tr + i * 8) * K + k0 + tc] = f2bf(tile[tc][tr + i * 8]);
}

// ---------------- generic 64x64-tile MFMA GEMM: out f32 = A @ B^T + bias ----------------
__global__ __launch_bounds__(256) void k_gemm_bias_f32(
    const uint16_t* __restrict__ A, const uint16_t* __restrict__ B,
    const void* __restrict__ bias, float* __restrict__ out, int K, int N,
    const int* __restrict__ dt)
{
    __shared__ __align__(16) uint16_t As[64 * 72];
    __shared__ __align__(16) uint16_t Bs[64 * 72];
    int bf = dt[0];
    int t = threadIdx.x;
    int row0 = blockIdx.x * 64, col0 = blockIdx.y * 64;
    int w = t >> 6, lane = t & 63, p = lane & 15, g = lane >> 4;
    int wm = w >> 1, wn = w & 1;
    f32x4 acc[2][2];
    #pragma unroll
    for (int i = 0; i < 2; ++i)
        #pragma unroll
        for (int j = 0; j < 2; ++j) acc[i][j] = (f32x4){0.f, 0.f, 0.f, 0.f};

    for (int kc = 0; kc < K; kc += 64) {
        __syncthreads();
        #pragma unroll
        for (int rep = 0; rep < 2; ++rep) {
            int i = t + rep * 256;
            int r = i >> 3, c8 = (i & 7) * 8;
            *(uint4*)&As[r * 72 + c8] = *(const uint4*)&A[(size_t)(row0 + r) * K + kc + c8];
            *(uint4*)&Bs[r * 72 + c8] = *(const uint4*)&B[(size_t)(col0 + r) * K + kc + c8];
        }
        __syncthreads();
        #pragma unroll
        for (int kk = 0; kk < 64; kk += 32) {
            bf16x8 a0 = *(const bf16x8*)&As[(wm * 32 + p) * 72 + kk + 8 * g];
            bf16x8 a1 = *(const bf16x8*)&As[(wm * 32 + 16 + p) * 72 + kk + 8 * g];
            bf16x8 b0 = *(const bf16x8*)&Bs[(wn * 32 + p) * 72 + kk + 8 * g];
            bf16x8 b1 = *(const bf16x8*)&Bs[(wn * 32 + 16 + p) * 72 + kk + 8 * g];
            acc[0][0] = __builtin_amdgcn_mfma_f32_16x16x32_bf16(a0, b0, acc[0][0], 0, 0, 0);
            acc[0][1] = __builtin_amdgcn_mfma_f32_16x16x32_bf16(a0, b1, acc[0][1], 0, 0, 0);
            acc[1][0] = __builtin_amdgcn_mfma_f32_16x16x32_bf16(a1, b0, acc[1][0], 0, 0, 0);
            acc[1][1] = __builtin_amdgcn_mfma_f32_16x16x32_bf16(a1, b1, acc[1][1], 0, 0, 0);
        }
    }
    #pragma unroll
    for (int mi = 0; mi < 2; ++mi)
        #pragma unroll
        for (int ni = 0; ni < 2; ++ni) {
            int n = col0 + wn * 32 + ni * 16 + p;
            float bb = ld(bias, n, bf);
            #pragma unroll
            for (int reg = 0; reg < 4; ++reg) {
                int m = row0 + wm * 32 + mi * 16 + 4 * g + reg;
                out[(size_t)m * N + n] = acc[mi][ni][reg] + bb;
            }
        }
}

// ---------------- q,k,v GEMM: [384x768x256] = xb @ [Wq|Wk|Wv]^T -> canon bf16 ----------------
__global__ __launch_bounds__(256) void k_gemm_qkv(
    const uint16_t* __restrict__ A, const uint16_t* __restrict__ B,
    uint16_t* __restrict__ q, uint16_t* __restrict__ k, uint16_t* __restrict__ v)
{
    __shared__ __align__(16) uint16_t As[64 * 72];
    __shared__ __align__(16) uint16_t Bs[64 * 72];
    const int K = 256;
    int t = threadIdx.x;
    int row0 = blockIdx.x * 64, col0 = blockIdx.y * 64;
    int w = t >> 6, lane = t & 63, p = lane & 15, g = lane >> 4;
    int wm = w >> 1, wn = w & 1;
    f32x4 acc[2][2];
    #pragma unroll
    for (int i = 0; i < 2; ++i)
        #pragma unroll
        for (int j = 0; j < 2; ++j) acc[i][j] = (f32x4){0.f, 0.f, 0.f, 0.f};

    for (int kc = 0; kc < K; kc += 64) {
        __syncthreads();
        #pragma unroll
        for (int rep = 0; rep < 2; ++rep) {
            int i = t + rep * 256;
            int r = i >> 3, c8 = (i & 7) * 8;
            *(uint4*)&As[r * 72 + c8] = *(const uint4*)&A[(size_t)(row0 + r) * K + kc + c8];
            *(uint4*)&Bs[r * 72 + c8] = *(const uint4*)&B[(size_t)(col0 + r) * K + kc + c8];
        }
        __syncthreads();
        #pragma unroll
        for (int kk = 0; kk < 64; kk += 32) {
            bf16x8 a0 = *(const bf16x8*)&As[(wm * 32 + p) * 72 + kk + 8 * g];
            bf16x8 a1 = *(const bf16x8*)&As[(wm * 32 + 16 + p) * 72 + kk + 8 * g];
            bf16x8 b0 = *(const bf16x8*)&Bs[(wn * 32 + p) * 72 + kk + 8 * g];
            bf16x8 b1 = *(const bf16x8*)&Bs[(wn * 32 + 16 + p) * 72 + kk + 8 * g];
            acc[0][0] = __builtin_amdgcn_mfma_f32_16x16x32_bf16(a0, b0, acc[0][0], 0, 0, 0);
            acc[0][1] = __builtin_amdgcn_mfma_f32_16x16x32_bf16(a0, b1, acc[0][1], 0, 0, 0);
            acc[1][0] = __builtin_amdgcn_mfma_f32_16x16x32_bf16(a1, b0, acc[1][0], 0, 0, 0);
            acc[1][1] = __builtin_amdgcn_mfma_f32_16x16x32_bf16(a1, b1, acc[1][1], 0, 0, 0);
        }
    }
    #pragma unroll
    for (int mi = 0; mi < 2; ++mi)
        #pragma unroll
        for (int ni = 0; ni < 2; ++ni) {
            int nglob = col0 + wn * 32 + ni * 16 + p;
            int sel = nglob >> 8, col = nglob & 255;
            uint16_t* dst = (sel == 0) ? q : (sel == 1) ? k : v;
            #pragma unroll
            for (int reg = 0; reg < 4; ++reg) {
                int m = row0 + wm * 32 + mi * 16 + 4 * g + reg;
                dst[(size_t)m * 256 + col] = f2bf(acc[mi][ni][reg]);
            }
        }
}

// ---------------- lin2 + bias + residual + final LN, fused MFMA ----------------
__global__ __launch_bounds__(256) void k_lin2lnf_mfma(
    const uint16_t* __restrict__ A, const uint16_t* __restrict__ B,
    const void* __restrict__ bias, const void* __restrict__ x,
    const void* __restrict__ lnw, const void* __restrict__ lnb,
    void* __restrict__ out, const int* __restrict__ dt)
{
    __shared__ __align__(16) uint16_t As[32 * 72];
    __shared__ __align__(16) uint16_t Bs[256 * 72];
    const int K = 512;
    int bf = dt[0];
    int t = threadIdx.x;
    int row0 = blockIdx.x * 32;
    int w = t >> 6, lane = t & 63, p = lane & 15, g = lane >> 4;
    f32x4 acc[2][4];
    #pragma unroll
    for (int i = 0; i < 2; ++i)
        #pragma unroll
        for (int j = 0; j < 4; ++j) acc[i][j] = (f32x4){0.f, 0.f, 0.f, 0.f};

    for (int kc = 0; kc < K; kc += 64) {
        __syncthreads();
        {   // A: 32x64 = 256 uint4 groups
            int r = t >> 3, c8 = (t & 7) * 8;
            *(uint4*)&As[r * 72 + c8] = *(const uint4*)&A[(size_t)(row0 + r) * K + kc + c8];
        }
        #pragma unroll
        for (int rep = 0; rep < 8; ++rep) {   // B: 256x64 = 2048 uint4 groups
            int i = t + rep * 256;
            int r = i >> 3, c8 = (i & 7) * 8;
            *(uint4*)&Bs[r * 72 + c8] = *(const uint4*)&B[(size_t)r * K + kc + c8];
        }
        __syncthreads();
        #pragma unroll
        for (int kk = 0; kk < 64; kk += 32) {
            bf16x8 a0 = *(const bf16x8*)&As[(p) * 72 + kk + 8 * g];
            bf16x8 a1 = *(const bf16x8*)&As[(16 + p) * 72 + kk + 8 * g];
            #pragma unroll
            for (int ni = 0; ni < 4; ++ni) {
                bf16x8 bq = *(const bf16x8*)&Bs[(w * 64 + ni * 16 + p) * 72 + kk + 8 * g];
                acc[0][ni] = __builtin_amdgcn_mfma_f32_16x16x32_bf16(a0, bq, acc[0][ni], 0, 0, 0);
                acc[1][ni] = __builtin_amdgcn_mfma_f32_16x16x32_bf16(a1, bq, acc[1][ni], 0, 0, 0);
            }
        }
    }
    __syncthreads();
    float* lnt = (float*)Bs;   // 32 x 264 f32 tile
    #pragma unroll
    for (int mi = 0; mi < 2; ++mi)
        #pragma unroll
        for (int ni = 0; ni < 4; ++ni) {
            int n = w * 64 + ni * 16 + p;
            float bb = ld(bias, n, bf);
            #pragma unroll
            for (int reg = 0; reg < 4; ++reg) {
                int m = mi * 16 + 4 * g + reg;
                lnt[m * 264 + n] = acc[mi][ni][reg] + bb + ld(x, (size_t)(row0 + m) * 256 + n, bf);
            }
        }
    __syncthreads();
    for (int rr = 0; rr < 8; ++rr) {
        int m = w * 8 + rr;
        float4 v4 = *(const float4*)&lnt[m * 264 + lane * 4];
        float vv[4] = { v4.x, v4.y, v4.z, v4.w };
        float s = (vv[0] + vv[1]) + (vv[2] + vv[3]);
        float ss = fmaf(vv[0], vv[0], fmaf(vv[1], vv[1], fmaf(vv[2], vv[2], vv[3] * vv[3])));
        #pragma unroll
        for (int off = 32; off > 0; off >>= 1) {
            s  += __shfl_xor(s, off);
            ss += __shfl_xor(ss, off);
        }
        float mean = s / 256.f;
        float rstd = rsqrtf(fmaxf(ss / 256.f - mean * mean, 0.f) + 1e-5f);
        #pragma unroll
        for (int i = 0; i < 4; ++i) {
            int c = lane * 4 + i;
            float val = (vv[i] - mean) * rstd * ld(lnw, c, bf) + ld(lnb, c, bf);
            stout(out, (size_t)(row0 + m) * 256 + c, val, bf);
        }
    }
}

// ---------------- a_pair = z @ Wp2a -> acat[h][l][m] (bf16) ----------------
__global__ __launch_bounds__(256) void k_apair(
    const void* __restrict__ z, const void* __restrict__ Wp2a,
    uint16_t* __restrict__ acat, const int* __restrict__ dt)
{
    __shared__ float zl[32 * 129];
    __shared__ float wp[PDIM * NH];
    int bf = dt[0];
    int t = threadIdx.x, m0 = blockIdx.x * 32, l = blockIdx.y;
    for (int i = t; i < PDIM * NH; i += 256) wp[i] = ld(Wp2a, i, bf);
    for (int i = t; i < 32 * PDIM; i += 256) {
        int ml = i >> 7, p = i & 127;
        zl[ml * 129 + p] = ld(z, ((size_t)(l * LSEQ + m0 + ml)) * PDIM + p, bf);
    }
    __syncthreads();
    int h = t >> 5, ml = t & 31;
    float acc = 0.f;
    for (int p = 0; p < PDIM; ++p) acc = fmaf(zl[ml * 129 + p], wp[p * NH + h], acc);
    acat[(size_t)h * LL + l * LSEQ + m0 + ml] = f2bf(acc);
}

// ---------------- a_node = (q k^T)/sqrt(hd) -> acat[8+h][l][m] (bf16) ----------------
__global__ __launch_bounds__(256) void k_anode(
    const uint16_t* __restrict__ q, const uint16_t* __restrict__ k,
    uint16_t* __restrict__ acat)
{
    __shared__ float kl[NODE * 33];
    __shared__ float qr[NH * 33];
    int t = threadIdx.x, m0 = blockIdx.x * 32, l = blockIdx.y;
    for (int i = t; i < 32 * NODE; i += 256) {
        int ml = i >> 8, col = i & 255;
        kl[col * 33 + ml] = bf2f(k[(m0 + ml) * NODE + col]);
    }
    qr[(t >> 5) * 33 + (t & 31)] = bf2f(q[l * NODE + t]);
    __syncthreads();
    int h = t >> 5, ml = t & 31;
    float acc = 0.f;
    #pragma unroll 8
    for (int d = 0; d < HD; ++d)
        acc = fmaf(qr[h * 33 + d], kl[(h * HD + d) * 33 + ml], acc);
    acat[(size_t)(NH + h) * LL + l * LSEQ + m0 + ml] = f2bf(acc * 0.17677669529663687f);
}

// ---------------- unified stats partial: canon channels (+ optional raw tail ch) ------
// grid (18, Cy). c < C: bf16 channel c of src. c == C: raw dtype-adaptive buffer.
__global__ __launch_bounds__(256) void k_scp(
    const uint16_t* __restrict__ src, const void* __restrict__ raw,
    float* __restrict__ ps, float* __restrict__ pss, const int* __restrict__ dt, int C)
{
    __shared__ float s1[256], s2[256];
    int c = blockIdx.y, chunk = blockIdx.x, t = threadIdx.x;
    float s = 0.f, ss = 0.f;
    if (c < C) {
        const uint16_t* p = src + (size_t)c * LL + (size_t)chunk * 8192;
        #pragma unroll
        for (int it = 0; it < 4; ++it) acc8(*(const uint4*)&p[(it * 256 + t) * 8], s, ss);
    } else if (dt[0]) {
        const uint4* p = (const uint4*)raw + (size_t)chunk * 1024;
        #pragma unroll
        for (int it = 0; it < 4; ++it) acc8(p[it * 256 + t], s, ss);
    } else {
        const float4* p = (const float4*)raw + (size_t)chunk * 2048;
        #pragma unroll
        for (int it = 0; it < 8; ++it) {
            float4 a = p[it * 256 + t];
            s += (a.x + a.y) + (a.z + a.w);
            ss = fmaf(a.x, a.x, fmaf(a.y, a.y, fmaf(a.z, a.z, fmaf(a.w, a.w, ss))));
        }
    }
    s1[t] = s; s2[t] = ss;
    block_reduce2_256(s1, s2, t);
    if (t == 0) { ps[c * 18 + chunk] = s1[0]; pss[c * 18 + chunk] = s2[0]; }
}

// finalize: thread t < C sums 18 partials
__global__ void k_scf(
    const float* __restrict__ ps, const float* __restrict__ pss,
    float* __restrict__ mean_out, float* __restrict__ rstd_out, int C)
{
    int t = threadIdx.x;
    if (t < C) {
        float s = 0.f, ss = 0.f;
        for (int i = 0; i < 18; ++i) { s += ps[t * 18 + i]; ss += pss[t * 18 + i]; }
        float m = s / (float)LL;
        float var = ss / (float)LL - m * m;
        mean_out[t] = m; rstd_out[t] = rsqrtf(fmaxf(var, 0.f) + 1e-5f);
    }
}

// ---------------- conv_a: 16 -> 8 channels, IN folded into weights ----------------
__global__ __launch_bounds__(128) void k_conv_a(
    const uint16_t* __restrict__ acat, const void* __restrict__ wa,
    const void* __restrict__ ba, const float* __restrict__ mean,
    const float* __restrict__ rstd, uint16_t* __restrict__ out,
    const int* __restrict__ dt)
{
    __shared__ float wl[144];
    __shared__ float ot[9];
    __shared__ float mn[16];
    int bf = dt[0];
    int t = threadIdx.x;
    int oc = blockIdx.z, l = blockIdx.y, m = blockIdx.x * 128 + t;
    if (t < 16) mn[t] = mean[t];
    for (int i = t; i < 144; i += 128) {
        int ic = i / 9;
        wl[i] = ld(wa, oc * 144 + i, bf) * rstd[ic];
    }
    __syncthreads();
    if (t < 9) {
        float s = 0.f;
        for (int ic = 0; ic < 16; ++ic) s = fmaf(mn[ic], wl[ic * 9 + t], s);
        ot[t] = s;
    }
    __syncthreads();
    float acc = ld(ba, oc, bf);
    #pragma unroll
    for (int r = 0; r < 3; ++r) {
        int li = l + r - 1;
        if (li < 0 || li >= LSEQ) continue;
        #pragma unroll
        for (int c = 0; c < 3; ++c) {
            int mi = m + c - 1;
            if (mi < 0 || mi >= LSEQ) continue;
            const uint16_t* ip = acat + li * LSEQ + mi;
            float a = 0.f;
            #pragma unroll
            for (int ic = 0; ic < 16; ++ic) a = fmaf(bf2f(ip[(size_t)ic * LL]), wl[ic * 9 + r * 3 + c], a);
            acc += a - ot[r * 3 + c];
        }
    }
    acc = acc >= 0.f ? acc : 0.01f * acc;
    out[(size_t)oc * LL + l * LSEQ + m] = f2bf(acc);
}

// ---------------- conv_m: 9 -> 8 channels (8 canon bf16 + raw plddt) ----------------
__global__ __launch_bounds__(128) void k_conv_m(
    const uint16_t* __restrict__ a1, const void* __restrict__ plddt,
    const void* __restrict__ wm, const void* __restrict__ bm,
    const float* __restrict__ mean, const float* __restrict__ rstd,
    uint16_t* __restrict__ out, const int* __restrict__ dt)
{
    __shared__ float wl[81];
    __shared__ float ot[9];
    __shared__ float mn[9];
    int bf = dt[0];
    int t = threadIdx.x;
    int oc = blockIdx.z, l = blockIdx.y, m = blockIdx.x * 128 + t;
    if (t < 9) mn[t] = mean[t];
    for (int i = t; i < 81; i += 128) {
        int ic = i / 9;
        wl[i] = ld(wm, oc * 81 + i, bf) * rstd[ic];
    }
    __syncthreads();
    if (t < 9) {
        float s = 0.f;
        for (int ic = 0; ic < 9; ++ic) s = fmaf(mn[ic], wl[ic * 9 + t], s);
        ot[t] = s;
    }
    __syncthreads();
    float acc = ld(bm, oc, bf);
    #pragma unroll
    for (int r = 0; r < 3; ++r) {
        int li = l + r - 1;
        if (li < 0 || li >= LSEQ) continue;
        #pragma unroll
        for (int c = 0; c < 3; ++c) {
            int mi = m + c - 1;
            if (mi < 0 || mi >= LSEQ) continue;
            int off = li * LSEQ + mi;
            float a = 0.f;
            #pragma unroll
            for (int ic = 0; ic < 8; ++ic) a = fmaf(bf2f(a1[(size_t)ic * LL + off]), wl[ic * 9 + r * 3 + c], a);
            a = fmaf(ld(plddt, off, bf), wl[72 + r * 3 + c], a);
            acc += a - ot[r * 3 + c];
        }
    }
    acc = acc >= 0.f ? acc : 0.01f * acc;
    out[(size_t)oc * LL + l * LSEQ + m] = f2bf(acc);
}

// ---------------- aggregations: nfp + nfn -> cat (384 x 1280, f32) ----------------
// 512 thr: nfp with 4-way m-split + LDS combine; nfn with 2-way m-split.
__global__ __launch_bounds__(512) void k_agg(
    const uint16_t* __restrict__ a2, const uint16_t* __restrict__ v,
    const void* __restrict__ z, float* __restrict__ cat,
    const int* __restrict__ dt)
{
    __shared__ float al[NH * LSEQ];       // 12 KB
    __shared__ float hp[3 * NH * PDIM];   // 12 KB partials (reused for nfn)
    int bf = dt[0];
    int t = threadIdx.x, l = blockIdx.x;
    for (int i = t; i < NH * LSEQ; i += 512) {
        int h = i / LSEQ, m = i - h * LSEQ;
        al[i] = bf2f(a2[(size_t)h * LL + l * LSEQ + m]);
    }
    __syncthreads();
    int p = t & 127, qq = t >> 7;   // qq in 0..3
    float acc[NH];
    #pragma unroll
    for (int h = 0; h < NH; ++h) acc[h] = 0.f;
    size_t zrow = (size_t)l * LSEQ * PDIM;
    for (int m = qq; m < LSEQ; m += 4) {
        float zv = ld(z, zrow + (size_t)m * PDIM + p, bf);
        #pragma unroll
        for (int h = 0; h < NH; ++h) acc[h] = fmaf(al[h * LSEQ + m], zv, acc[h]);
    }
    if (qq) {
        #pragma unroll
        for (int h = 0; h < NH; ++h) hp[(qq - 1) * 1024 + h * PDIM + p] = acc[h];
    }
    __syncthreads();
    if (qq == 0) {
        #pragma unroll
        for (int h = 0; h < NH; ++h)
            cat[(size_t)l * D1 + h * PDIM + p] =
                acc[h] + hp[h * PDIM + p] + hp[1024 + h * PDIM + p] + hp[2048 + h * PDIM + p];
    }
    // nfn: 256 outputs, 2-way m split
    int o = t & 255, half = t >> 8;
    int h2 = o >> 5;
    float s = 0.f;
    for (int m = half; m < LSEQ; m += 2)
        s = fmaf(al[h2 * LSEQ + m], bf2f(v[m * NODE + o]), s);
    __syncthreads();
    if (half) hp[o] = s;
    __syncthreads();
    if (!half) cat[(size_t)l * D1 + NH * PDIM + o] = s + hp[o];
}

// ---------------- LN over 1280, affine -> canon bf16 ----------------
__global__ __launch_bounds__(256) void k_ln1(
    const float* __restrict__ cat, const void* __restrict__ w,
    const void* __restrict__ b, uint16_t* __restrict__ outn,
    const int* __restrict__ dt)
{
    __shared__ float s1[256], s2[256];
    int bf = dt[0];
    int t = threadIdx.x, l = blockIdx.x;
    const float* row = cat + (size_t)l * D1;
    float s = 0.f, ss = 0.f;
    for (int i = t; i < D1; i += 256) { float v = row[i]; s += v; ss = fmaf(v, v, ss); }
    s1[t] = s; s2[t] = ss;
    block_reduce2_256(s1, s2, t);
    float m = s1[0] / (float)D1;
    float rstd = rsqrtf(fmaxf(s2[0] / (float)D1 - m * m, 0.f) + 1e-5f);
    for (int i = t; i < D1; i += 256)
        outn[(size_t)l * D1 + i] = f2bf((row[i] - m) * rstd * ld(w, i, bf) + ld(b, i, bf));
}

// ---------------- LN over 512, affine, leaky -> canon bf16 ----------------
__global__ __launch_bounds__(256) void k_ln2(
    const float* __restrict__ in, const void* __restrict__ w,
    const void* __restrict__ b, uint16_t* __restrict__ outn,
    const int* __restrict__ dt)
{
    __shared__ float s1[256], s2[256];
    int bf = dt[0];
    int t = threadIdx.x, l = blockIdx.x;
    const float* row = in + (size_t)l * D2;
    float v0 = row[t], v1 = row[t + 256];
    s1[t] = v0 + v1; s2[t] = v0 * v0 + v1 * v1;
    block_reduce2_256(s1, s2, t);
    float m = s1[0] / (float)D2;
    float rstd = rsqrtf(fmaxf(s2[0] / (float)D2 - m * m, 0.f) + 1e-5f);
    float o0 = (v0 - m) * rstd * ld(w, t, bf) + ld(b, t, bf);
    float o1 = (v1 - m) * rstd * ld(w, t + 256, bf) + ld(b, t + 256, bf);
    outn[(size_t)l * D2 + t]       = f2bf(o0 >= 0.f ? o0 : 0.01f * o0);
    outn[(size_t)l * D2 + t + 256] = f2bf(o1 >= 0.f ? o1 : 0.01f * o1);
}

// ---------------- partial stats over z channels (2-way row split) ----------------
__global__ __launch_bounds__(256) void k_pstat(
    const void* __restrict__ z, float* __restrict__ psum, float* __restrict__ psumsq,
    const int* __restrict__ dt)
{
    __shared__ float sa[128], sb[128];
    int bf = dt[0];
    int t = threadIdx.x;
    int ch = t & 127, half = t >> 7;
    size_t r0 = (size_t)blockIdx.x * 256;
    float s = 0.f, ss = 0.f;
    for (int i = 0; i < 128; ++i) {
        float v = ld(z, (r0 + half + 2 * i) * PDIM + ch, bf);
        s += v; ss = fmaf(v, v, ss);
    }
    if (half) { sa[ch] = s; sb[ch] = ss; }
    __syncthreads();
    if (!half) {
        psum[blockIdx.x * PDIM + ch] = s + sa[ch];
        psumsq[blockIdx.x * PDIM + ch] = ss + sb[ch];
    }
}

__global__ __launch_bounds__(512) void k_finP(
    const float* __restrict__ psum, const float* __restrict__ psumsq,
    float* __restrict__ meanP, float* __restrict__ rstdP)
{
    __shared__ float s1[512], s2[512];
    int t = threadIdx.x;
    int c = t & 127, seg = t >> 7;
    float s = 0.f, ss = 0.f;
    for (int b = seg * 144; b < seg * 144 + 144; ++b) {
        s += psum[b * PDIM + c]; ss += psumsq[b * PDIM + c];
    }
    s1[t] = s; s2[t] = ss;
    __syncthreads();
    if (t < 128) {
        float S  = s1[t] + s1[t + 128] + s1[t + 256] + s1[t + 384];
        float SS = s2[t] + s2[t + 128] + s2[t + 256] + s2[t + 384];
        float m = S / (float)LL;
        float var = SS / (float)LL - m * m;
        meanP[t] = m; rstdP[t] = rsqrtf(fmaxf(var, 0.f) + 1e-5f);
    }
}

// ---------------- weight pre-transform for MFMA conv_p ----------------
// wp OIHW (128 oc, 136 ic, 3, 3) -> wt[tap][oc][144] bf16, ic 136..143 = 0
__global__ __launch_bounds__(64) void k_wprep(
    const void* __restrict__ wp, uint16_t* __restrict__ wt, const int* __restrict__ dt)
{
    int bf = dt[0];
    int oc = blockIdx.x, tap = blockIdx.y;
    for (int ic = threadIdx.x; ic < 144; ic += 64) {
        float v = (ic < 136) ? ld(wp, (size_t)oc * 1224 + (size_t)ic * 9 + tap, bf) : 0.f;
        wt[((size_t)tap * 128 + oc) * 144 + ic] = f2bf(v);
    }
}

// ---------------- conv_p via MFMA implicit GEMM, v2 ----------------
// Block: 128 px (4 rows x 32 cols) x 128 oc, 512 thr / 8 waves.
// Wave w: row r = w>>2... (r = w>>1 over 4 rows), oc base 64*(w&1).
// Double-buffered Ws + reg-staged async weight prefetch -> 1 barrier per tap.
// LDS: As 6x34x144 (58752 B) + Ws[2][128*144] (73728 B) + stats (1088 B) = 133.6 KB.
__global__ __launch_bounds__(512, 1) void k_conv_p_mfma(
    const void* __restrict__ z, const uint16_t* __restrict__ a2,
    const uint16_t* __restrict__ wt, const void* __restrict__ bp,
    const float* __restrict__ meanP, const float* __restrict__ rstdP,
    void* __restrict__ out, const int* __restrict__ dt)
{
    __shared__ __align__(16) uint16_t As[6 * 34 * 144];     // 58752 B
    __shared__ __align__(16) uint16_t Ws[2][128 * 144];     // 73728 B
    __shared__ float mloc[136], rloc[136];

    int bf = dt[0];
    int t = threadIdx.x;
    int m0 = blockIdx.x * 32, l0 = blockIdx.y * 4;

    if (t < 136) { mloc[t] = meanP[t]; rloc[t] = rstdP[t]; }
    __syncthreads();

    // ---- stage normalized input halo: 6 rows x 34 cols x 144 ch (bf16) ----
    for (int grp = t; grp < 3672; grp += 512) {             // 8-elem groups
        int pixidx = grp / 18;
        int icg = (grp - pixidx * 18) * 8;
        int lr = pixidx / 34, lc = pixidx - lr * 34;
        int li = l0 - 1 + lr, mi = m0 - 1 + lc;
        uint16_t vals[8];
        if (li < 0 || li >= LSEQ || mi < 0 || mi >= LSEQ || icg >= 136) {
            #pragma unroll
            for (int j = 0; j < 8; ++j) vals[j] = 0;
        } else if (icg < 128) {
            size_t zoff = ((size_t)li * LSEQ + mi) * PDIM + icg;
            if (bf) {
                const uint16_t* zp = (const uint16_t*)z + zoff;
                #pragma unroll
                for (int j = 0; j < 8; ++j)
                    vals[j] = f2bf((bf2f(zp[j]) - mloc[icg + j]) * rloc[icg + j]);
            } else {
                const float* zp = (const float*)z + zoff;
                #pragma unroll
                for (int j = 0; j < 8; ++j)
                    vals[j] = f2bf((zp[j] - mloc[icg + j]) * rloc[icg + j]);
            }
        } else {  // icg == 128: channels 128..135 from a2 (channel-major bf16)
            size_t poff = (size_t)li * LSEQ + mi;
            #pragma unroll
            for (int j = 0; j < 8; ++j)
                vals[j] = f2bf((bf2f(a2[(size_t)j * LL + poff]) - mloc[128 + j]) * rloc[128 + j]);
        }
        *(uint4*)&As[pixidx * 144 + icg] = *(const uint4*)vals;
    }
    // stage tap-0 weights
    {
        const uint4* wsrc = (const uint4*)wt;
        uint4* wdst = (uint4*)Ws[0];
        for (int i = t; i < 2304; i += 512) wdst[i] = wsrc[i];
    }
    __syncthreads();

    int w = t >> 6, lane = t & 63;
    int p = lane & 15, g = lane >> 4;
    int r = w >> 1;             // output row 0..3
    int ocb = (w & 1) * 64;     // oc base for this wave
    int bb0 = (ocb + p) * 144 + 8 * g;

    f32x4 acc0[4], acc1[4];
    #pragma unroll
    for (int n = 0; n < 4; ++n) {
        acc0[n] = (f32x4){0.f, 0.f, 0.f, 0.f};
        acc1[n] = (f32x4){0.f, 0.f, 0.f, 0.f};
    }
    bf16x8 bz = bf16x8_zero();

    for (int tap = 0; tap < 9; ++tap) {
        int cur = tap & 1;
        uint4 wreg[5];
        if (tap < 8) {   // async prefetch of next tap's weights into regs
            const uint4* wsrc = (const uint4*)(wt + (size_t)(tap + 1) * 18432);
            #pragma unroll
            for (int j = 0; j < 4; ++j) wreg[j] = wsrc[t + 512 * j];
            if (t < 256) wreg[4] = wsrc[2048 + t];
        }

        int tr = tap / 3, tc = tap - tr * 3;
        int abase = ((r + tr) * 34 + p + tc) * 144 + 8 * g;
        const uint16_t* Wc = Ws[cur];

        #pragma unroll
        for (int ch = 0; ch < 5; ++ch) {
            const int ic0 = (ch < 4) ? ch * 32 : 112;
            bf16x8 a0 = *(const bf16x8*)&As[abase + ic0];
            bf16x8 a1 = *(const bf16x8*)&As[abase + 2304 + ic0];
            #pragma unroll
            for (int n = 0; n < 4; ++n) {
                bf16x8 bq;
                if (ch < 4) {
                    bq = *(const bf16x8*)&Wc[bb0 + n * 2304 + ic0];
                } else {
                    bq = bz;
                    if (g == 2) bq = *(const bf16x8*)&Wc[bb0 + n * 2304 + 112];
                }
                acc0[n] = __builtin_amdgcn_mfma_f32_16x16x32_bf16(a0, bq, acc0[n], 0, 0, 0);
                acc1[n] = __builtin_amdgcn_mfma_f32_16x16x32_bf16(a1, bq, acc1[n], 0, 0, 0);
            }
        }

        if (tap < 8) {   // write prefetched weights into the alternate buffer
            uint4* wdst = (uint4*)Ws[cur ^ 1];
            #pragma unroll
            for (int j = 0; j < 4; ++j) wdst[t + 512 * j] = wreg[j];
            if (t < 256) wdst[2048 + t] = wreg[4];
        }
        __syncthreads();
    }

    // ---- epilogue: bias + leaky + store ----
    int l = l0 + r;
    #pragma unroll
    for (int n = 0; n < 4; ++n) {
        int oc = ocb + 16 * n + p;
        float bb = ld(bp, oc, bf);
        #pragma unroll
        for (int reg = 0; reg < 4; ++reg) {
            int pc = 4 * g + reg;
            float v0 = acc0[n][reg] + bb; v0 = v0 >= 0.f ? v0 : 0.01f * v0;
            stout(out, 98304 + ((size_t)l * LSEQ + (m0 + pc)) * PDIM + oc, v0, bf);
            float v1 = acc1[n][reg] + bb; v1 = v1 >= 0.f ? v1 : 0.01f * v1;
            stout(out, 98304 + ((size_t)l * LSEQ + (m0 + 16 + pc)) * PDIM + oc, v1, bf);
        }
    }
}

// ---------------- conv_p fallback: f32 VALU path (used if workspace too small) ----------------
__global__ __launch_bounds__(128) void k_conv_p(
    const void* __restrict__ z, const uint16_t* __restrict__ a2,
    const void* __restrict__ wp, const void* __restrict__ bp,
    const float* __restrict__ meanP, const float* __restrict__ rstdP,
    void* __restrict__ out, const int* __restrict__ dt)
{
    __shared__ __align__(16) float wlds[128 * 76];
    __shared__ __align__(16) float inl[4 * 18 * 8];
    int bf = dt[0];
    int t = threadIdx.x;
    int m0 = blockIdx.x * 16, l0 = blockIdx.y * 2;
    float acc0[16], acc1[16];
    #pragma unroll
    for (int i = 0; i < 16; ++i) { acc0[i] = 0.f; acc1[i] = 0.f; }

    for (int ic0 = 0; ic0 < 136; ic0 += 8) {
        __syncthreads();
        for (int i = t; i < 128 * 72; i += 128) {
            int op = i / 72, r = i % 72;
            int cc = r / 9, tap = r % 9;
            wlds[op * 76 + tap * 8 + cc] = ld(wp, op * 1224 + (ic0 + cc) * 9 + tap, bf);
        }
        for (int i = t; i < 4 * 18 * 8; i += 128) {
            int rr = i / 144, rem = i % 144;
            int col = rem >> 3, cc = rem & 7;
            int li = l0 - 1 + rr, mi = m0 - 1 + col, ic = ic0 + cc;
            float vv = 0.f;
            if (li >= 0 && li < LSEQ && mi >= 0 && mi < LSEQ) {
                float raw = (ic < PDIM) ? ld(z, ((size_t)li * LSEQ + mi) * PDIM + ic, bf)
                                        : bf2f(a2[(size_t)(ic - PDIM) * LL + li * LSEQ + mi]);
                vv = (raw - meanP[ic]) * rstdP[ic];
            }
            inl[i] = vv;
        }
        __syncthreads();
        #pragma unroll
        for (int qd = 0; qd < 2; ++qd) {
            float4 wq[9];
            #pragma unroll
            for (int tap = 0; tap < 9; ++tap)
                wq[tap] = *(const float4*)&wlds[t * 76 + tap * 8 + qd * 4];
            float4 win[4][3];
            #pragma unroll
            for (int r = 0; r < 4; ++r) {
                win[r][1] = *(const float4*)&inl[(r * 18 + 0) * 8 + qd * 4];
                win[r][2] = *(const float4*)&inl[(r * 18 + 1) * 8 + qd * 4];
                win[r][0] = win[r][1];
            }
            #pragma unroll
            for (int pix = 0; pix < 16; ++pix) {
                #pragma unroll
                for (int r = 0; r < 4; ++r) {
                    win[r][0] = win[r][1];
                    win[r][1] = win[r][2];
                    win[r][2] = *(const float4*)&inl[(r * 18 + pix + 2) * 8 + qd * 4];
                }
                float p0x = 0.f, p0y = 0.f, p0z = 0.f, p0w = 0.f;
                float p1x = 0.f, p1y = 0.f, p1z = 0.f, p1w = 0.f;
                #pragma unroll
                for (int tr = 0; tr < 3; ++tr) {
                    #pragma unroll
                    for (int c = 0; c < 3; ++c) {
                        float4 w4 = wq[tr * 3 + c];
                        float4 u0 = win[tr][c];
                        float4 u1 = win[tr + 1][c];
                        p0x = fmaf(w4.x, u0.x, p0x); p0y = fmaf(w4.y, u0.y, p0y);
                        p0z = fmaf(w4.z, u0.z, p0z); p0w = fmaf(w4.w, u0.w, p0w);
                        p1x = fmaf(w4.x, u1.x, p1x); p1y = fmaf(w4.y, u1.y, p1y);
                        p1z = fmaf(w4.z, u1.z, p1z); p1w = fmaf(w4.w, u1.w, p1w);
                    }
                }
                acc0[pix] += (p0x + p0y) + (p0z + p0w);
                acc1[pix] += (p1x + p1y) + (p1z + p1w);
            }
        }
    }
    float bb = ld(bp, t, bf);
    #pragma unroll
    for (int pix = 0; pix < 16; ++pix) {
        float v0 = acc0[pix] + bb; v0 = v0 >= 0.f ? v0 : 0.01f * v0;
        stout(out, 98304 + ((size_t)l0 * LSEQ + m0 + pix) * PDIM + t, v0, bf);
        float v1 = acc1[pix] + bb; v1 = v1 >= 0.f ? v1 : 0.01f * v1;
        stout(out, 98304 + ((size_t)(l0 + 1) * LSEQ + m0 + pix) * PDIM + t, v1, bf);
    }
}

extern "C" void kernel_launch(void* const* d_in, const int* in_sizes, int n_in,
                              void* d_out, int out_size, void* d_ws, size_t ws_size,
                              hipStream_t stream)
{
    const void* x     = d_in[0];
    const void* z     = d_in[1];
    const void* plddt = d_in[2];
    const void* Wq    = d_in[3];
    const void* Wk    = d_in[4];
    const void* Wv    = d_in[5];
    const void* Wp2a  = d_in[6];
    const void* caw   = d_in[7];
    const void* cab   = d_in[8];
    const void* cmw   = d_in[9];
    const void* cmb   = d_in[10];
    const void* ln1w  = d_in[11];
    const void* ln1b  = d_in[12];
    const void* l1w   = d_in[13];
    const void* l1b   = d_in[14];
    const void* ln2w  = d_in[15];
    const void* ln2b  = d_in[16];
    const void* l2w   = d_in[17];
    const void* l2b   = d_in[18];
    const void* lnfw  = d_in[19];
    const void* lnfb  = d_in[20];
    const void* cpw   = d_in[21];
    const void* cpb   = d_in[22];

    // Scratch in d_out's z_new region (fully overwritten by the final writers
    // in either dtype mode; all overlays dead before their region is clobbered).
    uint16_t* O = (uint16_t*)d_out;
    uint16_t* acat = O + 98304;               // 16*LL bf16
    uint16_t* a1b  = O + 2457600;             // 8*LL bf16 (pre-conv_a: q,k)
    uint16_t* qb   = a1b;
    uint16_t* kb   = a1b + 98304;
    uint16_t* vb   = O + 3637248;
    float*    cat  = (float*)(O + 3735552);   // 384x1280 f32
    float*    h1   = (float*)(O + 5701632);   // 384x512 f32
    float*    psum = (float*)(O + 6488064);
    float*    psumsq = (float*)(O + 6635520); // ends 6782976
    uint16_t* cb   = O + 6782976;             // 384x1280 bf16 (LN1 out)
    uint16_t* h1nb = O + 7274496;             // 384x512 bf16 (LN2 out)
    uint16_t* xb   = O + 7471104;             // 384x256 bf16
    uint16_t* wtq  = O + 7569408;             // 768x256 bf16 (Wq|Wk|Wv, n-major)
    uint16_t* wt1  = O + 7766016;             // 512x1280 bf16 (lin1, n-major)
    uint16_t* wt2  = O + 8421376;             // 256x512 bf16 (lin2, n-major)

    uint16_t* U = (uint16_t*)d_ws;
    uint16_t* a2b = U;                        // 8*LL bf16, live into conv_p
    float*    st  = (float*)(U + 1179648);    // stats, live into conv_p
    float* m16 = st;        float* r16 = st + 16;
    float* m9  = st + 32;   float* r9  = st + 48;
    float* mP  = st + 64;   float* rP  = st + 200;   // 136 each
    int*   flg = (int*)(U + 1181696);         // dtype flag
    uint16_t* wt = U + 1182720;               // 9*128*144 bf16 = 331776 B (conv_p MFMA weights)
    int use_mfma = (ws_size >= (size_t)2365440 + 331776);

    k_detect<<<1, 64, 0, stream>>>((const uint32_t*)z, flg);
    // prep: canon-bf16 x and n-major bf16 weights for the MFMA GEMMs
    k_cvt<<<384, 256, 0, stream>>>(x, xb, flg);
    k_wnk<<<dim3(8, 8), 256, 0, stream>>>(Wq, wtq,          256, 256, flg);
    k_wnk<<<dim3(8, 8), 256, 0, stream>>>(Wk, wtq +  65536, 256, 256, flg);
    k_wnk<<<dim3(8, 8), 256, 0, stream>>>(Wv, wtq + 131072, 256, 256, flg);
    k_wnk<<<dim3(40, 16), 256, 0, stream>>>(l1w, wt1, 1280, 512, flg);
    k_wnk<<<dim3(16, 8), 256, 0, stream>>>(l2w, wt2,  512, 256, flg);

    k_gemm_qkv<<<dim3(6, 12), 256, 0, stream>>>(xb, wtq, qb, kb, vb);
    k_apair <<<dim3(12, LSEQ), 256, 0, stream>>>(z, Wp2a, acat, flg);
    k_anode <<<dim3(12, LSEQ), 256, 0, stream>>>(qb, kb, acat);
    // stats over acat (16 ch)
    k_scp<<<dim3(18, 16), 256, 0, stream>>>(acat, plddt, psum, psumsq, flg, 16);
    k_scf<<<1, 16, 0, stream>>>(psum, psumsq, m16, r16, 16);
    k_conv_a<<<dim3(3, LSEQ, 8), 128, 0, stream>>>(acat, caw, cab, m16, r16, a1b, flg);
    // stats over a1b (8 ch) + plddt (tail channel 8) in one pass
    k_scp<<<dim3(18, 9), 256, 0, stream>>>(a1b, plddt, psum, psumsq, flg, 8);
    k_scf<<<1, 9, 0, stream>>>(psum, psumsq, m9, r9, 9);
    k_conv_m<<<dim3(3, LSEQ, 8), 128, 0, stream>>>(a1b, plddt, cmw, cmb, m9, r9, a2b, flg);
    k_agg   <<<LSEQ, 512, 0, stream>>>(a2b, vb, z, cat, flg);
    k_ln1   <<<LSEQ, 256, 0, stream>>>(cat, ln1w, ln1b, cb, flg);
    k_gemm_bias_f32<<<dim3(6, 8), 256, 0, stream>>>(cb, wt1, l1b, h1, 1280, 512, flg);
    k_ln2   <<<LSEQ, 256, 0, stream>>>(h1, ln2w, ln2b, h1nb, flg);
    k_lin2lnf_mfma<<<12, 256, 0, stream>>>(h1nb, wt2, l2b, x, lnfw, lnfb, d_out, flg);
    // stats over a2b (8 ch)
    k_scp<<<dim3(18, 8), 256, 0, stream>>>(a2b, plddt, psum, psumsq, flg, 8);
    k_scf<<<1, 8, 0, stream>>>(psum, psumsq, mP + 128, rP + 128, 8);
    k_pstat <<<576, 256, 0, stream>>>(z, psum, psumsq, flg);
    k_finP  <<<1, 512, 0, stream>>>(psum, psumsq, mP, rP);
    if (use_mfma) {
        k_wprep<<<dim3(128, 9), 64, 0, stream>>>(cpw, wt, flg);
        k_conv_p_mfma<<<dim3(12, 96), 512, 0, stream>>>(z, a2b, wt, cpb, mP, rP, d_out, flg);
    } else {
        k_conv_p<<<dim3(24, 192), 128, 0, stream>>>(z, a2b, cpw, cpb, mP, rP, d_out, flg);
    }
}

// Round 5
// 579.860 us; speedup vs baseline: 1.0710x; 1.0710x over previous
//
#include <hip/hip_runtime.h>
#include <stdint.h>

#define LSEQ 384
#define LL   147456   // 384*384
#define NODE 256
#define NH   8
#define HD   32
#define PDIM 128
#define D1   1280
#define D2   512

typedef __attribute__((ext_vector_type(8))) short s16x8;
typedef __attribute__((ext_vector_type(8))) __bf16 bf16x8;
typedef __attribute__((ext_vector_type(4))) float f32x4;

__device__ __forceinline__ float bf2f(uint16_t u) {
    union { uint32_t i; float f; } x; x.i = ((uint32_t)u) << 16; return x.f;
}
__device__ __forceinline__ uint16_t f2bf(float f) {
    uint32_t b = __float_as_uint(f);
    return (uint16_t)((b + 0x7FFFu + ((b >> 16) & 1u)) >> 16);
}
// dtype-adaptive input load: element index i, bf=1 -> bf16, bf=0 -> f32
__device__ __forceinline__ float ld(const void* p, size_t i, int bf) {
    return bf ? bf2f(((const uint16_t*)p)[i]) : ((const float*)p)[i];
}
// dtype-adaptive output store
__device__ __forceinline__ void stout(void* p, size_t i, float v, int bf) {
    if (bf) ((uint16_t*)p)[i] = f2bf(v);
    else    ((float*)p)[i] = v;
}

__device__ __forceinline__ bf16x8 bf16x8_zero() {
    union { s16x8 s; bf16x8 b; } u; u.s = (s16x8)0; return u.b;
}

__device__ __forceinline__ void block_reduce2_256(float* s1, float* s2, int t) {
    __syncthreads();
    for (int o = 128; o > 0; o >>= 1) {
        if (t < o) { s1[t] += s1[t + o]; s2[t] += s2[t + o]; }
        __syncthreads();
    }
}

// accumulate 8 bf16 packed in a uint4 into sum / sumsq
__device__ __forceinline__ void acc8(uint4 u, float& s, float& ss) {
    uint32_t w[4] = { u.x, u.y, u.z, u.w };
    #pragma unroll
    for (int i = 0; i < 4; ++i) {
        float a = bf2f((uint16_t)(w[i] & 0xFFFFu));
        float b = bf2f((uint16_t)(w[i] >> 16));
        s += a + b;
        ss = fmaf(a, a, ss);
        ss = fmaf(b, b, ss);
    }
}

// ---------------- dtype detection: sample low u16 halves of z ----------------
__global__ void k_detect(const uint32_t* __restrict__ zz, int* __restrict__ flag) {
    if (threadIdx.x == 0 && blockIdx.x == 0) {
        int cnt = 0;
        for (int i = 0; i < 256; ++i) {
            uint32_t lo = zz[i] & 0xFFFFu;
            uint32_t e = (lo >> 7) & 0xFFu;
            if (lo == 0u || (e >= 96u && e <= 142u)) ++cnt;
        }
        flag[0] = (cnt >= 192) ? 1 : 0;   // 1 = inputs are bf16, 0 = f32
    }
}

// ---------------- convert to canon bf16 (identity roundtrip in bf16 mode) ----------------
__global__ __launch_bounds__(256) void k_cvt(
    const void* __restrict__ src, uint16_t* __restrict__ dst, const int* __restrict__ dt)
{
    int bf = dt[0];
    int i = blockIdx.x * 256 + threadIdx.x;
    dst[i] = f2bf(ld(src, i, bf));
}

// ---------------- weight transpose K-major -> N-major bf16 via 32x32 LDS tiles ----------
__global__ __launch_bounds__(256) void k_wnk(
    const void* __restrict__ src, uint16_t* __restrict__ dst, int K, int N,
    const int* __restrict__ dt)
{
    __shared__ float tile[32][33];
    int bf = dt[0];
    int k0 = blockIdx.x * 32, n0 = blockIdx.y * 32;
    int tr = threadIdx.x >> 5, tc = threadIdx.x & 31;
    #pragma unroll
    for (int i = 0; i < 4; ++i)
        tile[tr + i * 8][tc] = ld(src, (size_t)(k0 + tr + i * 8) * N + n0 + tc, bf);
    __syncthreads();
    #pragma unroll
    for (int i = 0; i < 4; ++i)
        dst[(size_t)(n0 + tr + i * 8) * K + k0 + tc] = f2bf(tile[tc][tr + i * 8]);
}

// ---------------- generic 64x64-tile MFMA GEMM: out f32 = A @ B^T + bias ----------------
__global__ __launch_bounds__(256) void k_gemm_bias_f32(
    const uint16_t* __restrict__ A, const uint16_t* __restrict__ B,
    const void* __restrict__ bias, float* __restrict__ out, int K, int N,
    const int* __restrict__ dt)
{
    __shared__ __align__(16) uint16_t As[64 * 72];
    __shared__ __align__(16) uint16_t Bs[64 * 72];
    int bf = dt[0];
    int t = threadIdx.x;
    int row0 = blockIdx.x * 64, col0 = blockIdx.y * 64;
    int w = t >> 6, lane = t & 63, p = lane & 15, g = lane >> 4;
    int wm = w >> 1, wn = w & 1;
    f32x4 acc[2][2];
    #pragma unroll
    for (int i = 0; i < 2; ++i)
        #pragma unroll
        for (int j = 0; j < 2; ++j) acc[i][j] = (f32x4){0.f, 0.f, 0.f, 0.f};

    for (int kc = 0; kc < K; kc += 64) {
        __syncthreads();
        #pragma unroll
        for (int rep = 0; rep < 2; ++rep) {
            int i = t + rep * 256;
            int r = i >> 3, c8 = (i & 7) * 8;
            *(uint4*)&As[r * 72 + c8] = *(const uint4*)&A[(size_t)(row0 + r) * K + kc + c8];
            *(uint4*)&Bs[r * 72 + c8] = *(const uint4*)&B[(size_t)(col0 + r) * K + kc + c8];
        }
        __syncthreads();
        #pragma unroll
        for (int kk = 0; kk < 64; kk += 32) {
            bf16x8 a0 = *(const bf16x8*)&As[(wm * 32 + p) * 72 + kk + 8 * g];
            bf16x8 a1 = *(const bf16x8*)&As[(wm * 32 + 16 + p) * 72 + kk + 8 * g];
            bf16x8 b0 = *(const bf16x8*)&Bs[(wn * 32 + p) * 72 + kk + 8 * g];
            bf16x8 b1 = *(const bf16x8*)&Bs[(wn * 32 + 16 + p) * 72 + kk + 8 * g];
            acc[0][0] = __builtin_amdgcn_mfma_f32_16x16x32_bf16(a0, b0, acc[0][0], 0, 0, 0);
            acc[0][1] = __builtin_amdgcn_mfma_f32_16x16x32_bf16(a0, b1, acc[0][1], 0, 0, 0);
            acc[1][0] = __builtin_amdgcn_mfma_f32_16x16x32_bf16(a1, b0, acc[1][0], 0, 0, 0);
            acc[1][1] = __builtin_amdgcn_mfma_f32_16x16x32_bf16(a1, b1, acc[1][1], 0, 0, 0);
        }
    }
    #pragma unroll
    for (int mi = 0; mi < 2; ++mi)
        #pragma unroll
        for (int ni = 0; ni < 2; ++ni) {
            int n = col0 + wn * 32 + ni * 16 + p;
            float bb = ld(bias, n, bf);
            #pragma unroll
            for (int reg = 0; reg < 4; ++reg) {
                int m = row0 + wm * 32 + mi * 16 + 4 * g + reg;
                out[(size_t)m * N + n] = acc[mi][ni][reg] + bb;
            }
        }
}

// ---------------- q,k,v GEMM: [384x768x256] = xb @ [Wq|Wk|Wv]^T -> canon bf16 ----------------
__global__ __launch_bounds__(256) void k_gemm_qkv(
    const uint16_t* __restrict__ A, const uint16_t* __restrict__ B,
    uint16_t* __restrict__ q, uint16_t* __restrict__ k, uint16_t* __restrict__ v)
{
    __shared__ __align__(16) uint16_t As[64 * 72];
    __shared__ __align__(16) uint16_t Bs[64 * 72];
    const int K = 256;
    int t = threadIdx.x;
    int row0 = blockIdx.x * 64, col0 = blockIdx.y * 64;
    int w = t >> 6, lane = t & 63, p = lane & 15, g = lane >> 4;
    int wm = w >> 1, wn = w & 1;
    f32x4 acc[2][2];
    #pragma unroll
    for (int i = 0; i < 2; ++i)
        #pragma unroll
        for (int j = 0; j < 2; ++j) acc[i][j] = (f32x4){0.f, 0.f, 0.f, 0.f};

    for (int kc = 0; kc < K; kc += 64) {
        __syncthreads();
        #pragma unroll
        for (int rep = 0; rep < 2; ++rep) {
            int i = t + rep * 256;
            int r = i >> 3, c8 = (i & 7) * 8;
            *(uint4*)&As[r * 72 + c8] = *(const uint4*)&A[(size_t)(row0 + r) * K + kc + c8];
            *(uint4*)&Bs[r * 72 + c8] = *(const uint4*)&B[(size_t)(col0 + r) * K + kc + c8];
        }
        __syncthreads();
        #pragma unroll
        for (int kk = 0; kk < 64; kk += 32) {
            bf16x8 a0 = *(const bf16x8*)&As[(wm * 32 + p) * 72 + kk + 8 * g];
            bf16x8 a1 = *(const bf16x8*)&As[(wm * 32 + 16 + p) * 72 + kk + 8 * g];
            bf16x8 b0 = *(const bf16x8*)&Bs[(wn * 32 + p) * 72 + kk + 8 * g];
            bf16x8 b1 = *(const bf16x8*)&Bs[(wn * 32 + 16 + p) * 72 + kk + 8 * g];
            acc[0][0] = __builtin_amdgcn_mfma_f32_16x16x32_bf16(a0, b0, acc[0][0], 0, 0, 0);
            acc[0][1] = __builtin_amdgcn_mfma_f32_16x16x32_bf16(a0, b1, acc[0][1], 0, 0, 0);
            acc[1][0] = __builtin_amdgcn_mfma_f32_16x16x32_bf16(a1, b0, acc[1][0], 0, 0, 0);
            acc[1][1] = __builtin_amdgcn_mfma_f32_16x16x32_bf16(a1, b1, acc[1][1], 0, 0, 0);
        }
    }
    #pragma unroll
    for (int mi = 0; mi < 2; ++mi)
        #pragma unroll
        for (int ni = 0; ni < 2; ++ni) {
            int nglob = col0 + wn * 32 + ni * 16 + p;
            int sel = nglob >> 8, col = nglob & 255;
            uint16_t* dst = (sel == 0) ? q : (sel == 1) ? k : v;
            #pragma unroll
            for (int reg = 0; reg < 4; ++reg) {
                int m = row0 + wm * 32 + mi * 16 + 4 * g + reg;
                dst[(size_t)m * 256 + col] = f2bf(acc[mi][ni][reg]);
            }
        }
}

// ---------------- lin2 + bias + residual + final LN, fused MFMA ----------------
__global__ __launch_bounds__(256) void k_lin2lnf_mfma(
    const uint16_t* __restrict__ A, const uint16_t* __restrict__ B,
    const void* __restrict__ bias, const void* __restrict__ x,
    const void* __restrict__ lnw, const void* __restrict__ lnb,
    void* __restrict__ out, const int* __restrict__ dt)
{
    __shared__ __align__(16) uint16_t As[32 * 72];
    __shared__ __align__(16) uint16_t Bs[256 * 72];
    const int K = 512;
    int bf = dt[0];
    int t = threadIdx.x;
    int row0 = blockIdx.x * 32;
    int w = t >> 6, lane = t & 63, p = lane & 15, g = lane >> 4;
    f32x4 acc[2][4];
    #pragma unroll
    for (int i = 0; i < 2; ++i)
        #pragma unroll
        for (int j = 0; j < 4; ++j) acc[i][j] = (f32x4){0.f, 0.f, 0.f, 0.f};

    for (int kc = 0; kc < K; kc += 64) {
        __syncthreads();
        {   // A: 32x64 = 256 uint4 groups
            int r = t >> 3, c8 = (t & 7) * 8;
            *(uint4*)&As[r * 72 + c8] = *(const uint4*)&A[(size_t)(row0 + r) * K + kc + c8];
        }
        #pragma unroll
        for (int rep = 0; rep < 8; ++rep) {   // B: 256x64 = 2048 uint4 groups
            int i = t + rep * 256;
            int r = i >> 3, c8 = (i & 7) * 8;
            *(uint4*)&Bs[r * 72 + c8] = *(const uint4*)&B[(size_t)r * K + kc + c8];
        }
        __syncthreads();
        #pragma unroll
        for (int kk = 0; kk < 64; kk += 32) {
            bf16x8 a0 = *(const bf16x8*)&As[(p) * 72 + kk + 8 * g];
            bf16x8 a1 = *(const bf16x8*)&As[(16 + p) * 72 + kk + 8 * g];
            #pragma unroll
            for (int ni = 0; ni < 4; ++ni) {
                bf16x8 bq = *(const bf16x8*)&Bs[(w * 64 + ni * 16 + p) * 72 + kk + 8 * g];
                acc[0][ni] = __builtin_amdgcn_mfma_f32_16x16x32_bf16(a0, bq, acc[0][ni], 0, 0, 0);
                acc[1][ni] = __builtin_amdgcn_mfma_f32_16x16x32_bf16(a1, bq, acc[1][ni], 0, 0, 0);
            }
        }
    }
    __syncthreads();
    float* lnt = (float*)Bs;   // 32 x 264 f32 tile
    #pragma unroll
    for (int mi = 0; mi < 2; ++mi)
        #pragma unroll
        for (int ni = 0; ni < 4; ++ni) {
            int n = w * 64 + ni * 16 + p;
            float bb = ld(bias, n, bf);
            #pragma unroll
            for (int reg = 0; reg < 4; ++reg) {
                int m = mi * 16 + 4 * g + reg;
                lnt[m * 264 + n] = acc[mi][ni][reg] + bb + ld(x, (size_t)(row0 + m) * 256 + n, bf);
            }
        }
    __syncthreads();
    for (int rr = 0; rr < 8; ++rr) {
        int m = w * 8 + rr;
        float4 v4 = *(const float4*)&lnt[m * 264 + lane * 4];
        float vv[4] = { v4.x, v4.y, v4.z, v4.w };
        float s = (vv[0] + vv[1]) + (vv[2] + vv[3]);
        float ss = fmaf(vv[0], vv[0], fmaf(vv[1], vv[1], fmaf(vv[2], vv[2], vv[3] * vv[3])));
        #pragma unroll
        for (int off = 32; off > 0; off >>= 1) {
            s  += __shfl_xor(s, off);
            ss += __shfl_xor(ss, off);
        }
        float mean = s / 256.f;
        float rstd = rsqrtf(fmaxf(ss / 256.f - mean * mean, 0.f) + 1e-5f);
        #pragma unroll
        for (int i = 0; i < 4; ++i) {
            int c = lane * 4 + i;
            float val = (vv[i] - mean) * rstd * ld(lnw, c, bf) + ld(lnb, c, bf);
            stout(out, (size_t)(row0 + m) * 256 + c, val, bf);
        }
    }
}

// ---------------- a_pair = z @ Wp2a -> acat[h][l][m] (bf16) ----------------
__global__ __launch_bounds__(256) void k_apair(
    const void* __restrict__ z, const void* __restrict__ Wp2a,
    uint16_t* __restrict__ acat, const int* __restrict__ dt)
{
    __shared__ float zl[32 * 129];
    __shared__ float wp[PDIM * NH];
    int bf = dt[0];
    int t = threadIdx.x, m0 = blockIdx.x * 32, l = blockIdx.y;
    for (int i = t; i < PDIM * NH; i += 256) wp[i] = ld(Wp2a, i, bf);
    if (bf) {
        const uint16_t* zz = (const uint16_t*)z;
        for (int grp = t; grp < 512; grp += 256) {
            int ml = grp >> 4, p8 = (grp & 15) * 8;
            uint4 u = *(const uint4*)&zz[((size_t)(l * LSEQ + m0 + ml)) * PDIM + p8];
            const uint16_t* pu = (const uint16_t*)&u;
            #pragma unroll
            for (int j = 0; j < 8; ++j) zl[ml * 129 + p8 + j] = bf2f(pu[j]);
        }
    } else {
        const float* zz = (const float*)z;
        for (int grp = t; grp < 1024; grp += 256) {
            int ml = grp >> 5, p4 = (grp & 31) * 4;
            float4 u = *(const float4*)&zz[((size_t)(l * LSEQ + m0 + ml)) * PDIM + p4];
            zl[ml * 129 + p4 + 0] = u.x; zl[ml * 129 + p4 + 1] = u.y;
            zl[ml * 129 + p4 + 2] = u.z; zl[ml * 129 + p4 + 3] = u.w;
        }
    }
    __syncthreads();
    int h = t >> 5, ml = t & 31;
    float acc = 0.f;
    for (int p = 0; p < PDIM; ++p) acc = fmaf(zl[ml * 129 + p], wp[p * NH + h], acc);
    acat[(size_t)h * LL + l * LSEQ + m0 + ml] = f2bf(acc);
}

// ---------------- a_node = (q k^T)/sqrt(hd) -> acat[8+h][l][m] (bf16) ----------------
__global__ __launch_bounds__(256) void k_anode(
    const uint16_t* __restrict__ q, const uint16_t* __restrict__ k,
    uint16_t* __restrict__ acat)
{
    __shared__ float kl[NODE * 33];
    __shared__ float qr[NH * 33];
    int t = threadIdx.x, m0 = blockIdx.x * 32, l = blockIdx.y;
    for (int grp = t; grp < 1024; grp += 256) {   // 32 px x 256 ch, 8-elem groups
        int ml = grp >> 5, c8 = (grp & 31) * 8;
        uint4 u = *(const uint4*)&k[(size_t)(m0 + ml) * NODE + c8];
        const uint16_t* pu = (const uint16_t*)&u;
        #pragma unroll
        for (int j = 0; j < 8; ++j) kl[(c8 + j) * 33 + ml] = bf2f(pu[j]);
    }
    qr[(t >> 5) * 33 + (t & 31)] = bf2f(q[l * NODE + t]);
    __syncthreads();
    int h = t >> 5, ml = t & 31;
    float acc = 0.f;
    #pragma unroll 8
    for (int d = 0; d < HD; ++d)
        acc = fmaf(qr[h * 33 + d], kl[(h * HD + d) * 33 + ml], acc);
    acat[(size_t)(NH + h) * LL + l * LSEQ + m0 + ml] = f2bf(acc * 0.17677669529663687f);
}

// ---------------- unified stats partial: canon channels (+ optional raw tail ch) ------
__global__ __launch_bounds__(256) void k_scp(
    const uint16_t* __restrict__ src, const void* __restrict__ raw,
    float* __restrict__ ps, float* __restrict__ pss, const int* __restrict__ dt, int C)
{
    __shared__ float s1[256], s2[256];
    int c = blockIdx.y, chunk = blockIdx.x, t = threadIdx.x;
    float s = 0.f, ss = 0.f;
    if (c < C) {
        const uint16_t* p = src + (size_t)c * LL + (size_t)chunk * 8192;
        #pragma unroll
        for (int it = 0; it < 4; ++it) acc8(*(const uint4*)&p[(it * 256 + t) * 8], s, ss);
    } else if (dt[0]) {
        const uint4* p = (const uint4*)raw + (size_t)chunk * 1024;
        #pragma unroll
        for (int it = 0; it < 4; ++it) acc8(p[it * 256 + t], s, ss);
    } else {
        const float4* p = (const float4*)raw + (size_t)chunk * 2048;
        #pragma unroll
        for (int it = 0; it < 8; ++it) {
            float4 a = p[it * 256 + t];
            s += (a.x + a.y) + (a.z + a.w);
            ss = fmaf(a.x, a.x, fmaf(a.y, a.y, fmaf(a.z, a.z, fmaf(a.w, a.w, ss))));
        }
    }
    s1[t] = s; s2[t] = ss;
    block_reduce2_256(s1, s2, t);
    if (t == 0) { ps[c * 18 + chunk] = s1[0]; pss[c * 18 + chunk] = s2[0]; }
}

__global__ void k_scf(
    const float* __restrict__ ps, const float* __restrict__ pss,
    float* __restrict__ mean_out, float* __restrict__ rstd_out, int C)
{
    int t = threadIdx.x;
    if (t < C) {
        float s = 0.f, ss = 0.f;
        for (int i = 0; i < 18; ++i) { s += ps[t * 18 + i]; ss += pss[t * 18 + i]; }
        float m = s / (float)LL;
        float var = ss / (float)LL - m * m;
        mean_out[t] = m; rstd_out[t] = rsqrtf(fmaxf(var, 0.f) + 1e-5f);
    }
}

// ---------------- conv_a: 16 -> 8 channels, ALL oc per block ----------------
// weights LDS layout [tap][oc][ic] (float4-readable); 8 accumulators/thread.
__global__ __launch_bounds__(128) void k_conv_a(
    const uint16_t* __restrict__ acat, const void* __restrict__ wa,
    const void* __restrict__ ba, const float* __restrict__ mean,
    const float* __restrict__ rstd, uint16_t* __restrict__ out,
    const int* __restrict__ dt)
{
    __shared__ float wl[9 * 8 * 16];   // [tap][oc][ic], rstd folded
    __shared__ float ot[8 * 9];        // [oc][tap]
    int bf = dt[0];
    int t = threadIdx.x;
    int l = blockIdx.y, m = blockIdx.x * 128 + t;
    for (int i = t; i < 1152; i += 128) {
        int tap = i >> 7, rem = i & 127;
        int oc = rem >> 4, ic = rem & 15;
        wl[i] = ld(wa, (size_t)oc * 144 + ic * 9 + tap, bf) * rstd[ic];
    }
    __syncthreads();
    if (t < 72) {
        int oc = t / 9, tap = t - oc * 9;
        float s = 0.f;
        for (int ic = 0; ic < 16; ++ic) s = fmaf(mean[ic], wl[tap * 128 + oc * 16 + ic], s);
        ot[t] = s;
    }
    __syncthreads();
    float acc[8];
    #pragma unroll
    for (int oc = 0; oc < 8; ++oc) acc[oc] = ld(ba, oc, bf);
    #pragma unroll
    for (int r = 0; r < 3; ++r) {
        int li = l + r - 1;
        if (li < 0 || li >= LSEQ) continue;
        #pragma unroll
        for (int c = 0; c < 3; ++c) {
            int mi = m + c - 1;
            if (mi < 0 || mi >= LSEQ) continue;
            const uint16_t* ip = acat + li * LSEQ + mi;
            float v[16];
            #pragma unroll
            for (int ic = 0; ic < 16; ++ic) v[ic] = bf2f(ip[(size_t)ic * LL]);
            int tap = r * 3 + c;
            const float4* wq = (const float4*)&wl[tap * 128];
            #pragma unroll
            for (int oc = 0; oc < 8; ++oc) {
                float4 w0 = wq[oc * 4], w1 = wq[oc * 4 + 1], w2 = wq[oc * 4 + 2], w3 = wq[oc * 4 + 3];
                float a = acc[oc] - ot[oc * 9 + tap];
                a = fmaf(w0.x, v[0], a);  a = fmaf(w0.y, v[1], a);
                a = fmaf(w0.z, v[2], a);  a = fmaf(w0.w, v[3], a);
                a = fmaf(w1.x, v[4], a);  a = fmaf(w1.y, v[5], a);
                a = fmaf(w1.z, v[6], a);  a = fmaf(w1.w, v[7], a);
                a = fmaf(w2.x, v[8], a);  a = fmaf(w2.y, v[9], a);
                a = fmaf(w2.z, v[10], a); a = fmaf(w2.w, v[11], a);
                a = fmaf(w3.x, v[12], a); a = fmaf(w3.y, v[13], a);
                a = fmaf(w3.z, v[14], a); a = fmaf(w3.w, v[15], a);
                acc[oc] = a;
            }
        }
    }
    #pragma unroll
    for (int oc = 0; oc < 8; ++oc) {
        float a = acc[oc] >= 0.f ? acc[oc] : 0.01f * acc[oc];
        out[(size_t)oc * LL + l * LSEQ + m] = f2bf(a);
    }
}

// ---------------- conv_m: 9 -> 8 channels (8 canon bf16 + raw plddt), ALL oc/block ----
// weights LDS layout [tap][oc][12] (ic 0..7 = a1, ic 8 = plddt, 9..11 = 0)
__global__ __launch_bounds__(128) void k_conv_m(
    const uint16_t* __restrict__ a1, const void* __restrict__ plddt,
    const void* __restrict__ wm, const void* __restrict__ bm,
    const float* __restrict__ mean, const float* __restrict__ rstd,
    uint16_t* __restrict__ out, const int* __restrict__ dt)
{
    __shared__ float wl[9 * 8 * 12];
    __shared__ float ot[8 * 9];
    int bf = dt[0];
    int t = threadIdx.x;
    int l = blockIdx.y, m = blockIdx.x * 128 + t;
    for (int i = t; i < 864; i += 128) {
        int tap = i / 96, rem = i - tap * 96;
        int oc = rem / 12, ic = rem - oc * 12;
        wl[i] = (ic < 9) ? ld(wm, (size_t)oc * 81 + ic * 9 + tap, bf) * rstd[ic] : 0.f;
    }
    __syncthreads();
    if (t < 72) {
        int oc = t / 9, tap = t - oc * 9;
        float s = 0.f;
        for (int ic = 0; ic < 9; ++ic) s = fmaf(mean[ic], wl[tap * 96 + oc * 12 + ic], s);
        ot[t] = s;
    }
    __syncthreads();
    float acc[8];
    #pragma unroll
    for (int oc = 0; oc < 8; ++oc) acc[oc] = ld(bm, oc, bf);
    #pragma unroll
    for (int r = 0; r < 3; ++r) {
        int li = l + r - 1;
        if (li < 0 || li >= LSEQ) continue;
        #pragma unroll
        for (int c = 0; c < 3; ++c) {
            int mi = m + c - 1;
            if (mi < 0 || mi >= LSEQ) continue;
            int off = li * LSEQ + mi;
            float v[12];
            #pragma unroll
            for (int ic = 0; ic < 8; ++ic) v[ic] = bf2f(a1[(size_t)ic * LL + off]);
            v[8] = ld(plddt, off, bf); v[9] = 0.f; v[10] = 0.f; v[11] = 0.f;
            int tap = r * 3 + c;
            const float4* wq = (const float4*)&wl[tap * 96];
            #pragma unroll
            for (int oc = 0; oc < 8; ++oc) {
                float4 w0 = wq[oc * 3], w1 = wq[oc * 3 + 1], w2 = wq[oc * 3 + 2];
                float a = acc[oc] - ot[oc * 9 + tap];
                a = fmaf(w0.x, v[0], a); a = fmaf(w0.y, v[1], a);
                a = fmaf(w0.z, v[2], a); a = fmaf(w0.w, v[3], a);
                a = fmaf(w1.x, v[4], a); a = fmaf(w1.y, v[5], a);
                a = fmaf(w1.z, v[6], a); a = fmaf(w1.w, v[7], a);
                a = fmaf(w2.x, v[8], a);
                acc[oc] = a;
            }
        }
    }
    #pragma unroll
    for (int oc = 0; oc < 8; ++oc) {
        float a = acc[oc] >= 0.f ? acc[oc] : 0.01f * acc[oc];
        out[(size_t)oc * LL + l * LSEQ + m] = f2bf(a);
    }
}

// ---------------- aggregations: nfp + nfn -> cat (384 x 1280, f32) ----------------
__global__ __launch_bounds__(512) void k_agg(
    const uint16_t* __restrict__ a2, const uint16_t* __restrict__ v,
    const void* __restrict__ z, float* __restrict__ cat,
    const int* __restrict__ dt)
{
    __shared__ float al[NH * LSEQ];       // 12 KB
    __shared__ float hp[3 * NH * PDIM];   // 12 KB partials (reused for nfn)
    int bf = dt[0];
    int t = threadIdx.x, l = blockIdx.x;
    for (int i = t; i < NH * LSEQ; i += 512) {
        int h = i / LSEQ, m = i - h * LSEQ;
        al[i] = bf2f(a2[(size_t)h * LL + l * LSEQ + m]);
    }
    __syncthreads();
    int p = t & 127, qq = t >> 7;   // qq in 0..3
    float acc[NH];
    #pragma unroll
    for (int h = 0; h < NH; ++h) acc[h] = 0.f;
    size_t zrow = (size_t)l * LSEQ * PDIM;
    for (int m = qq; m < LSEQ; m += 4) {
        float zv = ld(z, zrow + (size_t)m * PDIM + p, bf);
        #pragma unroll
        for (int h = 0; h < NH; ++h) acc[h] = fmaf(al[h * LSEQ + m], zv, acc[h]);
    }
    if (qq) {
        #pragma unroll
        for (int h = 0; h < NH; ++h) hp[(qq - 1) * 1024 + h * PDIM + p] = acc[h];
    }
    __syncthreads();
    if (qq == 0) {
        #pragma unroll
        for (int h = 0; h < NH; ++h)
            cat[(size_t)l * D1 + h * PDIM + p] =
                acc[h] + hp[h * PDIM + p] + hp[1024 + h * PDIM + p] + hp[2048 + h * PDIM + p];
    }
    // nfn: 256 outputs, 2-way m split
    int o = t & 255, half = t >> 8;
    int h2 = o >> 5;
    float s = 0.f;
    for (int m = half; m < LSEQ; m += 2)
        s = fmaf(al[h2 * LSEQ + m], bf2f(v[m * NODE + o]), s);
    __syncthreads();
    if (half) hp[o] = s;
    __syncthreads();
    if (!half) cat[(size_t)l * D1 + NH * PDIM + o] = s + hp[o];
}

// ---------------- LN over 1280, affine -> canon bf16 ----------------
__global__ __launch_bounds__(256) void k_ln1(
    const float* __restrict__ cat, const void* __restrict__ w,
    const void* __restrict__ b, uint16_t* __restrict__ outn,
    const int* __restrict__ dt)
{
    __shared__ float s1[256], s2[256];
    int bf = dt[0];
    int t = threadIdx.x, l = blockIdx.x;
    const float* row = cat + (size_t)l * D1;
    float s = 0.f, ss = 0.f;
    for (int i = t; i < D1; i += 256) { float v = row[i]; s += v; ss = fmaf(v, v, ss); }
    s1[t] = s; s2[t] = ss;
    block_reduce2_256(s1, s2, t);
    float m = s1[0] / (float)D1;
    float rstd = rsqrtf(fmaxf(s2[0] / (float)D1 - m * m, 0.f) + 1e-5f);
    for (int i = t; i < D1; i += 256)
        outn[(size_t)l * D1 + i] = f2bf((row[i] - m) * rstd * ld(w, i, bf) + ld(b, i, bf));
}

// ---------------- LN over 512, affine, leaky -> canon bf16 ----------------
__global__ __launch_bounds__(256) void k_ln2(
    const float* __restrict__ in, const void* __restrict__ w,
    const void* __restrict__ b, uint16_t* __restrict__ outn,
    const int* __restrict__ dt)
{
    __shared__ float s1[256], s2[256];
    int bf = dt[0];
    int t = threadIdx.x, l = blockIdx.x;
    const float* row = in + (size_t)l * D2;
    float v0 = row[t], v1 = row[t + 256];
    s1[t] = v0 + v1; s2[t] = v0 * v0 + v1 * v1;
    block_reduce2_256(s1, s2, t);
    float m = s1[0] / (float)D2;
    float rstd = rsqrtf(fmaxf(s2[0] / (float)D2 - m * m, 0.f) + 1e-5f);
    float o0 = (v0 - m) * rstd * ld(w, t, bf) + ld(b, t, bf);
    float o1 = (v1 - m) * rstd * ld(w, t + 256, bf) + ld(b, t + 256, bf);
    outn[(size_t)l * D2 + t]       = f2bf(o0 >= 0.f ? o0 : 0.01f * o0);
    outn[(size_t)l * D2 + t + 256] = f2bf(o1 >= 0.f ? o1 : 0.01f * o1);
}

// ---------------- partial stats over z channels (2-way row split) ----------------
__global__ __launch_bounds__(256) void k_pstat(
    const void* __restrict__ z, float* __restrict__ psum, float* __restrict__ psumsq,
    const int* __restrict__ dt)
{
    __shared__ float sa[128], sb[128];
    int bf = dt[0];
    int t = threadIdx.x;
    int ch = t & 127, half = t >> 7;
    size_t r0 = (size_t)blockIdx.x * 256;
    float s = 0.f, ss = 0.f;
    for (int i = 0; i < 128; ++i) {
        float v = ld(z, (r0 + half + 2 * i) * PDIM + ch, bf);
        s += v; ss = fmaf(v, v, ss);
    }
    if (half) { sa[ch] = s; sb[ch] = ss; }
    __syncthreads();
    if (!half) {
        psum[blockIdx.x * PDIM + ch] = s + sa[ch];
        psumsq[blockIdx.x * PDIM + ch] = ss + sb[ch];
    }
}

__global__ __launch_bounds__(512) void k_finP(
    const float* __restrict__ psum, const float* __restrict__ psumsq,
    float* __restrict__ meanP, float* __restrict__ rstdP)
{
    __shared__ float s1[512], s2[512];
    int t = threadIdx.x;
    int c = t & 127, seg = t >> 7;
    float s = 0.f, ss = 0.f;
    for (int b = seg * 144; b < seg * 144 + 144; ++b) {
        s += psum[b * PDIM + c]; ss += psumsq[b * PDIM + c];
    }
    s1[t] = s; s2[t] = ss;
    __syncthreads();
    if (t < 128) {
        float S  = s1[t] + s1[t + 128] + s1[t + 256] + s1[t + 384];
        float SS = s2[t] + s2[t + 128] + s2[t + 256] + s2[t + 384];
        float m = S / (float)LL;
        float var = SS / (float)LL - m * m;
        meanP[t] = m; rstdP[t] = rsqrtf(fmaxf(var, 0.f) + 1e-5f);
    }
}

// ---------------- weight pre-transform for MFMA conv_p ----------------
__global__ __launch_bounds__(64) void k_wprep(
    const void* __restrict__ wp, uint16_t* __restrict__ wt, const int* __restrict__ dt)
{
    int bf = dt[0];
    int oc = blockIdx.x, tap = blockIdx.y;
    for (int ic = threadIdx.x; ic < 144; ic += 64) {
        float v = (ic < 136) ? ld(wp, (size_t)oc * 1224 + (size_t)ic * 9 + tap, bf) : 0.f;
        wt[((size_t)tap * 128 + oc) * 144 + ic] = f2bf(v);
    }
}

// ---------------- conv_p via MFMA implicit GEMM (r3 version: 256thr, 2 blocks/CU) ----
__global__ __launch_bounds__(256, 2) void k_conv_p_mfma(
    const void* __restrict__ z, const uint16_t* __restrict__ a2,
    const uint16_t* __restrict__ wt, const void* __restrict__ bp,
    const float* __restrict__ meanP, const float* __restrict__ rstdP,
    void* __restrict__ out, const int* __restrict__ dt)
{
    __shared__ __align__(16) uint16_t As[4 * 34 * 144];   // 39168 B
    __shared__ __align__(16) uint16_t Ws[128 * 144];      // 36864 B
    __shared__ float mloc[136], rloc[136];

    int bf = dt[0];
    int t = threadIdx.x;
    int m0 = blockIdx.x * 32, l0 = blockIdx.y * 2;

    if (t < 136) { mloc[t] = meanP[t]; rloc[t] = rstdP[t]; }
    __syncthreads();

    // ---- stage normalized input halo: 4 rows x 34 cols x 144 ch (bf16) ----
    for (int grp = t; grp < 2448; grp += 256) {
        int pixidx = grp / 18;
        int icg = (grp - pixidx * 18) * 8;
        int lr = pixidx / 34, lc = pixidx - lr * 34;
        int li = l0 - 1 + lr, mi = m0 - 1 + lc;
        uint16_t vals[8];
        if (li < 0 || li >= LSEQ || mi < 0 || mi >= LSEQ || icg >= 136) {
            #pragma unroll
            for (int j = 0; j < 8; ++j) vals[j] = 0;
        } else if (icg < 128) {
            size_t zoff = ((size_t)li * LSEQ + mi) * PDIM + icg;
            if (bf) {
                const uint16_t* zp = (const uint16_t*)z + zoff;
                #pragma unroll
                for (int j = 0; j < 8; ++j)
                    vals[j] = f2bf((bf2f(zp[j]) - mloc[icg + j]) * rloc[icg + j]);
            } else {
                const float* zp = (const float*)z + zoff;
                #pragma unroll
                for (int j = 0; j < 8; ++j)
                    vals[j] = f2bf((zp[j] - mloc[icg + j]) * rloc[icg + j]);
            }
        } else {
            size_t poff = (size_t)li * LSEQ + mi;
            #pragma unroll
            for (int j = 0; j < 8; ++j)
                vals[j] = f2bf((bf2f(a2[(size_t)j * LL + poff]) - mloc[128 + j]) * rloc[128 + j]);
        }
        *(uint4*)&As[pixidx * 144 + icg] = *(const uint4*)vals;
    }

    int w = t >> 6, lane = t & 63;
    int p = lane & 15, g = lane >> 4;
    int r = w >> 1;
    int ocb = (w & 1) * 64;
    int bb0 = (ocb + p) * 144 + 8 * g;

    f32x4 acc0[4], acc1[4];
    #pragma unroll
    for (int n = 0; n < 4; ++n) {
        acc0[n] = (f32x4){0.f, 0.f, 0.f, 0.f};
        acc1[n] = (f32x4){0.f, 0.f, 0.f, 0.f};
    }
    bf16x8 bz = bf16x8_zero();

    for (int tap = 0; tap < 9; ++tap) {
        __syncthreads();
        {   // stage this tap's weights: [oc][144] bf16, linear copy
            const uint4* wsrc = (const uint4*)(wt + (size_t)tap * 18432);
            uint4* wdst = (uint4*)Ws;
            #pragma unroll
            for (int i = 0; i < 9; ++i) wdst[t + i * 256] = wsrc[t + i * 256];
        }
        __syncthreads();

        int tr = tap / 3, tc = tap - tr * 3;
        int abase = ((r + tr) * 34 + p + tc) * 144 + 8 * g;

        #pragma unroll
        for (int ch = 0; ch < 5; ++ch) {
            const int ic0 = (ch < 4) ? ch * 32 : 112;
            bf16x8 a0 = *(const bf16x8*)&As[abase + ic0];
            bf16x8 a1 = *(const bf16x8*)&As[abase + 2304 + ic0];
            #pragma unroll
            for (int n = 0; n < 4; ++n) {
                bf16x8 bq;
                if (ch < 4) {
                    bq = *(const bf16x8*)&Ws[bb0 + n * 2304 + ic0];
                } else {
                    bq = bz;
                    if (g == 2) bq = *(const bf16x8*)&Ws[bb0 + n * 2304 + 112];
                }
                acc0[n] = __builtin_amdgcn_mfma_f32_16x16x32_bf16(a0, bq, acc0[n], 0, 0, 0);
                acc1[n] = __builtin_amdgcn_mfma_f32_16x16x32_bf16(a1, bq, acc1[n], 0, 0, 0);
            }
        }
    }

    int l = l0 + r;
    #pragma unroll
    for (int n = 0; n < 4; ++n) {
        int oc = ocb + 16 * n + p;
        float bb = ld(bp, oc, bf);
        #pragma unroll
        for (int reg = 0; reg < 4; ++reg) {
            int pc = 4 * g + reg;
            float v0 = acc0[n][reg] + bb; v0 = v0 >= 0.f ? v0 : 0.01f * v0;
            stout(out, 98304 + ((size_t)l * LSEQ + (m0 + pc)) * PDIM + oc, v0, bf);
            float v1 = acc1[n][reg] + bb; v1 = v1 >= 0.f ? v1 : 0.01f * v1;
            stout(out, 98304 + ((size_t)l * LSEQ + (m0 + 16 + pc)) * PDIM + oc, v1, bf);
        }
    }
}

// ---------------- conv_p fallback: f32 VALU path (used if workspace too small) ----------------
__global__ __launch_bounds__(128) void k_conv_p(
    const void* __restrict__ z, const uint16_t* __restrict__ a2,
    const void* __restrict__ wp, const void* __restrict__ bp,
    const float* __restrict__ meanP, const float* __restrict__ rstdP,
    void* __restrict__ out, const int* __restrict__ dt)
{
    __shared__ __align__(16) float wlds[128 * 76];
    __shared__ __align__(16) float inl[4 * 18 * 8];
    int bf = dt[0];
    int t = threadIdx.x;
    int m0 = blockIdx.x * 16, l0 = blockIdx.y * 2;
    float acc0[16], acc1[16];
    #pragma unroll
    for (int i = 0; i < 16; ++i) { acc0[i] = 0.f; acc1[i] = 0.f; }

    for (int ic0 = 0; ic0 < 136; ic0 += 8) {
        __syncthreads();
        for (int i = t; i < 128 * 72; i += 128) {
            int op = i / 72, r = i % 72;
            int cc = r / 9, tap = r % 9;
            wlds[op * 76 + tap * 8 + cc] = ld(wp, op * 1224 + (ic0 + cc) * 9 + tap, bf);
        }
        for (int i = t; i < 4 * 18 * 8; i += 128) {
            int rr = i / 144, rem = i % 144;
            int col = rem >> 3, cc = rem & 7;
            int li = l0 - 1 + rr, mi = m0 - 1 + col, ic = ic0 + cc;
            float vv = 0.f;
            if (li >= 0 && li < LSEQ && mi >= 0 && mi < LSEQ) {
                float raw = (ic < PDIM) ? ld(z, ((size_t)li * LSEQ + mi) * PDIM + ic, bf)
                                        : bf2f(a2[(size_t)(ic - PDIM) * LL + li * LSEQ + mi]);
                vv = (raw - meanP[ic]) * rstdP[ic];
            }
            inl[i] = vv;
        }
        __syncthreads();
        #pragma unroll
        for (int qd = 0; qd < 2; ++qd) {
            float4 wq[9];
            #pragma unroll
            for (int tap = 0; tap < 9; ++tap)
                wq[tap] = *(const float4*)&wlds[t * 76 + tap * 8 + qd * 4];
            float4 win[4][3];
            #pragma unroll
            for (int r = 0; r < 4; ++r) {
                win[r][1] = *(const float4*)&inl[(r * 18 + 0) * 8 + qd * 4];
                win[r][2] = *(const float4*)&inl[(r * 18 + 1) * 8 + qd * 4];
                win[r][0] = win[r][1];
            }
            #pragma unroll
            for (int pix = 0; pix < 16; ++pix) {
                #pragma unroll
                for (int r = 0; r < 4; ++r) {
                    win[r][0] = win[r][1];
                    win[r][1] = win[r][2];
                    win[r][2] = *(const float4*)&inl[(r * 18 + pix + 2) * 8 + qd * 4];
                }
                float p0x = 0.f, p0y = 0.f, p0z = 0.f, p0w = 0.f;
                float p1x = 0.f, p1y = 0.f, p1z = 0.f, p1w = 0.f;
                #pragma unroll
                for (int tr = 0; tr < 3; ++tr) {
                    #pragma unroll
                    for (int c = 0; c < 3; ++c) {
                        float4 w4 = wq[tr * 3 + c];
                        float4 u0 = win[tr][c];
                        float4 u1 = win[tr + 1][c];
                        p0x = fmaf(w4.x, u0.x, p0x); p0y = fmaf(w4.y, u0.y, p0y);
                        p0z = fmaf(w4.z, u0.z, p0z); p0w = fmaf(w4.w, u0.w, p0w);
                        p1x = fmaf(w4.x, u1.x, p1x); p1y = fmaf(w4.y, u1.y, p1y);
                        p1z = fmaf(w4.z, u1.z, p1z); p1w = fmaf(w4.w, u1.w, p1w);
                    }
                }
                acc0[pix] += (p0x + p0y) + (p0z + p0w);
                acc1[pix] += (p1x + p1y) + (p1z + p1w);
            }
        }
    }
    float bb = ld(bp, t, bf);
    #pragma unroll
    for (int pix = 0; pix < 16; ++pix) {
        float v0 = acc0[pix] + bb; v0 = v0 >= 0.f ? v0 : 0.01f * v0;
        stout(out, 98304 + ((size_t)l0 * LSEQ + m0 + pix) * PDIM + t, v0, bf);
        float v1 = acc1[pix] + bb; v1 = v1 >= 0.f ? v1 : 0.01f * v1;
        stout(out, 98304 + ((size_t)(l0 + 1) * LSEQ + m0 + pix) * PDIM + t, v1, bf);
    }
}

extern "C" void kernel_launch(void* const* d_in, const int* in_sizes, int n_in,
                              void* d_out, int out_size, void* d_ws, size_t ws_size,
                              hipStream_t stream)
{
    const void* x     = d_in[0];
    const void* z     = d_in[1];
    const void* plddt = d_in[2];
    const void* Wq    = d_in[3];
    const void* Wk    = d_in[4];
    const void* Wv    = d_in[5];
    const void* Wp2a  = d_in[6];
    const void* caw   = d_in[7];
    const void* cab   = d_in[8];
    const void* cmw   = d_in[9];
    const void* cmb   = d_in[10];
    const void* ln1w  = d_in[11];
    const void* ln1b  = d_in[12];
    const void* l1w   = d_in[13];
    const void* l1b   = d_in[14];
    const void* ln2w  = d_in[15];
    const void* ln2b  = d_in[16];
    const void* l2w   = d_in[17];
    const void* l2b   = d_in[18];
    const void* lnfw  = d_in[19];
    const void* lnfb  = d_in[20];
    const void* cpw   = d_in[21];
    const void* cpb   = d_in[22];

    uint16_t* O = (uint16_t*)d_out;
    uint16_t* acat = O + 98304;               // 16*LL bf16
    uint16_t* a1b  = O + 2457600;             // 8*LL bf16 (pre-conv_a: q,k)
    uint16_t* qb   = a1b;
    uint16_t* kb   = a1b + 98304;
    uint16_t* vb   = O + 3637248;
    float*    cat  = (float*)(O + 3735552);   // 384x1280 f32
    float*    h1   = (float*)(O + 5701632);   // 384x512 f32
    float*    psum = (float*)(O + 6488064);
    float*    psumsq = (float*)(O + 6635520); // ends 6782976
    uint16_t* cb   = O + 6782976;             // 384x1280 bf16 (LN1 out)
    uint16_t* h1nb = O + 7274496;             // 384x512 bf16 (LN2 out)
    uint16_t* xb   = O + 7471104;             // 384x256 bf16
    uint16_t* wtq  = O + 7569408;             // 768x256 bf16 (Wq|Wk|Wv, n-major)
    uint16_t* wt1  = O + 7766016;             // 512x1280 bf16 (lin1, n-major)
    uint16_t* wt2  = O + 8421376;             // 256x512 bf16 (lin2, n-major)

    uint16_t* U = (uint16_t*)d_ws;
    uint16_t* a2b = U;                        // 8*LL bf16, live into conv_p
    float*    st  = (float*)(U + 1179648);    // stats, live into conv_p
    float* m16 = st;        float* r16 = st + 16;
    float* m9  = st + 32;   float* r9  = st + 48;
    float* mP  = st + 64;   float* rP  = st + 200;   // 136 each
    int*   flg = (int*)(U + 1181696);         // dtype flag
    uint16_t* wt = U + 1182720;               // 9*128*144 bf16 (conv_p MFMA weights)
    int use_mfma = (ws_size >= (size_t)2365440 + 331776);

    k_detect<<<1, 64, 0, stream>>>((const uint32_t*)z, flg);
    // prep: canon-bf16 x and n-major bf16 weights for the MFMA GEMMs
    k_cvt<<<384, 256, 0, stream>>>(x, xb, flg);
    k_wnk<<<dim3(8, 8), 256, 0, stream>>>(Wq, wtq,          256, 256, flg);
    k_wnk<<<dim3(8, 8), 256, 0, stream>>>(Wk, wtq +  65536, 256, 256, flg);
    k_wnk<<<dim3(8, 8), 256, 0, stream>>>(Wv, wtq + 131072, 256, 256, flg);
    k_wnk<<<dim3(40, 16), 256, 0, stream>>>(l1w, wt1, 1280, 512, flg);
    k_wnk<<<dim3(16, 8), 256, 0, stream>>>(l2w, wt2,  512, 256, flg);

    k_gemm_qkv<<<dim3(6, 12), 256, 0, stream>>>(xb, wtq, qb, kb, vb);
    k_apair <<<dim3(12, LSEQ), 256, 0, stream>>>(z, Wp2a, acat, flg);
    k_anode <<<dim3(12, LSEQ), 256, 0, stream>>>(qb, kb, acat);
    // stats over acat (16 ch)
    k_scp<<<dim3(18, 16), 256, 0, stream>>>(acat, plddt, psum, psumsq, flg, 16);
    k_scf<<<1, 16, 0, stream>>>(psum, psumsq, m16, r16, 16);
    k_conv_a<<<dim3(3, LSEQ), 128, 0, stream>>>(acat, caw, cab, m16, r16, a1b, flg);
    // stats over a1b (8 ch) + plddt (tail channel 8) in one pass
    k_scp<<<dim3(18, 9), 256, 0, stream>>>(a1b, plddt, psum, psumsq, flg, 8);
    k_scf<<<1, 9, 0, stream>>>(psum, psumsq, m9, r9, 9);
    k_conv_m<<<dim3(3, LSEQ), 128, 0, stream>>>(a1b, plddt, cmw, cmb, m9, r9, a2b, flg);
    k_agg   <<<LSEQ, 512, 0, stream>>>(a2b, vb, z, cat, flg);
    k_ln1   <<<LSEQ, 256, 0, stream>>>(cat, ln1w, ln1b, cb, flg);
    k_gemm_bias_f32<<<dim3(6, 8), 256, 0, stream>>>(cb, wt1, l1b, h1, 1280, 512, flg);
    k_ln2   <<<LSEQ, 256, 0, stream>>>(h1, ln2w, ln2b, h1nb, flg);
    k_lin2lnf_mfma<<<12, 256, 0, stream>>>(h1nb, wt2, l2b, x, lnfw, lnfb, d_out, flg);
    // stats over a2b (8 ch)
    k_scp<<<dim3(18, 8), 256, 0, stream>>>(a2b, plddt, psum, psumsq, flg, 8);
    k_scf<<<1, 8, 0, stream>>>(psum, psumsq, mP + 128, rP + 128, 8);
    k_pstat <<<576, 256, 0, stream>>>(z, psum, psumsq, flg);
    k_finP  <<<1, 512, 0, stream>>>(psum, psumsq, mP, rP);
    if (use_mfma) {
        k_wprep<<<dim3(128, 9), 64, 0, stream>>>(cpw, wt, flg);
        k_conv_p_mfma<<<dim3(12, 192), 256, 0, stream>>>(z, a2b, wt, cpb, mP, rP, d_out, flg);
    } else {
        k_conv_p<<<dim3(24, 192), 128, 0, stream>>>(z, a2b, cpw, cpb, mP, rP, d_out, flg);
    }
}

// Round 6
// 576.450 us; speedup vs baseline: 1.0773x; 1.0059x over previous
//
#include <hip/hip_runtime.h>
#include <stdint.h>

#define LSEQ 384
#define LL   147456   // 384*384
#define NODE 256
#define NH   8
#define HD   32
#define PDIM 128
#define D1   1280
#define D2   512

typedef __attribute__((ext_vector_type(8))) short s16x8;
typedef __attribute__((ext_vector_type(8))) __bf16 bf16x8;
typedef __attribute__((ext_vector_type(4))) float f32x4;

__device__ __forceinline__ float bf2f(uint16_t u) {
    union { uint32_t i; float f; } x; x.i = ((uint32_t)u) << 16; return x.f;
}
__device__ __forceinline__ uint16_t f2bf(float f) {
    uint32_t b = __float_as_uint(f);
    return (uint16_t)((b + 0x7FFFu + ((b >> 16) & 1u)) >> 16);
}
// dtype-adaptive input load: element index i, bf=1 -> bf16, bf=0 -> f32
__device__ __forceinline__ float ld(const void* p, size_t i, int bf) {
    return bf ? bf2f(((const uint16_t*)p)[i]) : ((const float*)p)[i];
}
// dtype-adaptive output store
__device__ __forceinline__ void stout(void* p, size_t i, float v, int bf) {
    if (bf) ((uint16_t*)p)[i] = f2bf(v);
    else    ((float*)p)[i] = v;
}

__device__ __forceinline__ bf16x8 bf16x8_zero() {
    union { s16x8 s; bf16x8 b; } u; u.s = (s16x8)0; return u.b;
}

// async global->LDS, 16B per lane; lds dst is wave-uniform base (+lane*16 by HW)
__device__ __forceinline__ void gl_lds16(const void* g, void* l) {
    __builtin_amdgcn_global_load_lds(
        (const __attribute__((address_space(1))) uint32_t*)g,
        (__attribute__((address_space(3))) uint32_t*)l, 16, 0, 0);
}

__device__ __forceinline__ void block_reduce2_256(float* s1, float* s2, int t) {
    __syncthreads();
    for (int o = 128; o > 0; o >>= 1) {
        if (t < o) { s1[t] += s1[t + o]; s2[t] += s2[t + o]; }
        __syncthreads();
    }
}

// accumulate 8 bf16 packed in a uint4 into sum / sumsq
__device__ __forceinline__ void acc8(uint4 u, float& s, float& ss) {
    uint32_t w[4] = { u.x, u.y, u.z, u.w };
    #pragma unroll
    for (int i = 0; i < 4; ++i) {
        float a = bf2f((uint16_t)(w[i] & 0xFFFFu));
        float b = bf2f((uint16_t)(w[i] >> 16));
        s += a + b;
        ss = fmaf(a, a, ss);
        ss = fmaf(b, b, ss);
    }
}

// ---------------- dtype detection: sample low u16 halves of z ----------------
__global__ void k_detect(const uint32_t* __restrict__ zz, int* __restrict__ flag) {
    if (threadIdx.x == 0 && blockIdx.x == 0) {
        int cnt = 0;
        for (int i = 0; i < 256; ++i) {
            uint32_t lo = zz[i] & 0xFFFFu;
            uint32_t e = (lo >> 7) & 0xFFu;
            if (lo == 0u || (e >= 96u && e <= 142u)) ++cnt;
        }
        flag[0] = (cnt >= 192) ? 1 : 0;   // 1 = inputs are bf16, 0 = f32
    }
}

// ---------------- convert to canon bf16 (identity roundtrip in bf16 mode) ----------------
__global__ __launch_bounds__(256) void k_cvt(
    const void* __restrict__ src, uint16_t* __restrict__ dst, const int* __restrict__ dt)
{
    int bf = dt[0];
    int i = blockIdx.x * 256 + threadIdx.x;
    dst[i] = f2bf(ld(src, i, bf));
}

// ---------------- weight transpose K-major -> N-major bf16 via 32x32 LDS tiles ----------
__global__ __launch_bounds__(256) void k_wnk(
    const void* __restrict__ src, uint16_t* __restrict__ dst, int K, int N,
    const int* __restrict__ dt)
{
    __shared__ float tile[32][33];
    int bf = dt[0];
    int k0 = blockIdx.x * 32, n0 = blockIdx.y * 32;
    int tr = threadIdx.x >> 5, tc = threadIdx.x & 31;
    #pragma unroll
    for (int i = 0; i < 4; ++i)
        tile[tr + i * 8][tc] = ld(src, (size_t)(k0 + tr + i * 8) * N + n0 + tc, bf);
    __syncthreads();
    #pragma unroll
    for (int i = 0; i < 4; ++i)
        dst[(size_t)(n0 + tr + i * 8) * K + k0 + tc] = f2bf(tile[tc][tr + i * 8]);
}

// ---------------- generic 64x64-tile MFMA GEMM: out f32 = A @ B^T + bias ----------------
__global__ __launch_bounds__(256) void k_gemm_bias_f32(
    const uint16_t* __restrict__ A, const uint16_t* __restrict__ B,
    const void* __restrict__ bias, float* __restrict__ out, int K, int N,
    const int* __restrict__ dt)
{
    __shared__ __align__(16) uint16_t As[64 * 72];
    __shared__ __align__(16) uint16_t Bs[64 * 72];
    int bf = dt[0];
    int t = threadIdx.x;
    int row0 = blockIdx.x * 64, col0 = blockIdx.y * 64;
    int w = t >> 6, lane = t & 63, p = lane & 15, g = lane >> 4;
    int wm = w >> 1, wn = w & 1;
    f32x4 acc[2][2];
    #pragma unroll
    for (int i = 0; i < 2; ++i)
        #pragma unroll
        for (int j = 0; j < 2; ++j) acc[i][j] = (f32x4){0.f, 0.f, 0.f, 0.f};

    for (int kc = 0; kc < K; kc += 64) {
        __syncthreads();
        #pragma unroll
        for (int rep = 0; rep < 2; ++rep) {
            int i = t + rep * 256;
            int r = i >> 3, c8 = (i & 7) * 8;
            *(uint4*)&As[r * 72 + c8] = *(const uint4*)&A[(size_t)(row0 + r) * K + kc + c8];
            *(uint4*)&Bs[r * 72 + c8] = *(const uint4*)&B[(size_t)(col0 + r) * K + kc + c8];
        }
        __syncthreads();
        #pragma unroll
        for (int kk = 0; kk < 64; kk += 32) {
            bf16x8 a0 = *(const bf16x8*)&As[(wm * 32 + p) * 72 + kk + 8 * g];
            bf16x8 a1 = *(const bf16x8*)&As[(wm * 32 + 16 + p) * 72 + kk + 8 * g];
            bf16x8 b0 = *(const bf16x8*)&Bs[(wn * 32 + p) * 72 + kk + 8 * g];
            bf16x8 b1 = *(const bf16x8*)&Bs[(wn * 32 + 16 + p) * 72 + kk + 8 * g];
            acc[0][0] = __builtin_amdgcn_mfma_f32_16x16x32_bf16(a0, b0, acc[0][0], 0, 0, 0);
            acc[0][1] = __builtin_amdgcn_mfma_f32_16x16x32_bf16(a0, b1, acc[0][1], 0, 0, 0);
            acc[1][0] = __builtin_amdgcn_mfma_f32_16x16x32_bf16(a1, b0, acc[1][0], 0, 0, 0);
            acc[1][1] = __builtin_amdgcn_mfma_f32_16x16x32_bf16(a1, b1, acc[1][1], 0, 0, 0);
        }
    }
    #pragma unroll
    for (int mi = 0; mi < 2; ++mi)
        #pragma unroll
        for (int ni = 0; ni < 2; ++ni) {
            int n = col0 + wn * 32 + ni * 16 + p;
            float bb = ld(bias, n, bf);
            #pragma unroll
            for (int reg = 0; reg < 4; ++reg) {
                int m = row0 + wm * 32 + mi * 16 + 4 * g + reg;
                out[(size_t)m * N + n] = acc[mi][ni][reg] + bb;
            }
        }
}

// ---------------- q,k,v GEMM: [384x768x256] = xb @ [Wq|Wk|Wv]^T -> canon bf16 ----------------
__global__ __launch_bounds__(256) void k_gemm_qkv(
    const uint16_t* __restrict__ A, const uint16_t* __restrict__ B,
    uint16_t* __restrict__ q, uint16_t* __restrict__ k, uint16_t* __restrict__ v)
{
    __shared__ __align__(16) uint16_t As[64 * 72];
    __shared__ __align__(16) uint16_t Bs[64 * 72];
    const int K = 256;
    int t = threadIdx.x;
    int row0 = blockIdx.x * 64, col0 = blockIdx.y * 64;
    int w = t >> 6, lane = t & 63, p = lane & 15, g = lane >> 4;
    int wm = w >> 1, wn = w & 1;
    f32x4 acc[2][2];
    #pragma unroll
    for (int i = 0; i < 2; ++i)
        #pragma unroll
        for (int j = 0; j < 2; ++j) acc[i][j] = (f32x4){0.f, 0.f, 0.f, 0.f};

    for (int kc = 0; kc < K; kc += 64) {
        __syncthreads();
        #pragma unroll
        for (int rep = 0; rep < 2; ++rep) {
            int i = t + rep * 256;
            int r = i >> 3, c8 = (i & 7) * 8;
            *(uint4*)&As[r * 72 + c8] = *(const uint4*)&A[(size_t)(row0 + r) * K + kc + c8];
            *(uint4*)&Bs[r * 72 + c8] = *(const uint4*)&B[(size_t)(col0 + r) * K + kc + c8];
        }
        __syncthreads();
        #pragma unroll
        for (int kk = 0; kk < 64; kk += 32) {
            bf16x8 a0 = *(const bf16x8*)&As[(wm * 32 + p) * 72 + kk + 8 * g];
            bf16x8 a1 = *(const bf16x8*)&As[(wm * 32 + 16 + p) * 72 + kk + 8 * g];
            bf16x8 b0 = *(const bf16x8*)&Bs[(wn * 32 + p) * 72 + kk + 8 * g];
            bf16x8 b1 = *(const bf16x8*)&Bs[(wn * 32 + 16 + p) * 72 + kk + 8 * g];
            acc[0][0] = __builtin_amdgcn_mfma_f32_16x16x32_bf16(a0, b0, acc[0][0], 0, 0, 0);
            acc[0][1] = __builtin_amdgcn_mfma_f32_16x16x32_bf16(a0, b1, acc[0][1], 0, 0, 0);
            acc[1][0] = __builtin_amdgcn_mfma_f32_16x16x32_bf16(a1, b0, acc[1][0], 0, 0, 0);
            acc[1][1] = __builtin_amdgcn_mfma_f32_16x16x32_bf16(a1, b1, acc[1][1], 0, 0, 0);
        }
    }
    #pragma unroll
    for (int mi = 0; mi < 2; ++mi)
        #pragma unroll
        for (int ni = 0; ni < 2; ++ni) {
            int nglob = col0 + wn * 32 + ni * 16 + p;
            int sel = nglob >> 8, col = nglob & 255;
            uint16_t* dst = (sel == 0) ? q : (sel == 1) ? k : v;
            #pragma unroll
            for (int reg = 0; reg < 4; ++reg) {
                int m = row0 + wm * 32 + mi * 16 + 4 * g + reg;
                dst[(size_t)m * 256 + col] = f2bf(acc[mi][ni][reg]);
            }
        }
}

// ---------------- lin2 + bias + residual + final LN, fused MFMA ----------------
__global__ __launch_bounds__(256) void k_lin2lnf_mfma(
    const uint16_t* __restrict__ A, const uint16_t* __restrict__ B,
    const void* __restrict__ bias, const void* __restrict__ x,
    const void* __restrict__ lnw, const void* __restrict__ lnb,
    void* __restrict__ out, const int* __restrict__ dt)
{
    __shared__ __align__(16) uint16_t As[32 * 72];
    __shared__ __align__(16) uint16_t Bs[256 * 72];
    const int K = 512;
    int bf = dt[0];
    int t = threadIdx.x;
    int row0 = blockIdx.x * 32;
    int w = t >> 6, lane = t & 63, p = lane & 15, g = lane >> 4;
    f32x4 acc[2][4];
    #pragma unroll
    for (int i = 0; i < 2; ++i)
        #pragma unroll
        for (int j = 0; j < 4; ++j) acc[i][j] = (f32x4){0.f, 0.f, 0.f, 0.f};

    for (int kc = 0; kc < K; kc += 64) {
        __syncthreads();
        {   // A: 32x64 = 256 uint4 groups
            int r = t >> 3, c8 = (t & 7) * 8;
            *(uint4*)&As[r * 72 + c8] = *(const uint4*)&A[(size_t)(row0 + r) * K + kc + c8];
        }
        #pragma unroll
        for (int rep = 0; rep < 8; ++rep) {   // B: 256x64 = 2048 uint4 groups
            int i = t + rep * 256;
            int r = i >> 3, c8 = (i & 7) * 8;
            *(uint4*)&Bs[r * 72 + c8] = *(const uint4*)&B[(size_t)r * K + kc + c8];
        }
        __syncthreads();
        #pragma unroll
        for (int kk = 0; kk < 64; kk += 32) {
            bf16x8 a0 = *(const bf16x8*)&As[(p) * 72 + kk + 8 * g];
            bf16x8 a1 = *(const bf16x8*)&As[(16 + p) * 72 + kk + 8 * g];
            #pragma unroll
            for (int ni = 0; ni < 4; ++ni) {
                bf16x8 bq = *(const bf16x8*)&Bs[(w * 64 + ni * 16 + p) * 72 + kk + 8 * g];
                acc[0][ni] = __builtin_amdgcn_mfma_f32_16x16x32_bf16(a0, bq, acc[0][ni], 0, 0, 0);
                acc[1][ni] = __builtin_amdgcn_mfma_f32_16x16x32_bf16(a1, bq, acc[1][ni], 0, 0, 0);
            }
        }
    }
    __syncthreads();
    float* lnt = (float*)Bs;   // 32 x 264 f32 tile
    #pragma unroll
    for (int mi = 0; mi < 2; ++mi)
        #pragma unroll
        for (int ni = 0; ni < 4; ++ni) {
            int n = w * 64 + ni * 16 + p;
            float bb = ld(bias, n, bf);
            #pragma unroll
            for (int reg = 0; reg < 4; ++reg) {
                int m = mi * 16 + 4 * g + reg;
                lnt[m * 264 + n] = acc[mi][ni][reg] + bb + ld(x, (size_t)(row0 + m) * 256 + n, bf);
            }
        }
    __syncthreads();
    for (int rr = 0; rr < 8; ++rr) {
        int m = w * 8 + rr;
        float4 v4 = *(const float4*)&lnt[m * 264 + lane * 4];
        float vv[4] = { v4.x, v4.y, v4.z, v4.w };
        float s = (vv[0] + vv[1]) + (vv[2] + vv[3]);
        float ss = fmaf(vv[0], vv[0], fmaf(vv[1], vv[1], fmaf(vv[2], vv[2], vv[3] * vv[3])));
        #pragma unroll
        for (int off = 32; off > 0; off >>= 1) {
            s  += __shfl_xor(s, off);
            ss += __shfl_xor(ss, off);
        }
        float mean = s / 256.f;
        float rstd = rsqrtf(fmaxf(ss / 256.f - mean * mean, 0.f) + 1e-5f);
        #pragma unroll
        for (int i = 0; i < 4; ++i) {
            int c = lane * 4 + i;
            float val = (vv[i] - mean) * rstd * ld(lnw, c, bf) + ld(lnb, c, bf);
            stout(out, (size_t)(row0 + m) * 256 + c, val, bf);
        }
    }
}

// ---------------- a_pair = z @ Wp2a -> acat[h][l][m] (bf16) ----------------
__global__ __launch_bounds__(256) void k_apair(
    const void* __restrict__ z, const void* __restrict__ Wp2a,
    uint16_t* __restrict__ acat, const int* __restrict__ dt)
{
    __shared__ float zl[32 * 129];
    __shared__ float wp[PDIM * NH];
    int bf = dt[0];
    int t = threadIdx.x, m0 = blockIdx.x * 32, l = blockIdx.y;
    for (int i = t; i < PDIM * NH; i += 256) wp[i] = ld(Wp2a, i, bf);
    if (bf) {
        const uint16_t* zz = (const uint16_t*)z;
        for (int grp = t; grp < 512; grp += 256) {
            int ml = grp >> 4, p8 = (grp & 15) * 8;
            uint4 u = *(const uint4*)&zz[((size_t)(l * LSEQ + m0 + ml)) * PDIM + p8];
            const uint16_t* pu = (const uint16_t*)&u;
            #pragma unroll
            for (int j = 0; j < 8; ++j) zl[ml * 129 + p8 + j] = bf2f(pu[j]);
        }
    } else {
        const float* zz = (const float*)z;
        for (int grp = t; grp < 1024; grp += 256) {
            int ml = grp >> 5, p4 = (grp & 31) * 4;
            float4 u = *(const float4*)&zz[((size_t)(l * LSEQ + m0 + ml)) * PDIM + p4];
            zl[ml * 129 + p4 + 0] = u.x; zl[ml * 129 + p4 + 1] = u.y;
            zl[ml * 129 + p4 + 2] = u.z; zl[ml * 129 + p4 + 3] = u.w;
        }
    }
    __syncthreads();
    int h = t >> 5, ml = t & 31;
    float acc = 0.f;
    for (int p = 0; p < PDIM; ++p) acc = fmaf(zl[ml * 129 + p], wp[p * NH + h], acc);
    acat[(size_t)h * LL + l * LSEQ + m0 + ml] = f2bf(acc);
}

// ---------------- a_node = (q k^T)/sqrt(hd) -> acat[8+h][l][m] (bf16) ----------------
__global__ __launch_bounds__(256) void k_anode(
    const uint16_t* __restrict__ q, const uint16_t* __restrict__ k,
    uint16_t* __restrict__ acat)
{
    __shared__ float kl[NODE * 33];
    __shared__ float qr[NH * 33];
    int t = threadIdx.x, m0 = blockIdx.x * 32, l = blockIdx.y;
    for (int grp = t; grp < 1024; grp += 256) {   // 32 px x 256 ch, 8-elem groups
        int ml = grp >> 5, c8 = (grp & 31) * 8;
        uint4 u = *(const uint4*)&k[(size_t)(m0 + ml) * NODE + c8];
        const uint16_t* pu = (const uint16_t*)&u;
        #pragma unroll
        for (int j = 0; j < 8; ++j) kl[(c8 + j) * 33 + ml] = bf2f(pu[j]);
    }
    qr[(t >> 5) * 33 + (t & 31)] = bf2f(q[l * NODE + t]);
    __syncthreads();
    int h = t >> 5, ml = t & 31;
    float acc = 0.f;
    #pragma unroll 8
    for (int d = 0; d < HD; ++d)
        acc = fmaf(qr[h * 33 + d], kl[(h * HD + d) * 33 + ml], acc);
    acat[(size_t)(NH + h) * LL + l * LSEQ + m0 + ml] = f2bf(acc * 0.17677669529663687f);
}

// ---------------- unified stats partial: canon channels (+ optional raw tail ch) ------
__global__ __launch_bounds__(256) void k_scp(
    const uint16_t* __restrict__ src, const void* __restrict__ raw,
    float* __restrict__ ps, float* __restrict__ pss, const int* __restrict__ dt, int C)
{
    __shared__ float s1[256], s2[256];
    int c = blockIdx.y, chunk = blockIdx.x, t = threadIdx.x;
    float s = 0.f, ss = 0.f;
    if (c < C) {
        const uint16_t* p = src + (size_t)c * LL + (size_t)chunk * 8192;
        #pragma unroll
        for (int it = 0; it < 4; ++it) acc8(*(const uint4*)&p[(it * 256 + t) * 8], s, ss);
    } else if (dt[0]) {
        const uint4* p = (const uint4*)raw + (size_t)chunk * 1024;
        #pragma unroll
        for (int it = 0; it < 4; ++it) acc8(p[it * 256 + t], s, ss);
    } else {
        const float4* p = (const float4*)raw + (size_t)chunk * 2048;
        #pragma unroll
        for (int it = 0; it < 8; ++it) {
            float4 a = p[it * 256 + t];
            s += (a.x + a.y) + (a.z + a.w);
            ss = fmaf(a.x, a.x, fmaf(a.y, a.y, fmaf(a.z, a.z, fmaf(a.w, a.w, ss))));
        }
    }
    s1[t] = s; s2[t] = ss;
    block_reduce2_256(s1, s2, t);
    if (t == 0) { ps[c * 18 + chunk] = s1[0]; pss[c * 18 + chunk] = s2[0]; }
}

__global__ void k_scf(
    const float* __restrict__ ps, const float* __restrict__ pss,
    float* __restrict__ mean_out, float* __restrict__ rstd_out, int C)
{
    int t = threadIdx.x;
    if (t < C) {
        float s = 0.f, ss = 0.f;
        for (int i = 0; i < 18; ++i) { s += ps[t * 18 + i]; ss += pss[t * 18 + i]; }
        float m = s / (float)LL;
        float var = ss / (float)LL - m * m;
        mean_out[t] = m; rstd_out[t] = rsqrtf(fmaxf(var, 0.f) + 1e-5f);
    }
}

// ---------------- conv_a: 16 -> 8 channels, ALL oc per block ----------------
__global__ __launch_bounds__(128) void k_conv_a(
    const uint16_t* __restrict__ acat, const void* __restrict__ wa,
    const void* __restrict__ ba, const float* __restrict__ mean,
    const float* __restrict__ rstd, uint16_t* __restrict__ out,
    const int* __restrict__ dt)
{
    __shared__ float wl[9 * 8 * 16];   // [tap][oc][ic], rstd folded
    __shared__ float ot[8 * 9];        // [oc][tap]
    int bf = dt[0];
    int t = threadIdx.x;
    int l = blockIdx.y, m = blockIdx.x * 128 + t;
    for (int i = t; i < 1152; i += 128) {
        int tap = i >> 7, rem = i & 127;
        int oc = rem >> 4, ic = rem & 15;
        wl[i] = ld(wa, (size_t)oc * 144 + ic * 9 + tap, bf) * rstd[ic];
    }
    __syncthreads();
    if (t < 72) {
        int oc = t / 9, tap = t - oc * 9;
        float s = 0.f;
        for (int ic = 0; ic < 16; ++ic) s = fmaf(mean[ic], wl[tap * 128 + oc * 16 + ic], s);
        ot[t] = s;
    }
    __syncthreads();
    float acc[8];
    #pragma unroll
    for (int oc = 0; oc < 8; ++oc) acc[oc] = ld(ba, oc, bf);
    #pragma unroll
    for (int r = 0; r < 3; ++r) {
        int li = l + r - 1;
        if (li < 0 || li >= LSEQ) continue;
        #pragma unroll
        for (int c = 0; c < 3; ++c) {
            int mi = m + c - 1;
            if (mi < 0 || mi >= LSEQ) continue;
            const uint16_t* ip = acat + li * LSEQ + mi;
            float v[16];
            #pragma unroll
            for (int ic = 0; ic < 16; ++ic) v[ic] = bf2f(ip[(size_t)ic * LL]);
            int tap = r * 3 + c;
            const float4* wq = (const float4*)&wl[tap * 128];
            #pragma unroll
            for (int oc = 0; oc < 8; ++oc) {
                float4 w0 = wq[oc * 4], w1 = wq[oc * 4 + 1], w2 = wq[oc * 4 + 2], w3 = wq[oc * 4 + 3];
                float a = acc[oc] - ot[oc * 9 + tap];
                a = fmaf(w0.x, v[0], a);  a = fmaf(w0.y, v[1], a);
                a = fmaf(w0.z, v[2], a);  a = fmaf(w0.w, v[3], a);
                a = fmaf(w1.x, v[4], a);  a = fmaf(w1.y, v[5], a);
                a = fmaf(w1.z, v[6], a);  a = fmaf(w1.w, v[7], a);
                a = fmaf(w2.x, v[8], a);  a = fmaf(w2.y, v[9], a);
                a = fmaf(w2.z, v[10], a); a = fmaf(w2.w, v[11], a);
                a = fmaf(w3.x, v[12], a); a = fmaf(w3.y, v[13], a);
                a = fmaf(w3.z, v[14], a); a = fmaf(w3.w, v[15], a);
                acc[oc] = a;
            }
        }
    }
    #pragma unroll
    for (int oc = 0; oc < 8; ++oc) {
        float a = acc[oc] >= 0.f ? acc[oc] : 0.01f * acc[oc];
        out[(size_t)oc * LL + l * LSEQ + m] = f2bf(a);
    }
}

// ---------------- conv_m: 9 -> 8 channels (8 canon bf16 + raw plddt), ALL oc/block ----
__global__ __launch_bounds__(128) void k_conv_m(
    const uint16_t* __restrict__ a1, const void* __restrict__ plddt,
    const void* __restrict__ wm, const void* __restrict__ bm,
    const float* __restrict__ mean, const float* __restrict__ rstd,
    uint16_t* __restrict__ out, const int* __restrict__ dt)
{
    __shared__ float wl[9 * 8 * 12];
    __shared__ float ot[8 * 9];
    int bf = dt[0];
    int t = threadIdx.x;
    int l = blockIdx.y, m = blockIdx.x * 128 + t;
    for (int i = t; i < 864; i += 128) {
        int tap = i / 96, rem = i - tap * 96;
        int oc = rem / 12, ic = rem - oc * 12;
        wl[i] = (ic < 9) ? ld(wm, (size_t)oc * 81 + ic * 9 + tap, bf) * rstd[ic] : 0.f;
    }
    __syncthreads();
    if (t < 72) {
        int oc = t / 9, tap = t - oc * 9;
        float s = 0.f;
        for (int ic = 0; ic < 9; ++ic) s = fmaf(mean[ic], wl[tap * 96 + oc * 12 + ic], s);
        ot[t] = s;
    }
    __syncthreads();
    float acc[8];
    #pragma unroll
    for (int oc = 0; oc < 8; ++oc) acc[oc] = ld(bm, oc, bf);
    #pragma unroll
    for (int r = 0; r < 3; ++r) {
        int li = l + r - 1;
        if (li < 0 || li >= LSEQ) continue;
        #pragma unroll
        for (int c = 0; c < 3; ++c) {
            int mi = m + c - 1;
            if (mi < 0 || mi >= LSEQ) continue;
            int off = li * LSEQ + mi;
            float v[12];
            #pragma unroll
            for (int ic = 0; ic < 8; ++ic) v[ic] = bf2f(a1[(size_t)ic * LL + off]);
            v[8] = ld(plddt, off, bf); v[9] = 0.f; v[10] = 0.f; v[11] = 0.f;
            int tap = r * 3 + c;
            const float4* wq = (const float4*)&wl[tap * 96];
            #pragma unroll
            for (int oc = 0; oc < 8; ++oc) {
                float4 w0 = wq[oc * 3], w1 = wq[oc * 3 + 1], w2 = wq[oc * 3 + 2];
                float a = acc[oc] - ot[oc * 9 + tap];
                a = fmaf(w0.x, v[0], a); a = fmaf(w0.y, v[1], a);
                a = fmaf(w0.z, v[2], a); a = fmaf(w0.w, v[3], a);
                a = fmaf(w1.x, v[4], a); a = fmaf(w1.y, v[5], a);
                a = fmaf(w1.z, v[6], a); a = fmaf(w1.w, v[7], a);
                a = fmaf(w2.x, v[8], a);
                acc[oc] = a;
            }
        }
    }
    #pragma unroll
    for (int oc = 0; oc < 8; ++oc) {
        float a = acc[oc] >= 0.f ? acc[oc] : 0.01f * acc[oc];
        out[(size_t)oc * LL + l * LSEQ + m] = f2bf(a);
    }
}

// ---------------- aggregations: nfp + nfn -> cat (384 x 1280, f32) ----------------
__global__ __launch_bounds__(512) void k_agg(
    const uint16_t* __restrict__ a2, const uint16_t* __restrict__ v,
    const void* __restrict__ z, float* __restrict__ cat,
    const int* __restrict__ dt)
{
    __shared__ float al[NH * LSEQ];       // 12 KB
    __shared__ float hp[3 * NH * PDIM];   // 12 KB partials (reused for nfn)
    int bf = dt[0];
    int t = threadIdx.x, l = blockIdx.x;
    for (int i = t; i < NH * LSEQ; i += 512) {
        int h = i / LSEQ, m = i - h * LSEQ;
        al[i] = bf2f(a2[(size_t)h * LL + l * LSEQ + m]);
    }
    __syncthreads();
    int p = t & 127, qq = t >> 7;   // qq in 0..3
    float acc[NH];
    #pragma unroll
    for (int h = 0; h < NH; ++h) acc[h] = 0.f;
    size_t zrow = (size_t)l * LSEQ * PDIM;
    for (int m = qq; m < LSEQ; m += 4) {
        float zv = ld(z, zrow + (size_t)m * PDIM + p, bf);
        #pragma unroll
        for (int h = 0; h < NH; ++h) acc[h] = fmaf(al[h * LSEQ + m], zv, acc[h]);
    }
    if (qq) {
        #pragma unroll
        for (int h = 0; h < NH; ++h) hp[(qq - 1) * 1024 + h * PDIM + p] = acc[h];
    }
    __syncthreads();
    if (qq == 0) {
        #pragma unroll
        for (int h = 0; h < NH; ++h)
            cat[(size_t)l * D1 + h * PDIM + p] =
                acc[h] + hp[h * PDIM + p] + hp[1024 + h * PDIM + p] + hp[2048 + h * PDIM + p];
    }
    // nfn: 256 outputs, 2-way m split
    int o = t & 255, half = t >> 8;
    int h2 = o >> 5;
    float s = 0.f;
    for (int m = half; m < LSEQ; m += 2)
        s = fmaf(al[h2 * LSEQ + m], bf2f(v[m * NODE + o]), s);
    __syncthreads();
    if (half) hp[o] = s;
    __syncthreads();
    if (!half) cat[(size_t)l * D1 + NH * PDIM + o] = s + hp[o];
}

// ---------------- LN over 1280, affine -> canon bf16 ----------------
__global__ __launch_bounds__(256) void k_ln1(
    const float* __restrict__ cat, const void* __restrict__ w,
    const void* __restrict__ b, uint16_t* __restrict__ outn,
    const int* __restrict__ dt)
{
    __shared__ float s1[256], s2[256];
    int bf = dt[0];
    int t = threadIdx.x, l = blockIdx.x;
    const float* row = cat + (size_t)l * D1;
    float s = 0.f, ss = 0.f;
    for (int i = t; i < D1; i += 256) { float v = row[i]; s += v; ss = fmaf(v, v, ss); }
    s1[t] = s; s2[t] = ss;
    block_reduce2_256(s1, s2, t);
    float m = s1[0] / (float)D1;
    float rstd = rsqrtf(fmaxf(s2[0] / (float)D1 - m * m, 0.f) + 1e-5f);
    for (int i = t; i < D1; i += 256)
        outn[(size_t)l * D1 + i] = f2bf((row[i] - m) * rstd * ld(w, i, bf) + ld(b, i, bf));
}

// ---------------- LN over 512, affine, leaky -> canon bf16 ----------------
__global__ __launch_bounds__(256) void k_ln2(
    const float* __restrict__ in, const void* __restrict__ w,
    const void* __restrict__ b, uint16_t* __restrict__ outn,
    const int* __restrict__ dt)
{
    __shared__ float s1[256], s2[256];
    int bf = dt[0];
    int t = threadIdx.x, l = blockIdx.x;
    const float* row = in + (size_t)l * D2;
    float v0 = row[t], v1 = row[t + 256];
    s1[t] = v0 + v1; s2[t] = v0 * v0 + v1 * v1;
    block_reduce2_256(s1, s2, t);
    float m = s1[0] / (float)D2;
    float rstd = rsqrtf(fmaxf(s2[0] / (float)D2 - m * m, 0.f) + 1e-5f);
    float o0 = (v0 - m) * rstd * ld(w, t, bf) + ld(b, t, bf);
    float o1 = (v1 - m) * rstd * ld(w, t + 256, bf) + ld(b, t + 256, bf);
    outn[(size_t)l * D2 + t]       = f2bf(o0 >= 0.f ? o0 : 0.01f * o0);
    outn[(size_t)l * D2 + t + 256] = f2bf(o1 >= 0.f ? o1 : 0.01f * o1);
}

// ---------------- partial stats over z channels (2-way row split) ----------------
__global__ __launch_bounds__(256) void k_pstat(
    const void* __restrict__ z, float* __restrict__ psum, float* __restrict__ psumsq,
    const int* __restrict__ dt)
{
    __shared__ float sa[128], sb[128];
    int bf = dt[0];
    int t = threadIdx.x;
    int ch = t & 127, half = t >> 7;
    size_t r0 = (size_t)blockIdx.x * 256;
    float s = 0.f, ss = 0.f;
    for (int i = 0; i < 128; ++i) {
        float v = ld(z, (r0 + half + 2 * i) * PDIM + ch, bf);
        s += v; ss = fmaf(v, v, ss);
    }
    if (half) { sa[ch] = s; sb[ch] = ss; }
    __syncthreads();
    if (!half) {
        psum[blockIdx.x * PDIM + ch] = s + sa[ch];
        psumsq[blockIdx.x * PDIM + ch] = ss + sb[ch];
    }
}

__global__ __launch_bounds__(512) void k_finP(
    const float* __restrict__ psum, const float* __restrict__ psumsq,
    float* __restrict__ meanP, float* __restrict__ rstdP)
{
    __shared__ float s1[512], s2[512];
    int t = threadIdx.x;
    int c = t & 127, seg = t >> 7;
    float s = 0.f, ss = 0.f;
    for (int b = seg * 144; b < seg * 144 + 144; ++b) {
        s += psum[b * PDIM + c]; ss += psumsq[b * PDIM + c];
    }
    s1[t] = s; s2[t] = ss;
    __syncthreads();
    if (t < 128) {
        float S  = s1[t] + s1[t + 128] + s1[t + 256] + s1[t + 384];
        float SS = s2[t] + s2[t + 128] + s2[t + 256] + s2[t + 384];
        float m = S / (float)LL;
        float var = SS / (float)LL - m * m;
        meanP[t] = m; rstdP[t] = rsqrtf(fmaxf(var, 0.f) + 1e-5f);
    }
}

// ---------------- weight pre-transform for pipelined MFMA conv_p ----------------
// wp OIHW (128 oc,136 ic,3,3) -> per tap: part0 [oc][72] (ic 0..63, pad 0) then
// part1 [oc][88] (ic 64..135, pad 0). Per tap 40960 B (20480 u16).
__global__ __launch_bounds__(64) void k_wprep2(
    const void* __restrict__ wp, uint16_t* __restrict__ wt, const int* __restrict__ dt)
{
    int bf = dt[0];
    int oc = blockIdx.x, tap = blockIdx.y;
    size_t P0 = (size_t)tap * 20480;
    size_t P1 = P0 + 9216;
    for (int i = threadIdx.x; i < 72; i += 64) {
        float v = (i < 64) ? ld(wp, (size_t)oc * 1224 + (size_t)i * 9 + tap, bf) : 0.f;
        wt[P0 + (size_t)oc * 72 + i] = f2bf(v);
    }
    for (int i = threadIdx.x; i < 88; i += 64) {
        float v = (i < 72) ? ld(wp, (size_t)oc * 1224 + (size_t)(64 + i) * 9 + tap, bf) : 0.f;
        wt[P1 + (size_t)oc * 88 + i] = f2bf(v);
    }
}

// ---------------- conv_p via MFMA implicit GEMM, pipelined (v3) ----------------
// 256 thr / 4 waves, 2 blocks/CU. 18 phases (9 taps x 2 ic-parts), ONE barrier each:
// issue global_load_lds for next phase -> compute current -> __syncthreads (drains).
// LDS: As 4x34x136 (36992) + Ws0 (18432) + Ws1 (22528) + stats (1088) = 79040 B.
// Epilogue bounces through As for fully coalesced uint4 stores (kills 2x write amp).
__global__ __launch_bounds__(256, 2) void k_conv_p_mfma(
    const void* __restrict__ z, const uint16_t* __restrict__ a2,
    const uint16_t* __restrict__ wt, const void* __restrict__ bp,
    const float* __restrict__ meanP, const float* __restrict__ rstdP,
    void* __restrict__ out, const int* __restrict__ dt)
{
    __shared__ __align__(16) uint16_t As[4 * 34 * 136];   // 36992 B
    __shared__ __align__(16) uint16_t Ws0[9216];          // 18432 B: [oc][72]
    __shared__ __align__(16) uint16_t Ws1[11264];         // 22528 B: [oc][88]
    __shared__ float mloc[136], rloc[136];

    int bf = dt[0];
    int t = threadIdx.x;
    int m0 = blockIdx.x * 32, l0 = blockIdx.y * 2;
    int w = t >> 6, lane = t & 63;
    int p = lane & 15, g = lane >> 4;
    int r = w >> 1;
    int ocb = (w & 1) * 64;

    if (t < 136) { mloc[t] = meanP[t]; rloc[t] = rstdP[t]; }
    __syncthreads();

    // issue tap0/part0 weight prefetch (overlaps As staging below)
    {
        const char* src = (const char*)wt;   // part0 of tap 0 at offset 0
        for (int s = w; s < 18; s += 4)
            gl_lds16(src + s * 1024 + lane * 16, (char*)Ws0 + s * 1024);
    }

    // ---- stage normalized input halo: 4 rows x 34 cols x 136 ch (bf16) ----
    for (int grp = t; grp < 2312; grp += 256) {           // 17 groups of 8 per pixel
        int pixidx = grp / 17;
        int icg = (grp - pixidx * 17) * 8;
        int lr = pixidx / 34, lc = pixidx - lr * 34;
        int li = l0 - 1 + lr, mi = m0 - 1 + lc;
        uint16_t vals[8];
        if (li < 0 || li >= LSEQ || mi < 0 || mi >= LSEQ) {
            #pragma unroll
            for (int j = 0; j < 8; ++j) vals[j] = 0;
        } else if (icg < 128) {
            size_t zoff = ((size_t)li * LSEQ + mi) * PDIM + icg;
            if (bf) {
                const uint16_t* zp = (const uint16_t*)z + zoff;
                #pragma unroll
                for (int j = 0; j < 8; ++j)
                    vals[j] = f2bf((bf2f(zp[j]) - mloc[icg + j]) * rloc[icg + j]);
            } else {
                const float* zp = (const float*)z + zoff;
                #pragma unroll
                for (int j = 0; j < 8; ++j)
                    vals[j] = f2bf((zp[j] - mloc[icg + j]) * rloc[icg + j]);
            }
        } else {  // icg == 128: channels 128..135 from a2 (channel-major bf16)
            size_t poff = (size_t)li * LSEQ + mi;
            #pragma unroll
            for (int j = 0; j < 8; ++j)
                vals[j] = f2bf((bf2f(a2[(size_t)j * LL + poff]) - mloc[128 + j]) * rloc[128 + j]);
        }
        *(uint4*)&As[pixidx * 136 + icg] = *(const uint4*)vals;
    }
    __syncthreads();   // As ready; Ws0 (tap0/part0) drained by implicit vmcnt(0)

    int bb0p0 = (ocb + p) * 72 + 8 * g;   // part0 B base; n adds 1152
    int bb0p1 = (ocb + p) * 88 + 8 * g;   // part1 B base; n adds 1408

    f32x4 acc0[4], acc1[4];
    #pragma unroll
    for (int n = 0; n < 4; ++n) {
        acc0[n] = (f32x4){0.f, 0.f, 0.f, 0.f};
        acc1[n] = (f32x4){0.f, 0.f, 0.f, 0.f};
    }
    bf16x8 bz = bf16x8_zero();

    for (int tap = 0; tap < 9; ++tap) {
        int tr = tap / 3, tc = tap - tr * 3;
        int abase = ((r + tr) * 34 + p + tc) * 136 + 8 * g;   // +16px = +2176

        // ---- phase A: prefetch part1(tap) into Ws1; compute part0 from Ws0 ----
        {
            const char* src = (const char*)(wt + (size_t)tap * 20480 + 9216);
            for (int s = w; s < 22; s += 4)
                gl_lds16(src + s * 1024 + lane * 16, (char*)Ws1 + s * 1024);
        }
        #pragma unroll
        for (int cidx = 0; cidx < 2; ++cidx) {
            int ic0 = cidx * 32;
            bf16x8 a0 = *(const bf16x8*)&As[abase + ic0];
            bf16x8 a1 = *(const bf16x8*)&As[abase + 2176 + ic0];
            #pragma unroll
            for (int n = 0; n < 4; ++n) {
                bf16x8 bq = *(const bf16x8*)&Ws0[bb0p0 + n * 1152 + ic0];
                acc0[n] = __builtin_amdgcn_mfma_f32_16x16x32_bf16(a0, bq, acc0[n], 0, 0, 0);
                acc1[n] = __builtin_amdgcn_mfma_f32_16x16x32_bf16(a1, bq, acc1[n], 0, 0, 0);
            }
        }
        __syncthreads();   // drains Ws1 prefetch; all reads of Ws0 done

        // ---- phase B: prefetch part0(tap+1) into Ws0; compute part1 from Ws1 ----
        if (tap < 8) {
            const char* src = (const char*)(wt + (size_t)(tap + 1) * 20480);
            for (int s = w; s < 18; s += 4)
                gl_lds16(src + s * 1024 + lane * 16, (char*)Ws0 + s * 1024);
        }
        #pragma unroll
        for (int cidx = 0; cidx < 2; ++cidx) {
            int ic0 = 64 + cidx * 32;
            bf16x8 a0 = *(const bf16x8*)&As[abase + ic0];
            bf16x8 a1 = *(const bf16x8*)&As[abase + 2176 + ic0];
            #pragma unroll
            for (int n = 0; n < 4; ++n) {
                bf16x8 bq = *(const bf16x8*)&Ws1[bb0p1 + n * 1408 + (ic0 - 64)];
                acc0[n] = __builtin_amdgcn_mfma_f32_16x16x32_bf16(a0, bq, acc0[n], 0, 0, 0);
                acc1[n] = __builtin_amdgcn_mfma_f32_16x16x32_bf16(a1, bq, acc1[n], 0, 0, 0);
            }
        }
        {   // special chunk ic 112..143: A zero for g==3, B nonzero only for g==2
            bf16x8 a0s = bz, a1s = bz;
            if (g != 3) {
                a0s = *(const bf16x8*)&As[abase + 112];
                a1s = *(const bf16x8*)&As[abase + 2176 + 112];
            }
            #pragma unroll
            for (int n = 0; n < 4; ++n) {
                bf16x8 bq = bz;
                if (g == 2) bq = *(const bf16x8*)&Ws1[bb0p1 + n * 1408 + 48];
                acc0[n] = __builtin_amdgcn_mfma_f32_16x16x32_bf16(a0s, bq, acc0[n], 0, 0, 0);
                acc1[n] = __builtin_amdgcn_mfma_f32_16x16x32_bf16(a1s, bq, acc1[n], 0, 0, 0);
            }
        }
        __syncthreads();   // drains Ws0 prefetch; all reads of Ws1 done
    }

    // ---- epilogue: bias + leaky, bounce through As (dead), coalesced stores ----
    if (bf) {
        uint16_t* LB = As;   // [2 rows][32 px][128 oc] u16 = 16384 B
        #pragma unroll
        for (int n = 0; n < 4; ++n) {
            int oc = ocb + 16 * n + p;
            float bb = ld(bp, oc, bf);
            #pragma unroll
            for (int reg = 0; reg < 4; ++reg) {
                int ml = 4 * g + reg;
                float v0 = acc0[n][reg] + bb; v0 = v0 >= 0.f ? v0 : 0.01f * v0;
                LB[(r * 32 + ml) * 128 + oc] = f2bf(v0);
                float v1 = acc1[n][reg] + bb; v1 = v1 >= 0.f ? v1 : 0.01f * v1;
                LB[(r * 32 + 16 + ml) * 128 + oc] = f2bf(v1);
            }
        }
        __syncthreads();
        const uint4* srcv = (const uint4*)As;
        for (int i = t; i < 1024; i += 256) {
            int run = i >> 9, off = i & 511;
            uint16_t* dst = (uint16_t*)out + 98304 +
                ((size_t)(l0 + run) * LSEQ + m0) * PDIM + (size_t)off * 8;
            *(uint4*)dst = srcv[i];
        }
    } else {
        float* LB = (float*)As;   // [2][32][128] f32 = 32768 B
        #pragma unroll
        for (int n = 0; n < 4; ++n) {
            int oc = ocb + 16 * n + p;
            float bb = ld(bp, oc, bf);
            #pragma unroll
            for (int reg = 0; reg < 4; ++reg) {
                int ml = 4 * g + reg;
                float v0 = acc0[n][reg] + bb; v0 = v0 >= 0.f ? v0 : 0.01f * v0;
                LB[(r * 32 + ml) * 128 + oc] = v0;
                float v1 = acc1[n][reg] + bb; v1 = v1 >= 0.f ? v1 : 0.01f * v1;
                LB[(r * 32 + 16 + ml) * 128 + oc] = v1;
            }
        }
        __syncthreads();
        const uint4* srcv = (const uint4*)As;
        for (int i = t; i < 2048; i += 256) {
            int run = i >> 10, off = i & 1023;
            float* dst = (float*)out + 98304 +
                ((size_t)(l0 + run) * LSEQ + m0) * PDIM + (size_t)off * 4;
            *(uint4*)dst = srcv[i];
        }
    }
}

// ---------------- conv_p fallback: f32 VALU path (used if workspace too small) ----------------
__global__ __launch_bounds__(128) void k_conv_p(
    const void* __restrict__ z, const uint16_t* __restrict__ a2,
    const void* __restrict__ wp, const void* __restrict__ bp,
    const float* __restrict__ meanP, const float* __restrict__ rstdP,
    void* __restrict__ out, const int* __restrict__ dt)
{
    __shared__ __align__(16) float wlds[128 * 76];
    __shared__ __align__(16) float inl[4 * 18 * 8];
    int bf = dt[0];
    int t = threadIdx.x;
    int m0 = blockIdx.x * 16, l0 = blockIdx.y * 2;
    float acc0[16], acc1[16];
    #pragma unroll
    for (int i = 0; i < 16; ++i) { acc0[i] = 0.f; acc1[i] = 0.f; }

    for (int ic0 = 0; ic0 < 136; ic0 += 8) {
        __syncthreads();
        for (int i = t; i < 128 * 72; i += 128) {
            int op = i / 72, r = i % 72;
            int cc = r / 9, tap = r % 9;
            wlds[op * 76 + tap * 8 + cc] = ld(wp, op * 1224 + (ic0 + cc) * 9 + tap, bf);
        }
        for (int i = t; i < 4 * 18 * 8; i += 128) {
            int rr = i / 144, rem = i % 144;
            int col = rem >> 3, cc = rem & 7;
            int li = l0 - 1 + rr, mi = m0 - 1 + col, ic = ic0 + cc;
            float vv = 0.f;
            if (li >= 0 && li < LSEQ && mi >= 0 && mi < LSEQ) {
                float raw = (ic < PDIM) ? ld(z, ((size_t)li * LSEQ + mi) * PDIM + ic, bf)
                                        : bf2f(a2[(size_t)(ic - PDIM) * LL + li * LSEQ + mi]);
                vv = (raw - meanP[ic]) * rstdP[ic];
            }
            inl[i] = vv;
        }
        __syncthreads();
        #pragma unroll
        for (int qd = 0; qd < 2; ++qd) {
            float4 wq[9];
            #pragma unroll
            for (int tap = 0; tap < 9; ++tap)
                wq[tap] = *(const float4*)&wlds[t * 76 + tap * 8 + qd * 4];
            float4 win[4][3];
            #pragma unroll
            for (int r = 0; r < 4; ++r) {
                win[r][1] = *(const float4*)&inl[(r * 18 + 0) * 8 + qd * 4];
                win[r][2] = *(const float4*)&inl[(r * 18 + 1) * 8 + qd * 4];
                win[r][0] = win[r][1];
            }
            #pragma unroll
            for (int pix = 0; pix < 16; ++pix) {
                #pragma unroll
                for (int r = 0; r < 4; ++r) {
                    win[r][0] = win[r][1];
                    win[r][1] = win[r][2];
                    win[r][2] = *(const float4*)&inl[(r * 18 + pix + 2) * 8 + qd * 4];
                }
                float p0x = 0.f, p0y = 0.f, p0z = 0.f, p0w = 0.f;
                float p1x = 0.f, p1y = 0.f, p1z = 0.f, p1w = 0.f;
                #pragma unroll
                for (int tr = 0; tr < 3; ++tr) {
                    #pragma unroll
                    for (int c = 0; c < 3; ++c) {
                        float4 w4 = wq[tr * 3 + c];
                        float4 u0 = win[tr][c];
                        float4 u1 = win[tr + 1][c];
                        p0x = fmaf(w4.x, u0.x, p0x); p0y = fmaf(w4.y, u0.y, p0y);
                        p0z = fmaf(w4.z, u0.z, p0z); p0w = fmaf(w4.w, u0.w, p0w);
                        p1x = fmaf(w4.x, u1.x, p1x); p1y = fmaf(w4.y, u1.y, p1y);
                        p1z = fmaf(w4.z, u1.z, p1z); p1w = fmaf(w4.w, u1.w, p1w);
                    }
                }
                acc0[pix] += (p0x + p0y) + (p0z + p0w);
                acc1[pix] += (p1x + p1y) + (p1z + p1w);
            }
        }
    }
    float bb = ld(bp, t, bf);
    #pragma unroll
    for (int pix = 0; pix < 16; ++pix) {
        float v0 = acc0[pix] + bb; v0 = v0 >= 0.f ? v0 : 0.01f * v0;
        stout(out, 98304 + ((size_t)l0 * LSEQ + m0 + pix) * PDIM + t, v0, bf);
        float v1 = acc1[pix] + bb; v1 = v1 >= 0.f ? v1 : 0.01f * v1;
        stout(out, 98304 + ((size_t)(l0 + 1) * LSEQ + m0 + pix) * PDIM + t, v1, bf);
    }
}

extern "C" void kernel_launch(void* const* d_in, const int* in_sizes, int n_in,
                              void* d_out, int out_size, void* d_ws, size_t ws_size,
                              hipStream_t stream)
{
    const void* x     = d_in[0];
    const void* z     = d_in[1];
    const void* plddt = d_in[2];
    const void* Wq    = d_in[3];
    const void* Wk    = d_in[4];
    const void* Wv    = d_in[5];
    const void* Wp2a  = d_in[6];
    const void* caw   = d_in[7];
    const void* cab   = d_in[8];
    const void* cmw   = d_in[9];
    const void* cmb   = d_in[10];
    const void* ln1w  = d_in[11];
    const void* ln1b  = d_in[12];
    const void* l1w   = d_in[13];
    const void* l1b   = d_in[14];
    const void* ln2w  = d_in[15];
    const void* ln2b  = d_in[16];
    const void* l2w   = d_in[17];
    const void* l2b   = d_in[18];
    const void* lnfw  = d_in[19];
    const void* lnfb  = d_in[20];
    const void* cpw   = d_in[21];
    const void* cpb   = d_in[22];

    uint16_t* O = (uint16_t*)d_out;
    uint16_t* acat = O + 98304;               // 16*LL bf16
    uint16_t* a1b  = O + 2457600;             // 8*LL bf16 (pre-conv_a: q,k)
    uint16_t* qb   = a1b;
    uint16_t* kb   = a1b + 98304;
    uint16_t* vb   = O + 3637248;
    float*    cat  = (float*)(O + 3735552);   // 384x1280 f32
    float*    h1   = (float*)(O + 5701632);   // 384x512 f32
    float*    psum = (float*)(O + 6488064);
    float*    psumsq = (float*)(O + 6635520); // ends 6782976
    uint16_t* cb   = O + 6782976;             // 384x1280 bf16 (LN1 out)
    uint16_t* h1nb = O + 7274496;             // 384x512 bf16 (LN2 out)
    uint16_t* xb   = O + 7471104;             // 384x256 bf16
    uint16_t* wtq  = O + 7569408;             // 768x256 bf16 (Wq|Wk|Wv, n-major)
    uint16_t* wt1  = O + 7766016;             // 512x1280 bf16 (lin1, n-major)
    uint16_t* wt2  = O + 8421376;             // 256x512 bf16 (lin2, n-major)

    uint16_t* U = (uint16_t*)d_ws;
    uint16_t* a2b = U;                        // 8*LL bf16, live into conv_p
    float*    st  = (float*)(U + 1179648);    // stats, live into conv_p
    float* m16 = st;        float* r16 = st + 16;
    float* m9  = st + 32;   float* r9  = st + 48;
    float* mP  = st + 64;   float* rP  = st + 200;   // 136 each
    int*   flg = (int*)(U + 1181696);         // dtype flag
    uint16_t* wt = U + 1182720;               // 9*20480 u16 = 368640 B (part-major padded weights)
    int use_mfma = (ws_size >= (size_t)2365440 + 368640);

    k_detect<<<1, 64, 0, stream>>>((const uint32_t*)z, flg);
    // prep: canon-bf16 x and n-major bf16 weights for the MFMA GEMMs
    k_cvt<<<384, 256, 0, stream>>>(x, xb, flg);
    k_wnk<<<dim3(8, 8), 256, 0, stream>>>(Wq, wtq,          256, 256, flg);
    k_wnk<<<dim3(8, 8), 256, 0, stream>>>(Wk, wtq +  65536, 256, 256, flg);
    k_wnk<<<dim3(8, 8), 256, 0, stream>>>(Wv, wtq + 131072, 256, 256, flg);
    k_wnk<<<dim3(40, 16), 256, 0, stream>>>(l1w, wt1, 1280, 512, flg);
    k_wnk<<<dim3(16, 8), 256, 0, stream>>>(l2w, wt2,  512, 256, flg);

    k_gemm_qkv<<<dim3(6, 12), 256, 0, stream>>>(xb, wtq, qb, kb, vb);
    k_apair <<<dim3(12, LSEQ), 256, 0, stream>>>(z, Wp2a, acat, flg);
    k_anode <<<dim3(12, LSEQ), 256, 0, stream>>>(qb, kb, acat);
    // stats over acat (16 ch)
    k_scp<<<dim3(18, 16), 256, 0, stream>>>(acat, plddt, psum, psumsq, flg, 16);
    k_scf<<<1, 16, 0, stream>>>(psum, psumsq, m16, r16, 16);
    k_conv_a<<<dim3(3, LSEQ), 128, 0, stream>>>(acat, caw, cab, m16, r16, a1b, flg);
    // stats over a1b (8 ch) + plddt (tail channel 8) in one pass
    k_scp<<<dim3(18, 9), 256, 0, stream>>>(a1b, plddt, psum, psumsq, flg, 8);
    k_scf<<<1, 9, 0, stream>>>(psum, psumsq, m9, r9, 9);
    k_conv_m<<<dim3(3, LSEQ), 128, 0, stream>>>(a1b, plddt, cmw, cmb, m9, r9, a2b, flg);
    k_agg   <<<LSEQ, 512, 0, stream>>>(a2b, vb, z, cat, flg);
    k_ln1   <<<LSEQ, 256, 0, stream>>>(cat, ln1w, ln1b, cb, flg);
    k_gemm_bias_f32<<<dim3(6, 8), 256, 0, stream>>>(cb, wt1, l1b, h1, 1280, 512, flg);
    k_ln2   <<<LSEQ, 256, 0, stream>>>(h1, ln2w, ln2b, h1nb, flg);
    k_lin2lnf_mfma<<<12, 256, 0, stream>>>(h1nb, wt2, l2b, x, lnfw, lnfb, d_out, flg);
    // stats over a2b (8 ch)
    k_scp<<<dim3(18, 8), 256, 0, stream>>>(a2b, plddt, psum, psumsq, flg, 8);
    k_scf<<<1, 8, 0, stream>>>(psum, psumsq, mP + 128, rP + 128, 8);
    k_pstat <<<576, 256, 0, stream>>>(z, psum, psumsq, flg);
    k_finP  <<<1, 512, 0, stream>>>(psum, psumsq, mP, rP);
    if (use_mfma) {
        k_wprep2<<<dim3(128, 9), 64, 0, stream>>>(cpw, wt, flg);
        k_conv_p_mfma<<<dim3(12, 192), 256, 0, stream>>>(z, a2b, wt, cpb, mP, rP, d_out, flg);
    } else {
        k_conv_p<<<dim3(24, 192), 128, 0, stream>>>(z, a2b, cpw, cpb, mP, rP, d_out, flg);
    }
}

// Round 7
// 559.450 us; speedup vs baseline: 1.1101x; 1.0304x over previous
//
#include <hip/hip_runtime.h>
#include <stdint.h>

#define LSEQ 384
#define LL   147456   // 384*384
#define NODE 256
#define NH   8
#define HD   32
#define PDIM 128
#define D1   1280
#define D2   512

typedef __attribute__((ext_vector_type(8))) short s16x8;
typedef __attribute__((ext_vector_type(8))) __bf16 bf16x8;
typedef __attribute__((ext_vector_type(4))) float f32x4;

__device__ __forceinline__ float bf2f(uint16_t u) {
    union { uint32_t i; float f; } x; x.i = ((uint32_t)u) << 16; return x.f;
}
__device__ __forceinline__ uint16_t f2bf(float f) {
    uint32_t b = __float_as_uint(f);
    return (uint16_t)((b + 0x7FFFu + ((b >> 16) & 1u)) >> 16);
}
// dtype-adaptive input load: element index i, bf=1 -> bf16, bf=0 -> f32
__device__ __forceinline__ float ld(const void* p, size_t i, int bf) {
    return bf ? bf2f(((const uint16_t*)p)[i]) : ((const float*)p)[i];
}
// dtype-adaptive output store
__device__ __forceinline__ void stout(void* p, size_t i, float v, int bf) {
    if (bf) ((uint16_t*)p)[i] = f2bf(v);
    else    ((float*)p)[i] = v;
}

__device__ __forceinline__ bf16x8 bf16x8_zero() {
    union { s16x8 s; bf16x8 b; } u; u.s = (s16x8)0; return u.b;
}

// async global->LDS, 16B per lane; lds dst is wave-uniform base (+lane*16 by HW)
__device__ __forceinline__ void gl_lds16(const void* g, void* l) {
    __builtin_amdgcn_global_load_lds(
        (const __attribute__((address_space(1))) uint32_t*)g,
        (__attribute__((address_space(3))) uint32_t*)l, 16, 0, 0);
}

__device__ __forceinline__ void block_reduce2_256(float* s1, float* s2, int t) {
    __syncthreads();
    for (int o = 128; o > 0; o >>= 1) {
        if (t < o) { s1[t] += s1[t + o]; s2[t] += s2[t + o]; }
        __syncthreads();
    }
}

// accumulate 8 bf16 packed in a uint4 into sum / sumsq
__device__ __forceinline__ void acc8(uint4 u, float& s, float& ss) {
    uint32_t w[4] = { u.x, u.y, u.z, u.w };
    #pragma unroll
    for (int i = 0; i < 4; ++i) {
        float a = bf2f((uint16_t)(w[i] & 0xFFFFu));
        float b = bf2f((uint16_t)(w[i] >> 16));
        s += a + b;
        ss = fmaf(a, a, ss);
        ss = fmaf(b, b, ss);
    }
}

// ---------------- dtype detection: sample low u16 halves of z ----------------
__global__ void k_detect(const uint32_t* __restrict__ zz, int* __restrict__ flag) {
    if (threadIdx.x == 0 && blockIdx.x == 0) {
        int cnt = 0;
        for (int i = 0; i < 256; ++i) {
            uint32_t lo = zz[i] & 0xFFFFu;
            uint32_t e = (lo >> 7) & 0xFFu;
            if (lo == 0u || (e >= 96u && e <= 142u)) ++cnt;
        }
        flag[0] = (cnt >= 192) ? 1 : 0;   // 1 = inputs are bf16, 0 = f32
    }
}

// ---------------- merged prep: x->bf16 + five weight transposes ----------------
// grid (40,16,6). job 5: cvt x (384 flat blocks). jobs 0-4: K-major->N-major bf16
// transpose via 32x32 LDS tiles.
__global__ __launch_bounds__(256) void k_prep(
    const void* __restrict__ Wq, const void* __restrict__ Wk,
    const void* __restrict__ Wv, const void* __restrict__ l1w,
    const void* __restrict__ l2w, const void* __restrict__ x,
    uint16_t* __restrict__ wtq, uint16_t* __restrict__ wt1,
    uint16_t* __restrict__ wt2, uint16_t* __restrict__ xb,
    const int* __restrict__ dt)
{
    __shared__ float tile[32][33];
    int bf = dt[0];
    int job = blockIdx.z;
    if (job == 5) {
        int flat = blockIdx.y * 40 + blockIdx.x;
        if (flat < 384) {
            int i = flat * 256 + threadIdx.x;
            xb[i] = f2bf(ld(x, i, bf));
        }
        return;
    }
    const void* src; uint16_t* dst; int K, N;
    switch (job) {
        case 0: src = Wq;  dst = wtq;          K = 256;  N = 256; break;
        case 1: src = Wk;  dst = wtq + 65536;  K = 256;  N = 256; break;
        case 2: src = Wv;  dst = wtq + 131072; K = 256;  N = 256; break;
        case 3: src = l1w; dst = wt1;          K = 1280; N = 512; break;
        default: src = l2w; dst = wt2;         K = 512;  N = 256; break;
    }
    if ((int)blockIdx.x >= (K >> 5) || (int)blockIdx.y >= (N >> 5)) return;
    int k0 = blockIdx.x * 32, n0 = blockIdx.y * 32;
    int tr = threadIdx.x >> 5, tc = threadIdx.x & 31;
    #pragma unroll
    for (int i = 0; i < 4; ++i)
        tile[tr + i * 8][tc] = ld(src, (size_t)(k0 + tr + i * 8) * N + n0 + tc, bf);
    __syncthreads();
    #pragma unroll
    for (int i = 0; i < 4; ++i)
        dst[(size_t)(n0 + tr + i * 8) * K + k0 + tc] = f2bf(tile[tc][tr + i * 8]);
}

// ---------------- generic 64x64-tile MFMA GEMM: out f32 = A @ B^T + bias ----------------
__global__ __launch_bounds__(256) void k_gemm_bias_f32(
    const uint16_t* __restrict__ A, const uint16_t* __restrict__ B,
    const void* __restrict__ bias, float* __restrict__ out, int K, int N,
    const int* __restrict__ dt)
{
    __shared__ __align__(16) uint16_t As[64 * 72];
    __shared__ __align__(16) uint16_t Bs[64 * 72];
    int bf = dt[0];
    int t = threadIdx.x;
    int row0 = blockIdx.x * 64, col0 = blockIdx.y * 64;
    int w = t >> 6, lane = t & 63, p = lane & 15, g = lane >> 4;
    int wm = w >> 1, wn = w & 1;
    f32x4 acc[2][2];
    #pragma unroll
    for (int i = 0; i < 2; ++i)
        #pragma unroll
        for (int j = 0; j < 2; ++j) acc[i][j] = (f32x4){0.f, 0.f, 0.f, 0.f};

    for (int kc = 0; kc < K; kc += 64) {
        __syncthreads();
        #pragma unroll
        for (int rep = 0; rep < 2; ++rep) {
            int i = t + rep * 256;
            int r = i >> 3, c8 = (i & 7) * 8;
            *(uint4*)&As[r * 72 + c8] = *(const uint4*)&A[(size_t)(row0 + r) * K + kc + c8];
            *(uint4*)&Bs[r * 72 + c8] = *(const uint4*)&B[(size_t)(col0 + r) * K + kc + c8];
        }
        __syncthreads();
        #pragma unroll
        for (int kk = 0; kk < 64; kk += 32) {
            bf16x8 a0 = *(const bf16x8*)&As[(wm * 32 + p) * 72 + kk + 8 * g];
            bf16x8 a1 = *(const bf16x8*)&As[(wm * 32 + 16 + p) * 72 + kk + 8 * g];
            bf16x8 b0 = *(const bf16x8*)&Bs[(wn * 32 + p) * 72 + kk + 8 * g];
            bf16x8 b1 = *(const bf16x8*)&Bs[(wn * 32 + 16 + p) * 72 + kk + 8 * g];
            acc[0][0] = __builtin_amdgcn_mfma_f32_16x16x32_bf16(a0, b0, acc[0][0], 0, 0, 0);
            acc[0][1] = __builtin_amdgcn_mfma_f32_16x16x32_bf16(a0, b1, acc[0][1], 0, 0, 0);
            acc[1][0] = __builtin_amdgcn_mfma_f32_16x16x32_bf16(a1, b0, acc[1][0], 0, 0, 0);
            acc[1][1] = __builtin_amdgcn_mfma_f32_16x16x32_bf16(a1, b1, acc[1][1], 0, 0, 0);
        }
    }
    #pragma unroll
    for (int mi = 0; mi < 2; ++mi)
        #pragma unroll
        for (int ni = 0; ni < 2; ++ni) {
            int n = col0 + wn * 32 + ni * 16 + p;
            float bb = ld(bias, n, bf);
            #pragma unroll
            for (int reg = 0; reg < 4; ++reg) {
                int m = row0 + wm * 32 + mi * 16 + 4 * g + reg;
                out[(size_t)m * N + n] = acc[mi][ni][reg] + bb;
            }
        }
}

// ---------------- q,k,v GEMM: [384x768x256] = xb @ [Wq|Wk|Wv]^T -> canon bf16 ----------------
__global__ __launch_bounds__(256) void k_gemm_qkv(
    const uint16_t* __restrict__ A, const uint16_t* __restrict__ B,
    uint16_t* __restrict__ q, uint16_t* __restrict__ k, uint16_t* __restrict__ v)
{
    __shared__ __align__(16) uint16_t As[64 * 72];
    __shared__ __align__(16) uint16_t Bs[64 * 72];
    const int K = 256;
    int t = threadIdx.x;
    int row0 = blockIdx.x * 64, col0 = blockIdx.y * 64;
    int w = t >> 6, lane = t & 63, p = lane & 15, g = lane >> 4;
    int wm = w >> 1, wn = w & 1;
    f32x4 acc[2][2];
    #pragma unroll
    for (int i = 0; i < 2; ++i)
        #pragma unroll
        for (int j = 0; j < 2; ++j) acc[i][j] = (f32x4){0.f, 0.f, 0.f, 0.f};

    for (int kc = 0; kc < K; kc += 64) {
        __syncthreads();
        #pragma unroll
        for (int rep = 0; rep < 2; ++rep) {
            int i = t + rep * 256;
            int r = i >> 3, c8 = (i & 7) * 8;
            *(uint4*)&As[r * 72 + c8] = *(const uint4*)&A[(size_t)(row0 + r) * K + kc + c8];
            *(uint4*)&Bs[r * 72 + c8] = *(const uint4*)&B[(size_t)(col0 + r) * K + kc + c8];
        }
        __syncthreads();
        #pragma unroll
        for (int kk = 0; kk < 64; kk += 32) {
            bf16x8 a0 = *(const bf16x8*)&As[(wm * 32 + p) * 72 + kk + 8 * g];
            bf16x8 a1 = *(const bf16x8*)&As[(wm * 32 + 16 + p) * 72 + kk + 8 * g];
            bf16x8 b0 = *(const bf16x8*)&Bs[(wn * 32 + p) * 72 + kk + 8 * g];
            bf16x8 b1 = *(const bf16x8*)&Bs[(wn * 32 + 16 + p) * 72 + kk + 8 * g];
            acc[0][0] = __builtin_amdgcn_mfma_f32_16x16x32_bf16(a0, b0, acc[0][0], 0, 0, 0);
            acc[0][1] = __builtin_amdgcn_mfma_f32_16x16x32_bf16(a0, b1, acc[0][1], 0, 0, 0);
            acc[1][0] = __builtin_amdgcn_mfma_f32_16x16x32_bf16(a1, b0, acc[1][0], 0, 0, 0);
            acc[1][1] = __builtin_amdgcn_mfma_f32_16x16x32_bf16(a1, b1, acc[1][1], 0, 0, 0);
        }
    }
    #pragma unroll
    for (int mi = 0; mi < 2; ++mi)
        #pragma unroll
        for (int ni = 0; ni < 2; ++ni) {
            int nglob = col0 + wn * 32 + ni * 16 + p;
            int sel = nglob >> 8, col = nglob & 255;
            uint16_t* dst = (sel == 0) ? q : (sel == 1) ? k : v;
            #pragma unroll
            for (int reg = 0; reg < 4; ++reg) {
                int m = row0 + wm * 32 + mi * 16 + 4 * g + reg;
                dst[(size_t)m * 256 + col] = f2bf(acc[mi][ni][reg]);
            }
        }
}

// ---------------- lin2 + bias + residual + final LN, fused MFMA ----------------
__global__ __launch_bounds__(256) void k_lin2lnf_mfma(
    const uint16_t* __restrict__ A, const uint16_t* __restrict__ B,
    const void* __restrict__ bias, const void* __restrict__ x,
    const void* __restrict__ lnw, const void* __restrict__ lnb,
    void* __restrict__ out, const int* __restrict__ dt)
{
    __shared__ __align__(16) uint16_t As[32 * 72];
    __shared__ __align__(16) uint16_t Bs[256 * 72];
    const int K = 512;
    int bf = dt[0];
    int t = threadIdx.x;
    int row0 = blockIdx.x * 32;
    int w = t >> 6, lane = t & 63, p = lane & 15, g = lane >> 4;
    f32x4 acc[2][4];
    #pragma unroll
    for (int i = 0; i < 2; ++i)
        #pragma unroll
        for (int j = 0; j < 4; ++j) acc[i][j] = (f32x4){0.f, 0.f, 0.f, 0.f};

    for (int kc = 0; kc < K; kc += 64) {
        __syncthreads();
        {   // A: 32x64 = 256 uint4 groups
            int r = t >> 3, c8 = (t & 7) * 8;
            *(uint4*)&As[r * 72 + c8] = *(const uint4*)&A[(size_t)(row0 + r) * K + kc + c8];
        }
        #pragma unroll
        for (int rep = 0; rep < 8; ++rep) {   // B: 256x64 = 2048 uint4 groups
            int i = t + rep * 256;
            int r = i >> 3, c8 = (i & 7) * 8;
            *(uint4*)&Bs[r * 72 + c8] = *(const uint4*)&B[(size_t)r * K + kc + c8];
        }
        __syncthreads();
        #pragma unroll
        for (int kk = 0; kk < 64; kk += 32) {
            bf16x8 a0 = *(const bf16x8*)&As[(p) * 72 + kk + 8 * g];
            bf16x8 a1 = *(const bf16x8*)&As[(16 + p) * 72 + kk + 8 * g];
            #pragma unroll
            for (int ni = 0; ni < 4; ++ni) {
                bf16x8 bq = *(const bf16x8*)&Bs[(w * 64 + ni * 16 + p) * 72 + kk + 8 * g];
                acc[0][ni] = __builtin_amdgcn_mfma_f32_16x16x32_bf16(a0, bq, acc[0][ni], 0, 0, 0);
                acc[1][ni] = __builtin_amdgcn_mfma_f32_16x16x32_bf16(a1, bq, acc[1][ni], 0, 0, 0);
            }
        }
    }
    __syncthreads();
    float* lnt = (float*)Bs;   // 32 x 264 f32 tile
    #pragma unroll
    for (int mi = 0; mi < 2; ++mi)
        #pragma unroll
        for (int ni = 0; ni < 4; ++ni) {
            int n = w * 64 + ni * 16 + p;
            float bb = ld(bias, n, bf);
            #pragma unroll
            for (int reg = 0; reg < 4; ++reg) {
                int m = mi * 16 + 4 * g + reg;
                lnt[m * 264 + n] = acc[mi][ni][reg] + bb + ld(x, (size_t)(row0 + m) * 256 + n, bf);
            }
        }
    __syncthreads();
    for (int rr = 0; rr < 8; ++rr) {
        int m = w * 8 + rr;
        float4 v4 = *(const float4*)&lnt[m * 264 + lane * 4];
        float vv[4] = { v4.x, v4.y, v4.z, v4.w };
        float s = (vv[0] + vv[1]) + (vv[2] + vv[3]);
        float ss = fmaf(vv[0], vv[0], fmaf(vv[1], vv[1], fmaf(vv[2], vv[2], vv[3] * vv[3])));
        #pragma unroll
        for (int off = 32; off > 0; off >>= 1) {
            s  += __shfl_xor(s, off);
            ss += __shfl_xor(ss, off);
        }
        float mean = s / 256.f;
        float rstd = rsqrtf(fmaxf(ss / 256.f - mean * mean, 0.f) + 1e-5f);
        #pragma unroll
        for (int i = 0; i < 4; ++i) {
            int c = lane * 4 + i;
            float val = (vv[i] - mean) * rstd * ld(lnw, c, bf) + ld(lnb, c, bf);
            stout(out, (size_t)(row0 + m) * 256 + c, val, bf);
        }
    }
}

// ---------------- a_pair = z @ Wp2a -> acat[h][l][m] (bf16) ----------------
__global__ __launch_bounds__(256) void k_apair(
    const void* __restrict__ z, const void* __restrict__ Wp2a,
    uint16_t* __restrict__ acat, const int* __restrict__ dt)
{
    __shared__ float zl[32 * 129];
    __shared__ float wp[PDIM * NH];
    int bf = dt[0];
    int t = threadIdx.x, m0 = blockIdx.x * 32, l = blockIdx.y;
    for (int i = t; i < PDIM * NH; i += 256) wp[i] = ld(Wp2a, i, bf);
    if (bf) {
        const uint16_t* zz = (const uint16_t*)z;
        for (int grp = t; grp < 512; grp += 256) {
            int ml = grp >> 4, p8 = (grp & 15) * 8;
            uint4 u = *(const uint4*)&zz[((size_t)(l * LSEQ + m0 + ml)) * PDIM + p8];
            const uint16_t* pu = (const uint16_t*)&u;
            #pragma unroll
            for (int j = 0; j < 8; ++j) zl[ml * 129 + p8 + j] = bf2f(pu[j]);
        }
    } else {
        const float* zz = (const float*)z;
        for (int grp = t; grp < 1024; grp += 256) {
            int ml = grp >> 5, p4 = (grp & 31) * 4;
            float4 u = *(const float4*)&zz[((size_t)(l * LSEQ + m0 + ml)) * PDIM + p4];
            zl[ml * 129 + p4 + 0] = u.x; zl[ml * 129 + p4 + 1] = u.y;
            zl[ml * 129 + p4 + 2] = u.z; zl[ml * 129 + p4 + 3] = u.w;
        }
    }
    __syncthreads();
    int h = t >> 5, ml = t & 31;
    float acc = 0.f;
    for (int p = 0; p < PDIM; ++p) acc = fmaf(zl[ml * 129 + p], wp[p * NH + h], acc);
    acat[(size_t)h * LL + l * LSEQ + m0 + ml] = f2bf(acc);
}

// ---------------- a_node = (q k^T)/sqrt(hd) -> acat[8+h][l][m] (bf16) ----------------
__global__ __launch_bounds__(256) void k_anode(
    const uint16_t* __restrict__ q, const uint16_t* __restrict__ k,
    uint16_t* __restrict__ acat)
{
    __shared__ float kl[NODE * 33];
    __shared__ float qr[NH * 33];
    int t = threadIdx.x, m0 = blockIdx.x * 32, l = blockIdx.y;
    for (int grp = t; grp < 1024; grp += 256) {   // 32 px x 256 ch, 8-elem groups
        int ml = grp >> 5, c8 = (grp & 31) * 8;
        uint4 u = *(const uint4*)&k[(size_t)(m0 + ml) * NODE + c8];
        const uint16_t* pu = (const uint16_t*)&u;
        #pragma unroll
        for (int j = 0; j < 8; ++j) kl[(c8 + j) * 33 + ml] = bf2f(pu[j]);
    }
    qr[(t >> 5) * 33 + (t & 31)] = bf2f(q[l * NODE + t]);
    __syncthreads();
    int h = t >> 5, ml = t & 31;
    float acc = 0.f;
    #pragma unroll 8
    for (int d = 0; d < HD; ++d)
        acc = fmaf(qr[h * 33 + d], kl[(h * HD + d) * 33 + ml], acc);
    acat[(size_t)(NH + h) * LL + l * LSEQ + m0 + ml] = f2bf(acc * 0.17677669529663687f);
}

// ---------------- unified stats partial: canon channels (+ optional raw tail ch) ------
__global__ __launch_bounds__(256) void k_scp(
    const uint16_t* __restrict__ src, const void* __restrict__ raw,
    float* __restrict__ ps, float* __restrict__ pss, const int* __restrict__ dt, int C)
{
    __shared__ float s1[256], s2[256];
    int c = blockIdx.y, chunk = blockIdx.x, t = threadIdx.x;
    float s = 0.f, ss = 0.f;
    if (c < C) {
        const uint16_t* p = src + (size_t)c * LL + (size_t)chunk * 8192;
        #pragma unroll
        for (int it = 0; it < 4; ++it) acc8(*(const uint4*)&p[(it * 256 + t) * 8], s, ss);
    } else if (dt[0]) {
        const uint4* p = (const uint4*)raw + (size_t)chunk * 1024;
        #pragma unroll
        for (int it = 0; it < 4; ++it) acc8(p[it * 256 + t], s, ss);
    } else {
        const float4* p = (const float4*)raw + (size_t)chunk * 2048;
        #pragma unroll
        for (int it = 0; it < 8; ++it) {
            float4 a = p[it * 256 + t];
            s += (a.x + a.y) + (a.z + a.w);
            ss = fmaf(a.x, a.x, fmaf(a.y, a.y, fmaf(a.z, a.z, fmaf(a.w, a.w, ss))));
        }
    }
    s1[t] = s; s2[t] = ss;
    block_reduce2_256(s1, s2, t);
    if (t == 0) { ps[c * 18 + chunk] = s1[0]; pss[c * 18 + chunk] = s2[0]; }
}

__global__ void k_scf(
    const float* __restrict__ ps, const float* __restrict__ pss,
    float* __restrict__ mean_out, float* __restrict__ rstd_out, int C)
{
    int t = threadIdx.x;
    if (t < C) {
        float s = 0.f, ss = 0.f;
        for (int i = 0; i < 18; ++i) { s += ps[t * 18 + i]; ss += pss[t * 18 + i]; }
        float m = s / (float)LL;
        float var = ss / (float)LL - m * m;
        mean_out[t] = m; rstd_out[t] = rsqrtf(fmaxf(var, 0.f) + 1e-5f);
    }
}

// ---------------- conv_a: 16 -> 8 channels, ALL oc per block, XCD-swizzled ----------------
__global__ __launch_bounds__(128) void k_conv_a(
    const uint16_t* __restrict__ acat, const void* __restrict__ wa,
    const void* __restrict__ ba, const float* __restrict__ mean,
    const float* __restrict__ rstd, uint16_t* __restrict__ out,
    const int* __restrict__ dt)
{
    __shared__ float wl[9 * 8 * 16];   // [tap][oc][ic], rstd folded
    __shared__ float ot[8 * 9];        // [oc][tap]
    int bf = dt[0];
    int t = threadIdx.x;
    int flat = blockIdx.y * 3 + blockIdx.x;        // 1152 blocks, %8==0
    int wk = (flat & 7) * 144 + (flat >> 3);       // XCD-contiguous l chunks
    int l = wk / 3, m = (wk % 3) * 128 + t;
    for (int i = t; i < 1152; i += 128) {
        int tap = i >> 7, rem = i & 127;
        int oc = rem >> 4, ic = rem & 15;
        wl[i] = ld(wa, (size_t)oc * 144 + ic * 9 + tap, bf) * rstd[ic];
    }
    __syncthreads();
    if (t < 72) {
        int oc = t / 9, tap = t - oc * 9;
        float s = 0.f;
        for (int ic = 0; ic < 16; ++ic) s = fmaf(mean[ic], wl[tap * 128 + oc * 16 + ic], s);
        ot[t] = s;
    }
    __syncthreads();
    float acc[8];
    #pragma unroll
    for (int oc = 0; oc < 8; ++oc) acc[oc] = ld(ba, oc, bf);
    #pragma unroll
    for (int r = 0; r < 3; ++r) {
        int li = l + r - 1;
        if (li < 0 || li >= LSEQ) continue;
        #pragma unroll
        for (int c = 0; c < 3; ++c) {
            int mi = m + c - 1;
            if (mi < 0 || mi >= LSEQ) continue;
            const uint16_t* ip = acat + li * LSEQ + mi;
            float v[16];
            #pragma unroll
            for (int ic = 0; ic < 16; ++ic) v[ic] = bf2f(ip[(size_t)ic * LL]);
            int tap = r * 3 + c;
            const float4* wq = (const float4*)&wl[tap * 128];
            #pragma unroll
            for (int oc = 0; oc < 8; ++oc) {
                float4 w0 = wq[oc * 4], w1 = wq[oc * 4 + 1], w2 = wq[oc * 4 + 2], w3 = wq[oc * 4 + 3];
                float a = acc[oc] - ot[oc * 9 + tap];
                a = fmaf(w0.x, v[0], a);  a = fmaf(w0.y, v[1], a);
                a = fmaf(w0.z, v[2], a);  a = fmaf(w0.w, v[3], a);
                a = fmaf(w1.x, v[4], a);  a = fmaf(w1.y, v[5], a);
                a = fmaf(w1.z, v[6], a);  a = fmaf(w1.w, v[7], a);
                a = fmaf(w2.x, v[8], a);  a = fmaf(w2.y, v[9], a);
                a = fmaf(w2.z, v[10], a); a = fmaf(w2.w, v[11], a);
                a = fmaf(w3.x, v[12], a); a = fmaf(w3.y, v[13], a);
                a = fmaf(w3.z, v[14], a); a = fmaf(w3.w, v[15], a);
                acc[oc] = a;
            }
        }
    }
    #pragma unroll
    for (int oc = 0; oc < 8; ++oc) {
        float a = acc[oc] >= 0.f ? acc[oc] : 0.01f * acc[oc];
        out[(size_t)oc * LL + l * LSEQ + m] = f2bf(a);
    }
}

// ---------------- conv_m: 9 -> 8 channels, ALL oc/block, XCD-swizzled ----
__global__ __launch_bounds__(128) void k_conv_m(
    const uint16_t* __restrict__ a1, const void* __restrict__ plddt,
    const void* __restrict__ wm, const void* __restrict__ bm,
    const float* __restrict__ mean, const float* __restrict__ rstd,
    uint16_t* __restrict__ out, const int* __restrict__ dt)
{
    __shared__ float wl[9 * 8 * 12];
    __shared__ float ot[8 * 9];
    int bf = dt[0];
    int t = threadIdx.x;
    int flat = blockIdx.y * 3 + blockIdx.x;
    int wk = (flat & 7) * 144 + (flat >> 3);
    int l = wk / 3, m = (wk % 3) * 128 + t;
    for (int i = t; i < 864; i += 128) {
        int tap = i / 96, rem = i - tap * 96;
        int oc = rem / 12, ic = rem - oc * 12;
        wl[i] = (ic < 9) ? ld(wm, (size_t)oc * 81 + ic * 9 + tap, bf) * rstd[ic] : 0.f;
    }
    __syncthreads();
    if (t < 72) {
        int oc = t / 9, tap = t - oc * 9;
        float s = 0.f;
        for (int ic = 0; ic < 9; ++ic) s = fmaf(mean[ic], wl[tap * 96 + oc * 12 + ic], s);
        ot[t] = s;
    }
    __syncthreads();
    float acc[8];
    #pragma unroll
    for (int oc = 0; oc < 8; ++oc) acc[oc] = ld(bm, oc, bf);
    #pragma unroll
    for (int r = 0; r < 3; ++r) {
        int li = l + r - 1;
        if (li < 0 || li >= LSEQ) continue;
        #pragma unroll
        for (int c = 0; c < 3; ++c) {
            int mi = m + c - 1;
            if (mi < 0 || mi >= LSEQ) continue;
            int off = li * LSEQ + mi;
            float v[12];
            #pragma unroll
            for (int ic = 0; ic < 8; ++ic) v[ic] = bf2f(a1[(size_t)ic * LL + off]);
            v[8] = ld(plddt, off, bf); v[9] = 0.f; v[10] = 0.f; v[11] = 0.f;
            int tap = r * 3 + c;
            const float4* wq = (const float4*)&wl[tap * 96];
            #pragma unroll
            for (int oc = 0; oc < 8; ++oc) {
                float4 w0 = wq[oc * 3], w1 = wq[oc * 3 + 1], w2 = wq[oc * 3 + 2];
                float a = acc[oc] - ot[oc * 9 + tap];
                a = fmaf(w0.x, v[0], a); a = fmaf(w0.y, v[1], a);
                a = fmaf(w0.z, v[2], a); a = fmaf(w0.w, v[3], a);
                a = fmaf(w1.x, v[4], a); a = fmaf(w1.y, v[5], a);
                a = fmaf(w1.z, v[6], a); a = fmaf(w1.w, v[7], a);
                a = fmaf(w2.x, v[8], a);
                acc[oc] = a;
            }
        }
    }
    #pragma unroll
    for (int oc = 0; oc < 8; ++oc) {
        float a = acc[oc] >= 0.f ? acc[oc] : 0.01f * acc[oc];
        out[(size_t)oc * LL + l * LSEQ + m] = f2bf(a);
    }
}

// ---------------- aggregations: nfp + nfn -> cat (384 x 1280, f32) ----------------
__global__ __launch_bounds__(512) void k_agg(
    const uint16_t* __restrict__ a2, const uint16_t* __restrict__ v,
    const void* __restrict__ z, float* __restrict__ cat,
    const int* __restrict__ dt)
{
    __shared__ float al[NH * LSEQ];       // 12 KB
    __shared__ float hp[3 * NH * PDIM];   // 12 KB partials (reused for nfn)
    int bf = dt[0];
    int t = threadIdx.x, l = blockIdx.x;
    for (int i = t; i < NH * LSEQ; i += 512) {
        int h = i / LSEQ, m = i - h * LSEQ;
        al[i] = bf2f(a2[(size_t)h * LL + l * LSEQ + m]);
    }
    __syncthreads();
    int p = t & 127, qq = t >> 7;   // qq in 0..3
    float acc[NH];
    #pragma unroll
    for (int h = 0; h < NH; ++h) acc[h] = 0.f;
    size_t zrow = (size_t)l * LSEQ * PDIM;
    for (int m = qq; m < LSEQ; m += 4) {
        float zv = ld(z, zrow + (size_t)m * PDIM + p, bf);
        #pragma unroll
        for (int h = 0; h < NH; ++h) acc[h] = fmaf(al[h * LSEQ + m], zv, acc[h]);
    }
    if (qq) {
        #pragma unroll
        for (int h = 0; h < NH; ++h) hp[(qq - 1) * 1024 + h * PDIM + p] = acc[h];
    }
    __syncthreads();
    if (qq == 0) {
        #pragma unroll
        for (int h = 0; h < NH; ++h)
            cat[(size_t)l * D1 + h * PDIM + p] =
                acc[h] + hp[h * PDIM + p] + hp[1024 + h * PDIM + p] + hp[2048 + h * PDIM + p];
    }
    // nfn: 256 outputs, 2-way m split
    int o = t & 255, half = t >> 8;
    int h2 = o >> 5;
    float s = 0.f;
    for (int m = half; m < LSEQ; m += 2)
        s = fmaf(al[h2 * LSEQ + m], bf2f(v[m * NODE + o]), s);
    __syncthreads();
    if (half) hp[o] = s;
    __syncthreads();
    if (!half) cat[(size_t)l * D1 + NH * PDIM + o] = s + hp[o];
}

// ---------------- LN over 1280, affine -> canon bf16 ----------------
__global__ __launch_bounds__(256) void k_ln1(
    const float* __restrict__ cat, const void* __restrict__ w,
    const void* __restrict__ b, uint16_t* __restrict__ outn,
    const int* __restrict__ dt)
{
    __shared__ float s1[256], s2[256];
    int bf = dt[0];
    int t = threadIdx.x, l = blockIdx.x;
    const float* row = cat + (size_t)l * D1;
    float s = 0.f, ss = 0.f;
    for (int i = t; i < D1; i += 256) { float v = row[i]; s += v; ss = fmaf(v, v, ss); }
    s1[t] = s; s2[t] = ss;
    block_reduce2_256(s1, s2, t);
    float m = s1[0] / (float)D1;
    float rstd = rsqrtf(fmaxf(s2[0] / (float)D1 - m * m, 0.f) + 1e-5f);
    for (int i = t; i < D1; i += 256)
        outn[(size_t)l * D1 + i] = f2bf((row[i] - m) * rstd * ld(w, i, bf) + ld(b, i, bf));
}

// ---------------- LN over 512, affine, leaky -> canon bf16 ----------------
__global__ __launch_bounds__(256) void k_ln2(
    const float* __restrict__ in, const void* __restrict__ w,
    const void* __restrict__ b, uint16_t* __restrict__ outn,
    const int* __restrict__ dt)
{
    __shared__ float s1[256], s2[256];
    int bf = dt[0];
    int t = threadIdx.x, l = blockIdx.x;
    const float* row = in + (size_t)l * D2;
    float v0 = row[t], v1 = row[t + 256];
    s1[t] = v0 + v1; s2[t] = v0 * v0 + v1 * v1;
    block_reduce2_256(s1, s2, t);
    float m = s1[0] / (float)D2;
    float rstd = rsqrtf(fmaxf(s2[0] / (float)D2 - m * m, 0.f) + 1e-5f);
    float o0 = (v0 - m) * rstd * ld(w, t, bf) + ld(b, t, bf);
    float o1 = (v1 - m) * rstd * ld(w, t + 256, bf) + ld(b, t + 256, bf);
    outn[(size_t)l * D2 + t]       = f2bf(o0 >= 0.f ? o0 : 0.01f * o0);
    outn[(size_t)l * D2 + t + 256] = f2bf(o1 >= 0.f ? o1 : 0.01f * o1);
}

// ---------------- partial stats over z channels (2-way row split) ----------------
__global__ __launch_bounds__(256) void k_pstat(
    const void* __restrict__ z, float* __restrict__ psum, float* __restrict__ psumsq,
    const int* __restrict__ dt)
{
    __shared__ float sa[128], sb[128];
    int bf = dt[0];
    int t = threadIdx.x;
    int ch = t & 127, half = t >> 7;
    size_t r0 = (size_t)blockIdx.x * 256;
    float s = 0.f, ss = 0.f;
    for (int i = 0; i < 128; ++i) {
        float v = ld(z, (r0 + half + 2 * i) * PDIM + ch, bf);
        s += v; ss = fmaf(v, v, ss);
    }
    if (half) { sa[ch] = s; sb[ch] = ss; }
    __syncthreads();
    if (!half) {
        psum[blockIdx.x * PDIM + ch] = s + sa[ch];
        psumsq[blockIdx.x * PDIM + ch] = ss + sb[ch];
    }
}

__global__ __launch_bounds__(512) void k_finP(
    const float* __restrict__ psum, const float* __restrict__ psumsq,
    float* __restrict__ meanP, float* __restrict__ rstdP)
{
    __shared__ float s1[512], s2[512];
    int t = threadIdx.x;
    int c = t & 127, seg = t >> 7;
    float s = 0.f, ss = 0.f;
    for (int b = seg * 144; b < seg * 144 + 144; ++b) {
        s += psum[b * PDIM + c]; ss += psumsq[b * PDIM + c];
    }
    s1[t] = s; s2[t] = ss;
    __syncthreads();
    if (t < 128) {
        float S  = s1[t] + s1[t + 128] + s1[t + 256] + s1[t + 384];
        float SS = s2[t] + s2[t + 128] + s2[t + 256] + s2[t + 384];
        float m = S / (float)LL;
        float var = SS / (float)LL - m * m;
        meanP[t] = m; rstdP[t] = rsqrtf(fmaxf(var, 0.f) + 1e-5f);
    }
}

// ---------------- weight pre-transform for MFMA conv_p ----------------
// wp OIHW (128 oc, 136 ic, 3, 3) -> wt[tap][oc][144] bf16, ic 136..143 = 0
__global__ __launch_bounds__(64) void k_wprep(
    const void* __restrict__ wp, uint16_t* __restrict__ wt, const int* __restrict__ dt)
{
    int bf = dt[0];
    int oc = blockIdx.x, tap = blockIdx.y;
    for (int ic = threadIdx.x; ic < 144; ic += 64) {
        float v = (ic < 136) ? ld(wp, (size_t)oc * 1224 + (size_t)ic * 9 + tap, bf) : 0.f;
        wt[((size_t)tap * 128 + oc) * 144 + ic] = f2bf(v);
    }
}

// ---------------- conv_p via MFMA implicit GEMM v4 ----------------
// 512 thr / 8 waves, 4 rows x 32 cols per block (1152 blocks, XCD-swizzled).
// Full-tap double-buffered weights via global_load_lds: 9 phases, ONE barrier each.
// r3-proven bank layout: As stride 144 (zero tail), Ws [128][144].
// LDS: As 6x34x144 (58752) + Ws 2x36864 + stats 1088 = 133568 B -> 1 block/CU, 8 waves.
__global__ __launch_bounds__(512, 1) void k_conv_p_mfma(
    const void* __restrict__ z, const uint16_t* __restrict__ a2,
    const uint16_t* __restrict__ wt, const void* __restrict__ bp,
    const float* __restrict__ meanP, const float* __restrict__ rstdP,
    void* __restrict__ out, const int* __restrict__ dt)
{
    __shared__ __align__(16) uint16_t As[6 * 34 * 144];   // 58752 B
    __shared__ __align__(16) uint16_t Ws[2][128 * 144];   // 73728 B
    __shared__ float mloc[136], rloc[136];

    int bf = dt[0];
    int t = threadIdx.x;
    int flat = blockIdx.y * 12 + blockIdx.x;       // 1152 blocks, %8==0
    int wk = (flat & 7) * 144 + (flat >> 3);       // bijective XCD chunking
    int m0 = (wk % 12) * 32, l0 = (wk / 12) * 4;
    int w = t >> 6, lane = t & 63;
    int p = lane & 15, g = lane >> 4;
    int r = w >> 1;               // output row 0..3
    int ocb = (w & 1) * 64;       // oc base for this wave

    if (t < 136) { mloc[t] = meanP[t]; rloc[t] = rstdP[t]; }
    __syncthreads();   // stats visible (no outstanding vmem yet -> cheap)

    // issue tap0 weights into Ws[0] (36 KB = 36 x 1KB chunks across 8 waves)
    {
        const char* src = (const char*)wt;
        for (int s = w; s < 36; s += 8)
            gl_lds16(src + s * 1024 + lane * 16, (char*)Ws[0] + s * 1024);
    }

    // ---- stage normalized input halo: 6 rows x 34 cols x 144 ch (zero tail) ----
    for (int grp = t; grp < 3672; grp += 512) {           // 8-elem groups
        int pixidx = grp / 18;
        int icg = (grp - pixidx * 18) * 8;
        int lr = pixidx / 34, lc = pixidx - lr * 34;
        int li = l0 - 1 + lr, mi = m0 - 1 + lc;
        uint16_t vals[8];
        if (li < 0 || li >= LSEQ || mi < 0 || mi >= LSEQ || icg >= 136) {
            #pragma unroll
            for (int j = 0; j < 8; ++j) vals[j] = 0;
        } else if (icg < 128) {
            size_t zoff = ((size_t)li * LSEQ + mi) * PDIM + icg;
            if (bf) {
                const uint16_t* zp = (const uint16_t*)z + zoff;
                #pragma unroll
                for (int j = 0; j < 8; ++j)
                    vals[j] = f2bf((bf2f(zp[j]) - mloc[icg + j]) * rloc[icg + j]);
            } else {
                const float* zp = (const float*)z + zoff;
                #pragma unroll
                for (int j = 0; j < 8; ++j)
                    vals[j] = f2bf((zp[j] - mloc[icg + j]) * rloc[icg + j]);
            }
        } else {  // icg == 128: channels 128..135 from a2 (channel-major bf16)
            size_t poff = (size_t)li * LSEQ + mi;
            #pragma unroll
            for (int j = 0; j < 8; ++j)
                vals[j] = f2bf((bf2f(a2[(size_t)j * LL + poff]) - mloc[128 + j]) * rloc[128 + j]);
        }
        *(uint4*)&As[pixidx * 144 + icg] = *(const uint4*)vals;
    }
    __syncthreads();   // As ready; Ws[0] drained (implicit vmcnt(0))

    int bb0 = (ocb + p) * 144 + 8 * g;   // Ws frag base; n adds 16 rows = 2304

    f32x4 acc0[4], acc1[4];
    #pragma unroll
    for (int n = 0; n < 4; ++n) {
        acc0[n] = (f32x4){0.f, 0.f, 0.f, 0.f};
        acc1[n] = (f32x4){0.f, 0.f, 0.f, 0.f};
    }
    bf16x8 bz = bf16x8_zero();

    for (int tap = 0; tap < 9; ++tap) {
        int cur = tap & 1;
        if (tap < 8) {   // prefetch next tap into the other buffer (no VGPR cost)
            const char* src = (const char*)(wt + (size_t)(tap + 1) * 18432);
            for (int s = w; s < 36; s += 8)
                gl_lds16(src + s * 1024 + lane * 16, (char*)Ws[cur ^ 1] + s * 1024);
        }

        int tr = tap / 3, tc = tap - tr * 3;
        int abase = ((r + tr) * 34 + p + tc) * 144 + 8 * g;   // +16px = 2304
        const uint16_t* Wc = Ws[cur];

        #pragma unroll
        for (int ch = 0; ch < 5; ++ch) {
            const int ic0 = (ch < 4) ? ch * 32 : 112;
            bf16x8 a0 = *(const bf16x8*)&As[abase + ic0];
            bf16x8 a1 = *(const bf16x8*)&As[abase + 2304 + ic0];
            #pragma unroll
            for (int n = 0; n < 4; ++n) {
                bf16x8 bq;
                if (ch < 4) {
                    bq = *(const bf16x8*)&Wc[bb0 + n * 2304 + ic0];
                } else {
                    bq = bz;
                    if (g == 2) bq = *(const bf16x8*)&Wc[bb0 + n * 2304 + 112];
                }
                acc0[n] = __builtin_amdgcn_mfma_f32_16x16x32_bf16(a0, bq, acc0[n], 0, 0, 0);
                acc1[n] = __builtin_amdgcn_mfma_f32_16x16x32_bf16(a1, bq, acc1[n], 0, 0, 0);
            }
        }
        __syncthreads();   // drains prefetch; all reads of Ws[cur] done
    }

    // ---- epilogue: bias + leaky; bounce through As (dead) for coalesced stores ----
    if (bf) {
        uint16_t* LB = As;   // [4 rows][32 px][128 oc] u16 = 32768 B (fits 58752)
        #pragma unroll
        for (int n = 0; n < 4; ++n) {
            int oc = ocb + 16 * n + p;
            float bb = ld(bp, oc, bf);
            #pragma unroll
            for (int reg = 0; reg < 4; ++reg) {
                int ml = 4 * g + reg;
                float v0 = acc0[n][reg] + bb; v0 = v0 >= 0.f ? v0 : 0.01f * v0;
                LB[(r * 32 + ml) * 128 + oc] = f2bf(v0);
                float v1 = acc1[n][reg] + bb; v1 = v1 >= 0.f ? v1 : 0.01f * v1;
                LB[(r * 32 + 16 + ml) * 128 + oc] = f2bf(v1);
            }
        }
        __syncthreads();
        const uint4* srcv = (const uint4*)As;
        for (int i = t; i < 2048; i += 512) {   // 4 rows x 512 uint4/row
            int run = i >> 9, off = i & 511;
            uint16_t* dst = (uint16_t*)out + 98304 +
                ((size_t)(l0 + run) * LSEQ + m0) * PDIM + (size_t)off * 8;
            *(uint4*)dst = srcv[i];
        }
    } else {
        float* LB = (float*)As;   // [2 rows][32][128] f32 = 32768 B, two passes
        #pragma unroll
        for (int h = 0; h < 2; ++h) {
            __syncthreads();
            if ((r >> 1) == h) {
                #pragma unroll
                for (int n = 0; n < 4; ++n) {
                    int oc = ocb + 16 * n + p;
                    float bb = ld(bp, oc, bf);
                    #pragma unroll
                    for (int reg = 0; reg < 4; ++reg) {
                        int ml = 4 * g + reg;
                        float v0 = acc0[n][reg] + bb; v0 = v0 >= 0.f ? v0 : 0.01f * v0;
                        LB[((r & 1) * 32 + ml) * 128 + oc] = v0;
                        float v1 = acc1[n][reg] + bb; v1 = v1 >= 0.f ? v1 : 0.01f * v1;
                        LB[((r & 1) * 32 + 16 + ml) * 128 + oc] = v1;
                    }
                }
            }
            __syncthreads();
            const uint4* srcv = (const uint4*)As;
            for (int i = t; i < 2048; i += 512) {   // 2 rows x 1024 uint4/row
                int run = i >> 10, off = i & 1023;
                float* dst = (float*)out + 98304 +
                    ((size_t)(l0 + h * 2 + run) * LSEQ + m0) * PDIM + (size_t)off * 4;
                *(uint4*)dst = srcv[i];
            }
        }
    }
}

// ---------------- conv_p fallback: f32 VALU path (used if workspace too small) ----------------
__global__ __launch_bounds__(128) void k_conv_p(
    const void* __restrict__ z, const uint16_t* __restrict__ a2,
    const void* __restrict__ wp, const void* __restrict__ bp,
    const float* __restrict__ meanP, const float* __restrict__ rstdP,
    void* __restrict__ out, const int* __restrict__ dt)
{
    __shared__ __align__(16) float wlds[128 * 76];
    __shared__ __align__(16) float inl[4 * 18 * 8];
    int bf = dt[0];
    int t = threadIdx.x;
    int m0 = blockIdx.x * 16, l0 = blockIdx.y * 2;
    float acc0[16], acc1[16];
    #pragma unroll
    for (int i = 0; i < 16; ++i) { acc0[i] = 0.f; acc1[i] = 0.f; }

    for (int ic0 = 0; ic0 < 136; ic0 += 8) {
        __syncthreads();
        for (int i = t; i < 128 * 72; i += 128) {
            int op = i / 72, r = i % 72;
            int cc = r / 9, tap = r % 9;
            wlds[op * 76 + tap * 8 + cc] = ld(wp, op * 1224 + (ic0 + cc) * 9 + tap, bf);
        }
        for (int i = t; i < 4 * 18 * 8; i += 128) {
            int rr = i / 144, rem = i % 144;
            int col = rem >> 3, cc = rem & 7;
            int li = l0 - 1 + rr, mi = m0 - 1 + col, ic = ic0 + cc;
            float vv = 0.f;
            if (li >= 0 && li < LSEQ && mi >= 0 && mi < LSEQ) {
                float raw = (ic < PDIM) ? ld(z, ((size_t)li * LSEQ + mi) * PDIM + ic, bf)
                                        : bf2f(a2[(size_t)(ic - PDIM) * LL + li * LSEQ + mi]);
                vv = (raw - meanP[ic]) * rstdP[ic];
            }
            inl[i] = vv;
        }
        __syncthreads();
        #pragma unroll
        for (int qd = 0; qd < 2; ++qd) {
            float4 wq[9];
            #pragma unroll
            for (int tap = 0; tap < 9; ++tap)
                wq[tap] = *(const float4*)&wlds[t * 76 + tap * 8 + qd * 4];
            float4 win[4][3];
            #pragma unroll
            for (int r = 0; r < 4; ++r) {
                win[r][1] = *(const float4*)&inl[(r * 18 + 0) * 8 + qd * 4];
                win[r][2] = *(const float4*)&inl[(r * 18 + 1) * 8 + qd * 4];
                win[r][0] = win[r][1];
            }
            #pragma unroll
            for (int pix = 0; pix < 16; ++pix) {
                #pragma unroll
                for (int r = 0; r < 4; ++r) {
                    win[r][0] = win[r][1];
                    win[r][1] = win[r][2];
                    win[r][2] = *(const float4*)&inl[(r * 18 + pix + 2) * 8 + qd * 4];
                }
                float p0x = 0.f, p0y = 0.f, p0z = 0.f, p0w = 0.f;
                float p1x = 0.f, p1y = 0.f, p1z = 0.f, p1w = 0.f;
                #pragma unroll
                for (int tr = 0; tr < 3; ++tr) {
                    #pragma unroll
                    for (int c = 0; c < 3; ++c) {
                        float4 w4 = wq[tr * 3 + c];
                        float4 u0 = win[tr][c];
                        float4 u1 = win[tr + 1][c];
                        p0x = fmaf(w4.x, u0.x, p0x); p0y = fmaf(w4.y, u0.y, p0y);
                        p0z = fmaf(w4.z, u0.z, p0z); p0w = fmaf(w4.w, u0.w, p0w);
                        p1x = fmaf(w4.x, u1.x, p1x); p1y = fmaf(w4.y, u1.y, p1y);
                        p1z = fmaf(w4.z, u1.z, p1z); p1w = fmaf(w4.w, u1.w, p1w);
                    }
                }
                acc0[pix] += (p0x + p0y) + (p0z + p0w);
                acc1[pix] += (p1x + p1y) + (p1z + p1w);
            }
        }
    }
    float bb = ld(bp, t, bf);
    #pragma unroll
    for (int pix = 0; pix < 16; ++pix) {
        float v0 = acc0[pix] + bb; v0 = v0 >= 0.f ? v0 : 0.01f * v0;
        stout(out, 98304 + ((size_t)l0 * LSEQ + m0 + pix) * PDIM + t, v0, bf);
        float v1 = acc1[pix] + bb; v1 = v1 >= 0.f ? v1 : 0.01f * v1;
        stout(out, 98304 + ((size_t)(l0 + 1) * LSEQ + m0 + pix) * PDIM + t, v1, bf);
    }
}

extern "C" void kernel_launch(void* const* d_in, const int* in_sizes, int n_in,
                              void* d_out, int out_size, void* d_ws, size_t ws_size,
                              hipStream_t stream)
{
    const void* x     = d_in[0];
    const void* z     = d_in[1];
    const void* plddt = d_in[2];
    const void* Wq    = d_in[3];
    const void* Wk    = d_in[4];
    const void* Wv    = d_in[5];
    const void* Wp2a  = d_in[6];
    const void* caw   = d_in[7];
    const void* cab   = d_in[8];
    const void* cmw   = d_in[9];
    const void* cmb   = d_in[10];
    const void* ln1w  = d_in[11];
    const void* ln1b  = d_in[12];
    const void* l1w   = d_in[13];
    const void* l1b   = d_in[14];
    const void* ln2w  = d_in[15];
    const void* ln2b  = d_in[16];
    const void* l2w   = d_in[17];
    const void* l2b   = d_in[18];
    const void* lnfw  = d_in[19];
    const void* lnfb  = d_in[20];
    const void* cpw   = d_in[21];
    const void* cpb   = d_in[22];

    uint16_t* O = (uint16_t*)d_out;
    uint16_t* acat = O + 98304;               // 16*LL bf16
    uint16_t* a1b  = O + 2457600;             // 8*LL bf16 (pre-conv_a: q,k)
    uint16_t* qb   = a1b;
    uint16_t* kb   = a1b + 98304;
    uint16_t* vb   = O + 3637248;
    float*    cat  = (float*)(O + 3735552);   // 384x1280 f32
    float*    h1   = (float*)(O + 5701632);   // 384x512 f32
    float*    psum = (float*)(O + 6488064);
    float*    psumsq = (float*)(O + 6635520); // ends 6782976
    uint16_t* cb   = O + 6782976;             // 384x1280 bf16 (LN1 out)
    uint16_t* h1nb = O + 7274496;             // 384x512 bf16 (LN2 out)
    uint16_t* xb   = O + 7471104;             // 384x256 bf16
    uint16_t* wtq  = O + 7569408;             // 768x256 bf16 (Wq|Wk|Wv, n-major)
    uint16_t* wt1  = O + 7766016;             // 512x1280 bf16 (lin1, n-major)
    uint16_t* wt2  = O + 8421376;             // 256x512 bf16 (lin2, n-major)

    uint16_t* U = (uint16_t*)d_ws;
    uint16_t* a2b = U;                        // 8*LL bf16, live into conv_p
    float*    st  = (float*)(U + 1179648);    // stats, live into conv_p
    float* m16 = st;        float* r16 = st + 16;
    float* m9  = st + 32;   float* r9  = st + 48;
    float* mP  = st + 64;   float* rP  = st + 200;   // 136 each
    int*   flg = (int*)(U + 1181696);         // dtype flag
    uint16_t* wt = U + 1182720;               // 9*128*144 bf16 = 331776 B (conv_p MFMA weights)
    int use_mfma = (ws_size >= (size_t)2365440 + 331776);

    k_detect<<<1, 64, 0, stream>>>((const uint32_t*)z, flg);
    // merged prep: x->bf16 + five n-major weight transposes in one launch
    k_prep<<<dim3(40, 16, 6), 256, 0, stream>>>(Wq, Wk, Wv, l1w, l2w, x,
                                                wtq, wt1, wt2, xb, flg);

    k_gemm_qkv<<<dim3(6, 12), 256, 0, stream>>>(xb, wtq, qb, kb, vb);
    k_apair <<<dim3(12, LSEQ), 256, 0, stream>>>(z, Wp2a, acat, flg);
    k_anode <<<dim3(12, LSEQ), 256, 0, stream>>>(qb, kb, acat);
    // stats over acat (16 ch)
    k_scp<<<dim3(18, 16), 256, 0, stream>>>(acat, plddt, psum, psumsq, flg, 16);
    k_scf<<<1, 16, 0, stream>>>(psum, psumsq, m16, r16, 16);
    k_conv_a<<<dim3(3, LSEQ), 128, 0, stream>>>(acat, caw, cab, m16, r16, a1b, flg);
    // stats over a1b (8 ch) + plddt (tail channel 8) in one pass
    k_scp<<<dim3(18, 9), 256, 0, stream>>>(a1b, plddt, psum, psumsq, flg, 8);
    k_scf<<<1, 9, 0, stream>>>(psum, psumsq, m9, r9, 9);
    k_conv_m<<<dim3(3, LSEQ), 128, 0, stream>>>(a1b, plddt, cmw, cmb, m9, r9, a2b, flg);
    k_agg   <<<LSEQ, 512, 0, stream>>>(a2b, vb, z, cat, flg);
    k_ln1   <<<LSEQ, 256, 0, stream>>>(cat, ln1w, ln1b, cb, flg);
    k_gemm_bias_f32<<<dim3(6, 8), 256, 0, stream>>>(cb, wt1, l1b, h1, 1280, 512, flg);
    k_ln2   <<<LSEQ, 256, 0, stream>>>(h1, ln2w, ln2b, h1nb, flg);
    k_lin2lnf_mfma<<<12, 256, 0, stream>>>(h1nb, wt2, l2b, x, lnfw, lnfb, d_out, flg);
    // stats over a2b (8 ch)
    k_scp<<<dim3(18, 8), 256, 0, stream>>>(a2b, plddt, psum, psumsq, flg, 8);
    k_scf<<<1, 8, 0, stream>>>(psum, psumsq, mP + 128, rP + 128, 8);
    k_pstat <<<576, 256, 0, stream>>>(z, psum, psumsq, flg);
    k_finP  <<<1, 512, 0, stream>>>(psum, psumsq, mP, rP);
    if (use_mfma) {
        k_wprep<<<dim3(128, 9), 64, 0, stream>>>(cpw, wt, flg);
        k_conv_p_mfma<<<dim3(12, 96), 512, 0, stream>>>(z, a2b, wt, cpb, mP, rP, d_out, flg);
    } else {
        k_conv_p<<<dim3(24, 192), 128, 0, stream>>>(z, a2b, cpw, cpb, mP, rP, d_out, flg);
    }
}